// Round 2
// baseline (2637.674 us; speedup 1.0000x reference)
//
#include <hip/hip_runtime.h>
#include <math.h>

#define LSEQ 2048
#define NM   64     // N modes
#define HD   64     // H
#define NDIV 8
#define NB   8      // batch
#define NF   2049   // rfft bins of 4096
#define IH   32     // i-half size

// ---------------- double complex helpers (precompute only) ----------------
struct cplxd { double x, y; };
__device__ __forceinline__ cplxd cmuld(cplxd a, cplxd b) {
  return {a.x*b.x - a.y*b.y, a.x*b.y + a.y*b.x};
}
__device__ __forceinline__ cplxd cdivd(cplxd a, cplxd b) {
  double inv = 1.0 / (b.x*b.x + b.y*b.y);
  return {(a.x*b.x + a.y*b.y)*inv, (a.y*b.x - a.x*b.y)*inv};
}

// ---------------- 2048-pt radix-2 LDS FFT, 256 threads ----------------
__device__ __forceinline__ void build_tw(float2* TW) {
  for (int m = threadIdx.x; m < 1024; m += 256) {
    float s, c;
    __sincosf(-6.28318530717958647f * (float)m * (1.0f/2048.0f), &s, &c);
    TW[m] = make_float2(c, s);
  }
}

// DIF: natural input -> bit-reversed output. SIGN=-1 forward, +1 inverse (unscaled).
template<int SIGN>
__device__ __forceinline__ void fft2048_dif(float2* X, const float2* TW) {
  const int tid = threadIdx.x;
  int sh = 0;
  for (int half = 1024; half >= 1; half >>= 1, sh++) {
    __syncthreads();
    #pragma unroll 1
    for (int q = tid; q < 1024; q += 256) {
      int k  = q & (half - 1);
      int i0 = ((q & ~(half - 1)) << 1) | k;
      int i1 = i0 + half;
      float2 a = X[i0], b = X[i1];
      float2 w = TW[k << sh];
      float wy = (SIGN > 0) ? -w.y : w.y;
      float dx = a.x - b.x, dy = a.y - b.y;
      X[i0] = make_float2(a.x + b.x, a.y + b.y);
      X[i1] = make_float2(dx*w.x - dy*wy, dx*wy + dy*w.x);
    }
  }
}

// DIT: bit-reversed input -> natural output.
template<int SIGN>
__device__ __forceinline__ void fft2048_dit(float2* X, const float2* TW) {
  const int tid = threadIdx.x;
  int sh = 10;
  for (int half = 1; half <= 1024; half <<= 1, sh--) {
    __syncthreads();
    #pragma unroll 1
    for (int q = tid; q < 1024; q += 256) {
      int k  = q & (half - 1);
      int i0 = ((q & ~(half - 1)) << 1) | k;
      int i1 = i0 + half;
      float2 a = X[i0], b = X[i1];
      float2 w = TW[k << sh];
      float wy = (SIGN > 0) ? -w.y : w.y;
      float bx = b.x*w.x - b.y*wy;
      float by = b.x*wy + b.y*w.x;
      X[i0] = make_float2(a.x + bx, a.y + by);
      X[i1] = make_float2(a.x - bx, a.y - by);
    }
  }
}

// ---------------- K0a: rc = c*r (per l,div,n), cpx = c*(1+k11) ----------------
__global__ __launch_bounds__(256) void ssm_k0a(
    const float* __restrict__ Lre, const float* __restrict__ Lim,
    const float* __restrict__ Pre, const float* __restrict__ Pim,
    const float* __restrict__ step, float2* __restrict__ rc, float2* __restrict__ cpx) {
  int idx = blockIdx.x * 256 + threadIdx.x;     // 16384 = 2048 * 8
  int l = idx & (LSEQ - 1);
  int dv = idx >> 11;
  double s = (double)expf(step[0]);
  float angf = -6.2831855f * ((float)l * (1.0f/2048.0f));
  double si, co;
  sincos((double)angf, &si, &co);
  cplxd om    = {co, si};
  cplxd one_p = {1.0 + om.x,  om.y};
  double ts = 2.0 / s;
  cplxd g = cdivd({ts*(1.0 - om.x), ts*(-om.y)}, one_p);
  cplxd c = cdivd({2.0, 0.0}, one_p);
  cplxd k11 = {0.0, 0.0};
  float2* rcrow = rc + ((size_t)dv*LSEQ + l)*NM;
  for (int n = 0; n < NM; n++) {
    float lre = fminf(Lre[n*NDIV+dv], -0.0001f);
    float lim = Lim[n*NDIV+dv];
    cplxd den = {g.x - (double)lre, g.y - (double)lim};
    cplxd r   = cdivd({1.0, 0.0}, den);
    cplxd rcv = cmuld(c, r);
    rcrow[n] = make_float2((float)rcv.x, (float)rcv.y);
    double pr = (double)Pre[n*NDIV+dv], pi = (double)Pim[n*NDIV+dv];
    double p2 = pr*pr + pi*pi;                  // conj(p)*p is real
    k11.x += p2 * rcv.x; k11.y += p2 * rcv.y;
  }
  cpx[(size_t)dv*LSEQ + l] = make_float2((float)(c.x + k11.x), (float)(c.y + k11.y));
}

// ---------------- K0b: A1 = (c*k01)/cpx, k10c = c*k10 ----------------
__global__ __launch_bounds__(256) void ssm_k0b(
    const float* __restrict__ Pre, const float* __restrict__ Pim,
    const float* __restrict__ Cre, const float* __restrict__ Cim,
    const float* __restrict__ Bre, const float* __restrict__ Bim,
    const float2* __restrict__ rc, const float2* __restrict__ cpx,
    float2* __restrict__ A1, float2* __restrict__ k10c) {
  int dv = blockIdx.y;
  int l0 = blockIdx.x * 4;
  __shared__ float2 rcs[4][NM];
  __shared__ float2 ps[NM];
  int tid = threadIdx.x;
  { int q = tid; rcs[q>>6][q&63] = rc[((size_t)dv*LSEQ + l0 + (q>>6))*NM + (q&63)]; }
  if (tid < NM) ps[tid] = make_float2(Pre[tid*NDIV+dv], Pim[tid*NDIV+dv]);
  __syncthreads();
  int ll = tid >> 6, idx = tid & 63;
  int l = l0 + ll;
  float k01r=0.f, k01i=0.f, k10r=0.f, k10i=0.f;
  for (int n = 0; n < NM; n++) {
    float2 rv = rcs[ll][n];
    float2 pv = ps[n];
    float cr =  Cre[(idx*NM+n)*NDIV+dv];
    float ci = -Cim[(idx*NM+n)*NDIV+dv];        // conj(C)
    float tr = cr*rv.x - ci*rv.y, ti = cr*rv.y + ci*rv.x;
    k01r += tr*pv.x - ti*pv.y; k01i += tr*pv.y + ti*pv.x;
    float br_ = Bre[(n*HD+idx)*NDIV+dv], bi = Bim[(n*HD+idx)*NDIV+dv];
    float ur = pv.x*rv.x + pv.y*rv.y;           // conj(p)*rv
    float ui = pv.x*rv.y - pv.y*rv.x;
    k10r += ur*br_ - ui*bi; k10i += ur*bi + ui*br_;
  }
  float2 wv = cpx[(size_t)dv*LSEQ + l];
  float inv = 1.0f / (wv.x*wv.x + wv.y*wv.y);
  A1  [((size_t)dv*LSEQ + l)*HD + idx] = make_float2((k01r*wv.x + k01i*wv.y)*inv,
                                                     (k01i*wv.x - k01r*wv.y)*inv);
  k10c[((size_t)dv*LSEQ + l)*HD + idx] = make_float2(k10r, k10i);
}

// ---------------- Ku: u (b,l,512) -> ut[div][b][h][l] ----------------
__global__ __launch_bounds__(256) void ssm_ku(const float* __restrict__ u, float* __restrict__ ut) {
  __shared__ float s[16][513];
  int b  = blockIdx.x >> 7;
  int l0 = (blockIdx.x & 127) << 4;
  int tid = threadIdx.x;
  for (int q = tid; q < 16*512; q += 256) {
    int ll = q >> 9, dd = q & 511;
    s[ll][dd] = u[((size_t)b*LSEQ + l0 + ll)*512 + dd];
  }
  __syncthreads();
  for (int q = tid; q < 16*512; q += 256) {
    int d = q >> 4, ll = q & 15;
    int dvv = d & 7, h = d >> 3;
    ut[(((size_t)(dvv*NB + b))*HD + h)*LSEQ + l0 + ll] = s[ll][d];
  }
}

// ---------------- K3: per div: ud[c][f] = rfft_4096(pad(ut row)) ----------------
__global__ __launch_bounds__(256) void ssm_k3(const float* __restrict__ ut, float2* __restrict__ ud, int dv) {
  __shared__ float2 X[2048];
  __shared__ float2 TW[1024];
  int tid = threadIdx.x;
  int c = blockIdx.x;                           // 0..511 = b*64 + h
  const float2* src = (const float2*)(ut + ((size_t)dv*512 + c) * LSEQ);
  float2* dst = ud + (size_t)c * NF;
  build_tw(TW);
  for (int p = tid; p < 2048; p += 256)
    X[p] = (p < 1024) ? src[p] : make_float2(0.f, 0.f);   // z[t]=x[2t]+i x[2t+1]
  fft2048_dif<-1>(X, TW);
  __syncthreads();
  for (int f = tid; f <= 2048; f += 256) {
    int fa = f & 2047, fb = (2048 - f) & 2047;
    float2 Zf = X[__brev((unsigned)fa) >> 21];
    float2 Zm = X[__brev((unsigned)fb) >> 21];
    float Ex = (Zf.x + Zm.x)*0.5f, Ey = (Zf.y - Zm.y)*0.5f;
    float Dx = Zf.x - Zm.x,        Dy = Zf.y + Zm.y;
    float Ox = Dy*0.5f, Oy = -Dx*0.5f;                     // (Zf-conj(Zm))/(2i)
    float s, c2;
    __sincosf(-6.28318530717958647f * (float)f * (1.0f/4096.0f), &s, &c2);
    float WOx = Ox*c2 - Oy*s, WOy = Ox*s + Oy*c2;
    dst[f] = make_float2(Ex + WOx, Ey + WOy);
  }
}

// ---------------- K1: at_roots for (div, i-half), written chain-major ----------------
// chain ci = iloc*64 + j, row stride NF (in-place headroom for K2's 2049 bins)
__global__ __launch_bounds__(256) void ssm_k1(
    const float* __restrict__ Cre, const float* __restrict__ Cim,
    const float* __restrict__ Bre, const float* __restrict__ Bim,
    const float2* __restrict__ rc, const float2* __restrict__ A1,
    const float2* __restrict__ k10c, float2* __restrict__ big,
    int dv, int iBase) {
  __shared__ float2 CC[NM][IH];     // conj(C)[iBase+il][n]  (16KB)
  __shared__ float2 BB[NM][HD];     // B[n][j]               (32KB)
  __shared__ float2 rcs[8][NM+1];   // 8 l's (padded)        (4KB)
  int tid = threadIdx.x;
  int l0 = blockIdx.x * 8;
  for (int q = tid; q < NM*IH; q += 256) {
    int n = q >> 5, il = q & 31;
    int i = iBase + il;
    CC[n][il] = make_float2(Cre[((size_t)i*NM+n)*NDIV+dv], -Cim[((size_t)i*NM+n)*NDIV+dv]);
  }
  for (int q = tid; q < NM*HD; q += 256) {
    int n = q >> 6, j = q & 63;
    BB[n][j] = make_float2(Bre[((size_t)n*HD+j)*NDIV+dv], Bim[((size_t)n*HD+j)*NDIV+dv]);
  }
  for (int q = tid; q < 8*NM; q += 256) {
    int ll = q >> 6, n = q & 63;
    rcs[ll][n] = rc[((size_t)dv*LSEQ + l0 + ll)*NM + n];
  }
  __syncthreads();
  int lq = tid & 7;           // adjacent lanes = adjacent l (coalesced writes)
  int tile = tid >> 3;        // 32 tiles
  int ti = (tile >> 3) * 8;   // iloc base: 0/8/16/24, 8 consecutive i
  int tj = tile & 7;          // j = tj + 8*b (conflict-free BB reads)
  int l = l0 + lq;
  float2 acc[8][8];
  #pragma unroll
  for (int a = 0; a < 8; a++)
    #pragma unroll
    for (int b = 0; b < 8; b++) acc[a][b] = make_float2(0.f, 0.f);
  for (int n = 0; n < NM; n++) {
    float2 rv = rcs[lq][n];
    float2 uu[8];
    #pragma unroll
    for (int a = 0; a < 8; a++) {
      float2 cv = CC[n][ti+a];
      uu[a] = make_float2(cv.x*rv.x - cv.y*rv.y, cv.x*rv.y + cv.y*rv.x);
    }
    #pragma unroll
    for (int b = 0; b < 8; b++) {
      float2 bv = BB[n][tj + 8*b];
      #pragma unroll
      for (int a = 0; a < 8; a++) {
        acc[a][b].x = fmaf(uu[a].x, bv.x, fmaf(-uu[a].y, bv.y, acc[a][b].x));
        acc[a][b].y = fmaf(uu[a].x, bv.y, fmaf( uu[a].y, bv.x, acc[a][b].y));
      }
    }
  }
  const float2* A1row = A1   + ((size_t)dv*LSEQ + l)*HD;
  const float2* kqrow = k10c + ((size_t)dv*LSEQ + l)*HD;
  float2 ua[8], kb[8];
  #pragma unroll
  for (int a = 0; a < 8; a++) ua[a] = A1row[iBase + ti + a];
  #pragma unroll
  for (int b = 0; b < 8; b++) kb[b] = kqrow[tj + 8*b];
  #pragma unroll
  for (int a = 0; a < 8; a++)
    #pragma unroll
    for (int b = 0; b < 8; b++) {
      acc[a][b].x -= ua[a].x*kb[b].x - ua[a].y*kb[b].y;
      acc[a][b].y -= ua[a].x*kb[b].y + ua[a].y*kb[b].x;
    }
  #pragma unroll
  for (int a = 0; a < 8; a++)
    #pragma unroll
    for (int b = 0; b < 8; b++)
      big[((size_t)((ti+a)*64 + tj + 8*b))*NF + l] = acc[a][b];
}

// ---------------- K2: in-place per chain: art row (2048) -> Kd row (2049) ----------------
__global__ __launch_bounds__(256) void ssm_k2(float2* __restrict__ big) {
  __shared__ float2 X[2048];
  __shared__ float2 TW[1024];
  int tid = threadIdx.x;
  float2* row = big + (size_t)blockIdx.x * NF;
  build_tw(TW);
  for (int p = tid; p < 2048; p += 256) X[p] = row[p];
  __syncthreads();
  // even bins X4096[2l] = (ar[l] + conj(ar[(2048-l)%2048]))/2
  float2 ev[4];
  #pragma unroll
  for (int k = 0; k < 4; k++) {
    int l = tid + 256*k;                         // l in [0,1024)
    float2 a = X[l], b = X[(2048 - l) & 2047];
    ev[k] = make_float2((a.x+b.x)*0.5f, (a.y-b.y)*0.5f);
  }
  float ev1024 = X[1024].x;                      // bin 2048 = Re(ar[1024])
  // K = Re(ifft(ar)) (scale 1/2048), modulate by e^{-i*pi*t/2048}
  fft2048_dif<1>(X, TW);
  __syncthreads();
  const float sc = 1.0f/2048.0f;
  for (int p = tid; p < 2048; p += 256) {
    int t = (int)(__brev((unsigned)p) >> 21);
    float kr = X[p].x * sc;
    float s, c;
    __sincosf(-3.14159265358979324f * (float)t * (1.0f/2048.0f), &s, &c);
    X[p] = make_float2(kr*c, kr*s);
  }
  fft2048_dit<-1>(X, TW);   // odd bins: X[k] = X4096[2k+1], natural order
  __syncthreads();
  #pragma unroll
  for (int k = 0; k < 4; k++) { int l = tid + 256*k; X[1024 + l] = ev[k]; }
  __syncthreads();
  for (int e = tid; e < 2048; e += 256)
    row[e] = (e & 1) ? X[e >> 1] : X[1024 + (e >> 1)];
  if (tid == 0) row[2048] = make_float2(ev1024, 0.f);
}

// ---------------- K4: yf[b,f,iloc] = sum_j Kd[iloc*64+j][f] * ud[b*64+j][f] ----------------
__global__ __launch_bounds__(256) void ssm_k4(
    const float2* __restrict__ kdt, const float2* __restrict__ ud,
    float2* __restrict__ yf) {
  __shared__ float2 uds[NB][HD][8];   // 32KB
  int tid = threadIdx.x;
  int f0 = blockIdx.x * 8;
  for (int q = tid; q < NB*HD*8; q += 256) {
    int b = q >> 9, j = (q >> 3) & 63, ff = q & 7;
    int f = f0 + ff;
    uds[b][j][ff] = (f < NF) ? ud[((size_t)(b*HD + j))*NF + f] : make_float2(0.f, 0.f);
  }
  __syncthreads();
  int i = tid >> 3, fq = tid & 7;     // i = iloc in [0,32)
  int f = f0 + fq;
  if (f >= NF) return;
  float2 acc[NB];
  #pragma unroll
  for (int b = 0; b < NB; b++) acc[b] = make_float2(0.f, 0.f);
  for (int j = 0; j < HD; j++) {
    float2 kv = kdt[((size_t)(i*HD + j))*NF + f];
    #pragma unroll
    for (int b = 0; b < NB; b++) {
      float2 uv = uds[b][j][fq];
      acc[b].x += kv.x*uv.x - kv.y*uv.y;
      acc[b].y += kv.x*uv.y + kv.y*uv.x;
    }
  }
  #pragma unroll
  for (int b = 0; b < NB; b++)
    yf[((size_t)(b*IH + i))*NF + f] = acc[b];
}

// ---------------- K5: yt row = irfft_4096(yf row)[0:2048] ----------------
__global__ __launch_bounds__(256) void ssm_k5(const float2* __restrict__ yf,
                                              float* __restrict__ yt, int dv, int iBase) {
  __shared__ float2 X[2048];
  __shared__ float2 TW[1024];
  int tid = threadIdx.x;
  int b = blockIdx.x >> 5, iloc = blockIdx.x & 31;
  const float2* src = yf + (size_t)(b*IH + iloc) * NF;
  float2* dst = (float2*)(yt + (((size_t)(dv*NB + b))*HD + iBase + iloc) * LSEQ);
  build_tw(TW);
  for (int k = tid; k < 2048; k += 256) {
    float2 Xk = src[k];
    float2 Xm = src[2048 - k];
    float Ex = (Xk.x + Xm.x)*0.5f, Ey = (Xk.y - Xm.y)*0.5f;
    float Dx = Xk.x - Xm.x,        Dy = Xk.y + Xm.y;
    float s, c;
    __sincosf(6.28318530717958647f * (float)k * (1.0f/4096.0f), &s, &c);
    float Ox = 0.5f*(Dx*c - Dy*s);
    float Oy = 0.5f*(Dx*s + Dy*c);
    X[k] = make_float2(Ex - Oy, Ey + Ox);   // Z = E + i*O
  }
  fft2048_dif<1>(X, TW);
  __syncthreads();
  const float sc = 1.0f/2048.0f;
  for (int t = tid; t < 1024; t += 256) {
    int p = (int)(__brev((unsigned)t) >> 21);
    float2 z = X[p];
    dst[t] = make_float2(z.x*sc, z.y*sc);   // y[2t], y[2t+1]
  }
}

// ---------------- T2: yt[div][b][i][t] -> out[b][t][i*8+div] ----------------
__global__ __launch_bounds__(256) void ssm_t2(const float* __restrict__ yt, float* __restrict__ out) {
  __shared__ float s[512][17];
  int b  = blockIdx.x >> 7;
  int t0 = (blockIdx.x & 127) << 4;
  int tid = threadIdx.x;
  for (int q = tid; q < 512*16; q += 256) {
    int d = q >> 4, tt = q & 15;
    int dvv = d & 7, i = d >> 3;
    s[d][tt] = yt[(((size_t)(dvv*NB + b))*HD + i)*LSEQ + t0 + tt];
  }
  __syncthreads();
  for (int q = tid; q < 512*16; q += 256) {
    int tt = q >> 9, d = q & 511;
    out[((size_t)b*LSEQ + t0 + tt)*512 + d] = s[d][tt];
  }
}

// ---------------- host ----------------
extern "C" void kernel_launch(void* const* d_in, const int* in_sizes, int n_in,
                              void* d_out, int out_size, void* d_ws, size_t ws_size,
                              hipStream_t stream) {
  const float* u    = (const float*)d_in[0];
  const float* Lre  = (const float*)d_in[1];
  const float* Lim  = (const float*)d_in[2];
  const float* Pre  = (const float*)d_in[3];
  const float* Pim  = (const float*)d_in[4];
  const float* Bre  = (const float*)d_in[5];
  const float* Bim  = (const float*)d_in[6];
  const float* Cre  = (const float*)d_in[7];
  const float* Cim  = (const float*)d_in[8];
  const float* step = (const float*)d_in[9];
  float* out = (float*)d_out;

  char* w = (char*)d_ws;
  size_t off = 0;
  auto carve = [&](size_t bytes) -> void* {
    void* p = (void*)(w + off);
    off += (bytes + 255) & ~(size_t)255;
    return p;
  };
  float2* rc   = (float2*)carve((size_t)NDIV*LSEQ*NM*sizeof(float2));     // 8.39 MB
  float2* cpx  = (float2*)carve((size_t)NDIV*LSEQ*sizeof(float2));        // 0.13 MB
  float2* A1   = (float2*)carve((size_t)NDIV*LSEQ*HD*sizeof(float2));     // 8.39 MB
  float2* k10c = (float2*)carve((size_t)NDIV*LSEQ*HD*sizeof(float2));     // 8.39 MB
  float*  ut   = (float*) carve((size_t)NDIV*NB*HD*LSEQ*sizeof(float));   // 33.55 MB (later = yt)
  float2* big  = (float2*)carve((size_t)2048*NF*sizeof(float2));          // 33.57 MB (art/Kd, in-place)
  float2* ud   = (float2*)carve((size_t)512*NF*sizeof(float2));           // 8.39 MB (per div)
  float2* yf   = (float2*)carve((size_t)256*NF*sizeof(float2));           // 4.20 MB (per div-half)
  (void)in_sizes; (void)n_in; (void)out_size;
  if (ws_size < off) return;   // insufficient scratch -> leave out zeroed (diagnosable)

  ssm_k0a<<<64, 256, 0, stream>>>(Lre, Lim, Pre, Pim, step, rc, cpx);
  ssm_k0b<<<dim3(512, 8), 256, 0, stream>>>(Pre, Pim, Cre, Cim, Bre, Bim, rc, cpx, A1, k10c);
  ssm_ku<<<1024, 256, 0, stream>>>(u, ut);
  for (int dv = 0; dv < NDIV; ++dv) {
    ssm_k3<<<512, 256, 0, stream>>>(ut, ud, dv);
    for (int ih = 0; ih < 2; ++ih) {
      int iBase = ih * IH;
      ssm_k1<<<256, 256, 0, stream>>>(Cre, Cim, Bre, Bim, rc, A1, k10c, big, dv, iBase);
      ssm_k2<<<2048, 256, 0, stream>>>(big);
      ssm_k4<<<257, 256, 0, stream>>>(big, ud, yf);
      ssm_k5<<<256, 256, 0, stream>>>(yf, ut, dv, iBase);
    }
  }
  ssm_t2<<<1024, 256, 0, stream>>>(ut, out);
}

// Round 3
// 2216.461 us; speedup vs baseline: 1.1900x; 1.1900x over previous
//
#include <hip/hip_runtime.h>
#include <math.h>

#define LSEQ 2048
#define NM   64     // N modes
#define HD   64     // H
#define NDIV 8
#define NB   8      // batch
#define NF   2049   // rfft bins of 4096
#define IH   32     // i-half size

// ---------------- double complex helpers (precompute only) ----------------
struct cplxd { double x, y; };
__device__ __forceinline__ cplxd cmuld(cplxd a, cplxd b) {
  return {a.x*b.x - a.y*b.y, a.x*b.y + a.y*b.x};
}
__device__ __forceinline__ cplxd cdivd(cplxd a, cplxd b) {
  double inv = 1.0 / (b.x*b.x + b.y*b.y);
  return {(a.x*b.x + a.y*b.y)*inv, (a.y*b.x - a.x*b.y)*inv};
}

// ---------------- 2048-pt radix-2 LDS FFT, 256 threads ----------------
__device__ __forceinline__ void build_tw(float2* TW) {
  for (int m = threadIdx.x; m < 1024; m += 256) {
    float s, c;
    __sincosf(-6.28318530717958647f * (float)m * (1.0f/2048.0f), &s, &c);
    TW[m] = make_float2(c, s);
  }
}

// DIF: natural input -> bit-reversed output. SIGN=-1 forward, +1 inverse (unscaled).
template<int SIGN>
__device__ __forceinline__ void fft2048_dif(float2* X, const float2* TW) {
  const int tid = threadIdx.x;
  int sh = 0;
  for (int half = 1024; half >= 1; half >>= 1, sh++) {
    __syncthreads();
    #pragma unroll 1
    for (int q = tid; q < 1024; q += 256) {
      int k  = q & (half - 1);
      int i0 = ((q & ~(half - 1)) << 1) | k;
      int i1 = i0 + half;
      float2 a = X[i0], b = X[i1];
      float2 w = TW[k << sh];
      float wy = (SIGN > 0) ? -w.y : w.y;
      float dx = a.x - b.x, dy = a.y - b.y;
      X[i0] = make_float2(a.x + b.x, a.y + b.y);
      X[i1] = make_float2(dx*w.x - dy*wy, dx*wy + dy*w.x);
    }
  }
}

// DIT: bit-reversed input -> natural output.
template<int SIGN>
__device__ __forceinline__ void fft2048_dit(float2* X, const float2* TW) {
  const int tid = threadIdx.x;
  int sh = 10;
  for (int half = 1; half <= 1024; half <<= 1, sh--) {
    __syncthreads();
    #pragma unroll 1
    for (int q = tid; q < 1024; q += 256) {
      int k  = q & (half - 1);
      int i0 = ((q & ~(half - 1)) << 1) | k;
      int i1 = i0 + half;
      float2 a = X[i0], b = X[i1];
      float2 w = TW[k << sh];
      float wy = (SIGN > 0) ? -w.y : w.y;
      float bx = b.x*w.x - b.y*wy;
      float by = b.x*wy + b.y*w.x;
      X[i0] = make_float2(a.x + bx, a.y + by);
      X[i1] = make_float2(a.x - bx, a.y - by);
    }
  }
}

// ---------------- KT: transpose params to div-major coalesced layouts ----------------
// CT[dv][n][i] = conj(C)[i][n],  BT[dv][n][j] = B[n][j],  PT[dv][n] = P[n]
__global__ __launch_bounds__(256) void ssm_kt(
    const float* __restrict__ Cre, const float* __restrict__ Cim,
    const float* __restrict__ Bre, const float* __restrict__ Bim,
    const float* __restrict__ Pre, const float* __restrict__ Pim,
    float2* __restrict__ CT, float2* __restrict__ BT, float2* __restrict__ PT) {
  int idx = blockIdx.x * 256 + threadIdx.x;   // 32768 = dv*4096 + n*64 + x
  int dv = idx >> 12, n = (idx >> 6) & 63, x = idx & 63;
  CT[idx] = make_float2(Cre[((size_t)x*NM + n)*NDIV + dv], -Cim[((size_t)x*NM + n)*NDIV + dv]);
  BT[idx] = make_float2(Bre[((size_t)n*HD + x)*NDIV + dv],  Bim[((size_t)n*HD + x)*NDIV + dv]);
  if (idx < NDIV*NM) {
    int dv2 = idx >> 6, n2 = idx & 63;
    PT[idx] = make_float2(Pre[n2*NDIV + dv2], Pim[n2*NDIV + dv2]);
  }
}

// ---------------- K0a: rc = c*r (per l,div,n), cpx = c*(1+k11) ----------------
__global__ __launch_bounds__(256) void ssm_k0a(
    const float* __restrict__ Lre, const float* __restrict__ Lim,
    const float* __restrict__ Pre, const float* __restrict__ Pim,
    const float* __restrict__ step, float2* __restrict__ rc, float2* __restrict__ cpx) {
  int idx = blockIdx.x * 256 + threadIdx.x;     // 16384 = 2048 * 8
  int l = idx & (LSEQ - 1);
  int dv = idx >> 11;
  double s = (double)expf(step[0]);
  float angf = -6.2831855f * ((float)l * (1.0f/2048.0f));
  double si, co;
  sincos((double)angf, &si, &co);
  cplxd om    = {co, si};
  cplxd one_p = {1.0 + om.x,  om.y};
  double ts = 2.0 / s;
  cplxd g = cdivd({ts*(1.0 - om.x), ts*(-om.y)}, one_p);
  cplxd c = cdivd({2.0, 0.0}, one_p);
  cplxd k11 = {0.0, 0.0};
  float2* rcrow = rc + ((size_t)dv*LSEQ + l)*NM;
  for (int n = 0; n < NM; n++) {
    float lre = fminf(Lre[n*NDIV+dv], -0.0001f);
    float lim = Lim[n*NDIV+dv];
    cplxd den = {g.x - (double)lre, g.y - (double)lim};
    cplxd r   = cdivd({1.0, 0.0}, den);
    cplxd rcv = cmuld(c, r);
    rcrow[n] = make_float2((float)rcv.x, (float)rcv.y);
    double pr = (double)Pre[n*NDIV+dv], pi = (double)Pim[n*NDIV+dv];
    double p2 = pr*pr + pi*pi;                  // conj(p)*p is real
    k11.x += p2 * rcv.x; k11.y += p2 * rcv.y;
  }
  cpx[(size_t)dv*LSEQ + l] = make_float2((float)(c.x + k11.x), (float)(c.y + k11.y));
}

// ---------------- K0b: A1 = (c*k01)/cpx, k10c = c*k10 (coalesced CT/BT/PT) ----------------
__global__ __launch_bounds__(256) void ssm_k0b(
    const float2* __restrict__ PT, const float2* __restrict__ CT,
    const float2* __restrict__ BT, const float2* __restrict__ rc,
    const float2* __restrict__ cpx, float2* __restrict__ A1, float2* __restrict__ k10c) {
  int dv = blockIdx.y;
  int l0 = blockIdx.x * 4;
  __shared__ float2 rcs[4][NM];
  __shared__ float2 ps[NM];
  int tid = threadIdx.x;
  { int q = tid; rcs[q>>6][q&63] = rc[((size_t)dv*LSEQ + l0 + (q>>6))*NM + (q&63)]; }
  if (tid < NM) ps[tid] = PT[dv*NM + tid];
  __syncthreads();
  int ll = tid >> 6, idx = tid & 63;
  int l = l0 + ll;
  float k01r=0.f, k01i=0.f, k10r=0.f, k10i=0.f;
  const float2* CTd = CT + (size_t)dv*NM*HD;
  const float2* BTd = BT + (size_t)dv*NM*HD;
  for (int n = 0; n < NM; n++) {
    float2 rv = rcs[ll][n];
    float2 pv = ps[n];
    float2 cv = CTd[n*HD + idx];                // conj(C)[idx][n], coalesced
    float tr = cv.x*rv.x - cv.y*rv.y, ti = cv.x*rv.y + cv.y*rv.x;
    k01r += tr*pv.x - ti*pv.y; k01i += tr*pv.y + ti*pv.x;
    float2 bv = BTd[n*HD + idx];                // B[n][idx], coalesced
    float ur = pv.x*rv.x + pv.y*rv.y;           // conj(p)*rv
    float ui = pv.x*rv.y - pv.y*rv.x;
    k10r += ur*bv.x - ui*bv.y; k10i += ur*bv.y + ui*bv.x;
  }
  float2 wv = cpx[(size_t)dv*LSEQ + l];
  float inv = 1.0f / (wv.x*wv.x + wv.y*wv.y);
  A1  [((size_t)dv*LSEQ + l)*HD + idx] = make_float2((k01r*wv.x + k01i*wv.y)*inv,
                                                     (k01i*wv.x - k01r*wv.y)*inv);
  k10c[((size_t)dv*LSEQ + l)*HD + idx] = make_float2(k10r, k10i);
}

// ---------------- Ku: u (b,l,512) -> ut[div][b][h][l] ----------------
__global__ __launch_bounds__(256) void ssm_ku(const float* __restrict__ u, float* __restrict__ ut) {
  __shared__ float s[16][513];
  int b  = blockIdx.x >> 7;
  int l0 = (blockIdx.x & 127) << 4;
  int tid = threadIdx.x;
  for (int q = tid; q < 16*512; q += 256) {
    int ll = q >> 9, dd = q & 511;
    s[ll][dd] = u[((size_t)b*LSEQ + l0 + ll)*512 + dd];
  }
  __syncthreads();
  for (int q = tid; q < 16*512; q += 256) {
    int d = q >> 4, ll = q & 15;
    int dvv = d & 7, h = d >> 3;
    ut[(((size_t)(dvv*NB + b))*HD + h)*LSEQ + l0 + ll] = s[ll][d];
  }
}

// ---------------- K3: per div: ud[c][f] = rfft_4096(pad(ut row)) ----------------
__global__ __launch_bounds__(256) void ssm_k3(const float* __restrict__ ut, float2* __restrict__ ud, int dv) {
  __shared__ float2 X[2048];
  __shared__ float2 TW[1024];
  int tid = threadIdx.x;
  int c = blockIdx.x;                           // 0..511 = b*64 + h
  const float2* src = (const float2*)(ut + ((size_t)dv*512 + c) * LSEQ);
  float2* dst = ud + (size_t)c * NF;
  build_tw(TW);
  for (int p = tid; p < 2048; p += 256)
    X[p] = (p < 1024) ? src[p] : make_float2(0.f, 0.f);   // z[t]=x[2t]+i x[2t+1]
  fft2048_dif<-1>(X, TW);
  __syncthreads();
  for (int f = tid; f <= 2048; f += 256) {
    int fa = f & 2047, fb = (2048 - f) & 2047;
    float2 Zf = X[__brev((unsigned)fa) >> 21];
    float2 Zm = X[__brev((unsigned)fb) >> 21];
    float Ex = (Zf.x + Zm.x)*0.5f, Ey = (Zf.y - Zm.y)*0.5f;
    float Dx = Zf.x - Zm.x,        Dy = Zf.y + Zm.y;
    float Ox = Dy*0.5f, Oy = -Dx*0.5f;                     // (Zf-conj(Zm))/(2i)
    float s, c2;
    __sincosf(-6.28318530717958647f * (float)f * (1.0f/4096.0f), &s, &c2);
    float WOx = Ox*c2 - Oy*s, WOy = Ox*s + Oy*c2;
    dst[f] = make_float2(Ex + WOx, Ey + WOy);
  }
}

// ---------------- K1: at_roots for (div, i-half), written chain-major ----------------
__global__ __launch_bounds__(256) void ssm_k1(
    const float2* __restrict__ CT, const float2* __restrict__ BT,
    const float2* __restrict__ rc, const float2* __restrict__ A1,
    const float2* __restrict__ k10c, float2* __restrict__ big,
    int dv, int iBase) {
  __shared__ float2 CC[NM][IH];     // conj(C)[iBase+il][n]  (16KB)
  __shared__ float2 BB[NM][HD];     // B[n][j]               (32KB)
  __shared__ float2 rcs[8][NM+1];   // 8 l's (padded)        (4KB)
  int tid = threadIdx.x;
  int l0 = blockIdx.x * 8;
  const float2* CTd = CT + (size_t)dv*NM*HD;
  const float2* BTd = BT + (size_t)dv*NM*HD;
  for (int q = tid; q < NM*IH; q += 256) {
    int n = q >> 5, il = q & 31;
    CC[n][il] = CTd[n*HD + iBase + il];         // coalesced
  }
  for (int q = tid; q < NM*HD; q += 256) {
    int n = q >> 6, j = q & 63;
    BB[n][j] = BTd[n*HD + j];                   // coalesced
  }
  for (int q = tid; q < 8*NM; q += 256) {
    int ll = q >> 6, n = q & 63;
    rcs[ll][n] = rc[((size_t)dv*LSEQ + l0 + ll)*NM + n];
  }
  __syncthreads();
  int lq = tid & 7;           // adjacent lanes = adjacent l (coalesced writes)
  int tile = tid >> 3;        // 32 tiles
  int ti = (tile >> 3) * 8;   // iloc base: 0/8/16/24, 8 consecutive i
  int tj = tile & 7;          // j = tj + 8*b (conflict-free BB reads)
  int l = l0 + lq;
  float2 acc[8][8];
  #pragma unroll
  for (int a = 0; a < 8; a++)
    #pragma unroll
    for (int b = 0; b < 8; b++) acc[a][b] = make_float2(0.f, 0.f);
  for (int n = 0; n < NM; n++) {
    float2 rv = rcs[lq][n];
    float2 uu[8];
    #pragma unroll
    for (int a = 0; a < 8; a++) {
      float2 cv = CC[n][ti+a];
      uu[a] = make_float2(cv.x*rv.x - cv.y*rv.y, cv.x*rv.y + cv.y*rv.x);
    }
    #pragma unroll
    for (int b = 0; b < 8; b++) {
      float2 bv = BB[n][tj + 8*b];
      #pragma unroll
      for (int a = 0; a < 8; a++) {
        acc[a][b].x = fmaf(uu[a].x, bv.x, fmaf(-uu[a].y, bv.y, acc[a][b].x));
        acc[a][b].y = fmaf(uu[a].x, bv.y, fmaf( uu[a].y, bv.x, acc[a][b].y));
      }
    }
  }
  const float2* A1row = A1   + ((size_t)dv*LSEQ + l)*HD;
  const float2* kqrow = k10c + ((size_t)dv*LSEQ + l)*HD;
  float2 ua[8], kb[8];
  #pragma unroll
  for (int a = 0; a < 8; a++) ua[a] = A1row[iBase + ti + a];
  #pragma unroll
  for (int b = 0; b < 8; b++) kb[b] = kqrow[tj + 8*b];
  #pragma unroll
  for (int a = 0; a < 8; a++)
    #pragma unroll
    for (int b = 0; b < 8; b++) {
      acc[a][b].x -= ua[a].x*kb[b].x - ua[a].y*kb[b].y;
      acc[a][b].y -= ua[a].x*kb[b].y + ua[a].y*kb[b].x;
    }
  #pragma unroll
  for (int a = 0; a < 8; a++)
    #pragma unroll
    for (int b = 0; b < 8; b++)
      big[((size_t)((ti+a)*64 + tj + 8*b))*NF + l] = acc[a][b];
}

// ---------------- K2: in-place per chain: art row (2048) -> Kd row (2049) ----------------
__global__ __launch_bounds__(256) void ssm_k2(float2* __restrict__ big) {
  __shared__ float2 X[2048];
  __shared__ float2 TW[1024];
  int tid = threadIdx.x;
  float2* row = big + (size_t)blockIdx.x * NF;
  build_tw(TW);
  for (int p = tid; p < 2048; p += 256) X[p] = row[p];
  __syncthreads();
  // even bins X4096[2l] = (ar[l] + conj(ar[(2048-l)%2048]))/2
  float2 ev[4];
  #pragma unroll
  for (int k = 0; k < 4; k++) {
    int l = tid + 256*k;                         // l in [0,1024)
    float2 a = X[l], b = X[(2048 - l) & 2047];
    ev[k] = make_float2((a.x+b.x)*0.5f, (a.y-b.y)*0.5f);
  }
  float ev1024 = X[1024].x;                      // bin 2048 = Re(ar[1024])
  // K = Re(ifft(ar)) (scale 1/2048), modulate by e^{-i*pi*t/2048}
  fft2048_dif<1>(X, TW);
  __syncthreads();
  const float sc = 1.0f/2048.0f;
  for (int p = tid; p < 2048; p += 256) {
    int t = (int)(__brev((unsigned)p) >> 21);
    float kr = X[p].x * sc;
    float s, c;
    __sincosf(-3.14159265358979324f * (float)t * (1.0f/2048.0f), &s, &c);
    X[p] = make_float2(kr*c, kr*s);
  }
  fft2048_dit<-1>(X, TW);   // odd bins: X[k] = X4096[2k+1], natural order
  __syncthreads();
  #pragma unroll
  for (int k = 0; k < 4; k++) { int l = tid + 256*k; X[1024 + l] = ev[k]; }
  __syncthreads();
  for (int e = tid; e < 2048; e += 256)
    row[e] = (e & 1) ? X[e >> 1] : X[1024 + (e >> 1)];
  if (tid == 0) row[2048] = make_float2(ev1024, 0.f);
}

// ---------------- K4: yf[b,f,iloc] = sum_j Kd[iloc*64+j][f] * ud[b*64+j][f] ----------------
__global__ __launch_bounds__(256) void ssm_k4(
    const float2* __restrict__ kdt, const float2* __restrict__ ud,
    float2* __restrict__ yf) {
  __shared__ float2 uds[NB][HD][8];   // 32KB
  int tid = threadIdx.x;
  int f0 = blockIdx.x * 8;
  for (int q = tid; q < NB*HD*8; q += 256) {
    int b = q >> 9, j = (q >> 3) & 63, ff = q & 7;
    int f = f0 + ff;
    uds[b][j][ff] = (f < NF) ? ud[((size_t)(b*HD + j))*NF + f] : make_float2(0.f, 0.f);
  }
  __syncthreads();
  int i = tid >> 3, fq = tid & 7;     // i = iloc in [0,32)
  int f = f0 + fq;
  if (f >= NF) return;
  float2 acc[NB];
  #pragma unroll
  for (int b = 0; b < NB; b++) acc[b] = make_float2(0.f, 0.f);
  for (int j = 0; j < HD; j++) {
    float2 kv = kdt[((size_t)(i*HD + j))*NF + f];
    #pragma unroll
    for (int b = 0; b < NB; b++) {
      float2 uv = uds[b][j][fq];
      acc[b].x += kv.x*uv.x - kv.y*uv.y;
      acc[b].y += kv.x*uv.y + kv.y*uv.x;
    }
  }
  #pragma unroll
  for (int b = 0; b < NB; b++)
    yf[((size_t)(b*IH + i))*NF + f] = acc[b];
}

// ---------------- K5: yt row = irfft_4096(yf row)[0:2048] ----------------
__global__ __launch_bounds__(256) void ssm_k5(const float2* __restrict__ yf,
                                              float* __restrict__ yt, int dv, int iBase) {
  __shared__ float2 X[2048];
  __shared__ float2 TW[1024];
  int tid = threadIdx.x;
  int b = blockIdx.x >> 5, iloc = blockIdx.x & 31;
  const float2* src = yf + (size_t)(b*IH + iloc) * NF;
  float2* dst = (float2*)(yt + (((size_t)(dv*NB + b))*HD + iBase + iloc) * LSEQ);
  build_tw(TW);
  for (int k = tid; k < 2048; k += 256) {
    float2 Xk = src[k];
    float2 Xm = src[2048 - k];
    float Ex = (Xk.x + Xm.x)*0.5f, Ey = (Xk.y - Xm.y)*0.5f;
    float Dx = Xk.x - Xm.x,        Dy = Xk.y + Xm.y;
    float s, c;
    __sincosf(6.28318530717958647f * (float)k * (1.0f/4096.0f), &s, &c);
    float Ox = 0.5f*(Dx*c - Dy*s);
    float Oy = 0.5f*(Dx*s + Dy*c);
    X[k] = make_float2(Ex - Oy, Ey + Ox);   // Z = E + i*O
  }
  fft2048_dif<1>(X, TW);
  __syncthreads();
  const float sc = 1.0f/2048.0f;
  for (int t = tid; t < 1024; t += 256) {
    int p = (int)(__brev((unsigned)t) >> 21);
    float2 z = X[p];
    dst[t] = make_float2(z.x*sc, z.y*sc);   // y[2t], y[2t+1]
  }
}

// ---------------- T2: yt[div][b][i][t] -> out[b][t][i*8+div] ----------------
__global__ __launch_bounds__(256) void ssm_t2(const float* __restrict__ yt, float* __restrict__ out) {
  __shared__ float s[512][17];
  int b  = blockIdx.x >> 7;
  int t0 = (blockIdx.x & 127) << 4;
  int tid = threadIdx.x;
  for (int q = tid; q < 512*16; q += 256) {
    int d = q >> 4, tt = q & 15;
    int dvv = d & 7, i = d >> 3;
    s[d][tt] = yt[(((size_t)(dvv*NB + b))*HD + i)*LSEQ + t0 + tt];
  }
  __syncthreads();
  for (int q = tid; q < 512*16; q += 256) {
    int tt = q >> 9, d = q & 511;
    out[((size_t)b*LSEQ + t0 + tt)*512 + d] = s[d][tt];
  }
}

// ---------------- host ----------------
extern "C" void kernel_launch(void* const* d_in, const int* in_sizes, int n_in,
                              void* d_out, int out_size, void* d_ws, size_t ws_size,
                              hipStream_t stream) {
  const float* u    = (const float*)d_in[0];
  const float* Lre  = (const float*)d_in[1];
  const float* Lim  = (const float*)d_in[2];
  const float* Pre  = (const float*)d_in[3];
  const float* Pim  = (const float*)d_in[4];
  const float* Bre  = (const float*)d_in[5];
  const float* Bim  = (const float*)d_in[6];
  const float* Cre  = (const float*)d_in[7];
  const float* Cim  = (const float*)d_in[8];
  const float* step = (const float*)d_in[9];
  float* out = (float*)d_out;

  char* w = (char*)d_ws;
  size_t off = 0;
  auto carve = [&](size_t bytes) -> void* {
    void* p = (void*)(w + off);
    off += (bytes + 255) & ~(size_t)255;
    return p;
  };
  float2* rc   = (float2*)carve((size_t)NDIV*LSEQ*NM*sizeof(float2));     // 8.39 MB
  float2* cpx  = (float2*)carve((size_t)NDIV*LSEQ*sizeof(float2));        // 0.13 MB
  float2* A1   = (float2*)carve((size_t)NDIV*LSEQ*HD*sizeof(float2));     // 8.39 MB
  float2* k10c = (float2*)carve((size_t)NDIV*LSEQ*HD*sizeof(float2));     // 8.39 MB
  float*  ut   = (float*) carve((size_t)NDIV*NB*HD*LSEQ*sizeof(float));   // 33.55 MB (later = yt)
  float2* big  = (float2*)carve((size_t)2048*NF*sizeof(float2));          // 33.57 MB (art/Kd, in-place)
  float2* ud   = (float2*)carve((size_t)512*NF*sizeof(float2));           // 8.39 MB (per div)
  float2* yf   = (float2*)carve((size_t)256*NF*sizeof(float2));           // 4.20 MB (per div-half)
  float2* CT   = (float2*)carve((size_t)NDIV*NM*HD*sizeof(float2));       // 256 KB
  float2* BT   = (float2*)carve((size_t)NDIV*NM*HD*sizeof(float2));       // 256 KB
  float2* PT   = (float2*)carve((size_t)NDIV*NM*sizeof(float2));          // 4 KB
  (void)in_sizes; (void)n_in; (void)out_size;
  if (ws_size < off) return;   // insufficient scratch -> leave out zeroed (diagnosable)

  ssm_kt<<<128, 256, 0, stream>>>(Cre, Cim, Bre, Bim, Pre, Pim, CT, BT, PT);
  ssm_k0a<<<64, 256, 0, stream>>>(Lre, Lim, Pre, Pim, step, rc, cpx);
  ssm_k0b<<<dim3(512, 8), 256, 0, stream>>>(PT, CT, BT, rc, cpx, A1, k10c);
  ssm_ku<<<1024, 256, 0, stream>>>(u, ut);
  for (int dv = 0; dv < NDIV; ++dv) {
    ssm_k3<<<512, 256, 0, stream>>>(ut, ud, dv);
    for (int ih = 0; ih < 2; ++ih) {
      int iBase = ih * IH;
      ssm_k1<<<256, 256, 0, stream>>>(CT, BT, rc, A1, k10c, big, dv, iBase);
      ssm_k2<<<2048, 256, 0, stream>>>(big);
      ssm_k4<<<257, 256, 0, stream>>>(big, ud, yf);
      ssm_k5<<<256, 256, 0, stream>>>(yf, ut, dv, iBase);
    }
  }
  ssm_t2<<<1024, 256, 0, stream>>>(ut, out);
}

// Round 4
// 1799.517 us; speedup vs baseline: 1.4658x; 1.2317x over previous
//
#include <hip/hip_runtime.h>
#include <math.h>

#define LSEQ 2048
#define NM   64     // N modes
#define HD   64     // H
#define NDIV 8
#define NB   8      // batch
#define NF   2049   // rfft bins of 4096
#define IH   32     // i-half size

// padded LDS slot: +1 float2 every 32 -> all FFT accesses <=2-way bank aliasing
#define SL(E) ((E) + ((E) >> 5))
#define FFT_BUF 2112   // SL(2047)=2110 < 2112

// ---------------- double complex helpers (precompute only) ----------------
struct cplxd { double x, y; };
__device__ __forceinline__ cplxd cmuld(cplxd a, cplxd b) {
  return {a.x*b.x - a.y*b.y, a.x*b.y + a.y*b.x};
}
__device__ __forceinline__ cplxd cdivd(cplxd a, cplxd b) {
  double inv = 1.0 / (b.x*b.x + b.y*b.y);
  return {(a.x*b.x + a.y*b.y)*inv, (a.y*b.x - a.x*b.y)*inv};
}

// ---------------- TW[m] = exp(-2*pi*i*m/2048), m=0..1023 ----------------
__device__ __forceinline__ void build_tw(float2* TW) {
  for (int m = threadIdx.x; m < 1024; m += 256) {
    float s, c;
    __sincosf(-6.28318530717958647f * (float)m * (1.0f/2048.0f), &s, &c);
    TW[m] = make_float2(c, s);
  }
}

// ---------------- Stockham radix-4 stage (N=2048, 256 threads) ----------------
// State invariant: flat[q*M + p] = DFT_M of subseq stride N/M offset q, at freq p.
// SIGN=-1 forward, +1 inverse (unscaled). Reads src[idx + v*512] (contiguous).
template<int SIGN, int M>
__device__ __forceinline__ void r4_stage(const float2* __restrict__ src,
                                         float2* __restrict__ dst,
                                         const float2* __restrict__ TW) {
  constexpr int L = 2048 / (4 * M);
  __syncthreads();
  #pragma unroll
  for (int t = 0; t < 2; t++) {
    int idx = (int)threadIdx.x + t * 256;      // [0,512)
    int q = idx / M;                            // compile-time M -> shift
    int p = idx & (M - 1);
    float2 a0 = src[SL(idx)];
    float2 a1 = src[SL(idx + 512)];
    float2 a2 = src[SL(idx + 1024)];
    float2 a3 = src[SL(idx + 1536)];
    float2 w = TW[p * L];                       // e^{-2pi i p/(4M)}
    float2 W1 = make_float2(w.x, (SIGN > 0) ? -w.y : w.y);
    float2 W2 = make_float2(W1.x*W1.x - W1.y*W1.y, 2.f*W1.x*W1.y);
    float2 W3 = make_float2(W2.x*W1.x - W2.y*W1.y, W2.x*W1.y + W2.y*W1.x);
    float2 b1 = make_float2(a1.x*W1.x - a1.y*W1.y, a1.x*W1.y + a1.y*W1.x);
    float2 b2 = make_float2(a2.x*W2.x - a2.y*W2.y, a2.x*W2.y + a2.y*W2.x);
    float2 b3 = make_float2(a3.x*W3.x - a3.y*W3.y, a3.x*W3.y + a3.y*W3.x);
    float2 e0 = make_float2(a0.x + b2.x, a0.y + b2.y);
    float2 e1 = make_float2(b1.x + b3.x, b1.y + b3.y);
    float2 d0 = make_float2(a0.x - b2.x, a0.y - b2.y);
    float2 d1 = make_float2(b1.x - b3.x, b1.y - b3.y);
    float2 o1, o3;
    if (SIGN < 0) { o1 = make_float2(d0.x + d1.y, d0.y - d1.x);   // d0 - i*d1
                    o3 = make_float2(d0.x - d1.y, d0.y + d1.x); } // d0 + i*d1
    else          { o1 = make_float2(d0.x - d1.y, d0.y + d1.x);
                    o3 = make_float2(d0.x + d1.y, d0.y - d1.x); }
    int ob = q * 4 * M + p;
    dst[SL(ob)]         = make_float2(e0.x + e1.x, e0.y + e1.y);
    dst[SL(ob + M)]     = o1;
    dst[SL(ob + 2*M)]   = make_float2(e0.x - e1.x, e0.y - e1.y);
    dst[SL(ob + 3*M)]   = o3;
  }
}

template<int SIGN>
__device__ __forceinline__ void r2_stage_final(const float2* __restrict__ src,
                                               float2* __restrict__ dst,
                                               const float2* __restrict__ TW) {
  __syncthreads();
  #pragma unroll
  for (int t = 0; t < 4; t++) {
    int p = (int)threadIdx.x + t * 256;        // [0,1024)
    float2 a = src[SL(p)], b = src[SL(p + 1024)];
    float2 w = TW[p];
    float wy = (SIGN > 0) ? -w.y : w.y;
    float2 wb = make_float2(b.x*w.x - b.y*wy, b.x*wy + b.y*w.x);
    dst[SL(p)]        = make_float2(a.x + wb.x, a.y + wb.y);
    dst[SL(p + 1024)] = make_float2(a.x - wb.x, a.y - wb.y);
  }
}

// Full 2048-pt FFT: natural in (b0) -> natural out (b0). Trailing barrier included.
template<int SIGN>
__device__ __forceinline__ void fft2048_st(float2* b0, float2* b1, const float2* TW) {
  r4_stage<SIGN,   1>(b0, b1, TW);
  r4_stage<SIGN,   4>(b1, b0, TW);
  r4_stage<SIGN,  16>(b0, b1, TW);
  r4_stage<SIGN,  64>(b1, b0, TW);
  r4_stage<SIGN, 256>(b0, b1, TW);
  r2_stage_final<SIGN>(b1, b0, TW);
  __syncthreads();
}

// ---------------- KT: params -> div-major coalesced layouts ----------------
__global__ __launch_bounds__(256) void ssm_kt(
    const float* __restrict__ Cre, const float* __restrict__ Cim,
    const float* __restrict__ Bre, const float* __restrict__ Bim,
    const float* __restrict__ Pre, const float* __restrict__ Pim,
    float2* __restrict__ CT, float2* __restrict__ BT, float2* __restrict__ PT) {
  int idx = blockIdx.x * 256 + threadIdx.x;   // 32768 = dv*4096 + n*64 + x
  int dv = idx >> 12, n = (idx >> 6) & 63, x = idx & 63;
  CT[idx] = make_float2(Cre[((size_t)x*NM + n)*NDIV + dv], -Cim[((size_t)x*NM + n)*NDIV + dv]);
  BT[idx] = make_float2(Bre[((size_t)n*HD + x)*NDIV + dv],  Bim[((size_t)n*HD + x)*NDIV + dv]);
  if (idx < NDIV*NM) {
    int dv2 = idx >> 6, n2 = idx & 63;
    PT[idx] = make_float2(Pre[n2*NDIV + dv2], Pim[n2*NDIV + dv2]);
  }
}

// ---------------- K0a: rc = c*r, cpx = c*(1+k11); 4 lanes per (l,dv) ----------------
__global__ __launch_bounds__(256) void ssm_k0a(
    const float* __restrict__ Lre, const float* __restrict__ Lim,
    const float* __restrict__ Pre, const float* __restrict__ Pim,
    const float* __restrict__ step, float2* __restrict__ rc, float2* __restrict__ cpx) {
  int idx = blockIdx.x * 256 + threadIdx.x;     // 65536 = (dv*2048 + l)*4 + qn
  int qn = idx & 3;
  int rest = idx >> 2;
  int l = rest & (LSEQ - 1);
  int dv = rest >> 11;
  double s = (double)expf(step[0]);
  float angf = -6.2831855f * ((float)l * (1.0f/2048.0f));
  double si, co;
  sincos((double)angf, &si, &co);
  cplxd om    = {co, si};
  cplxd one_p = {1.0 + om.x,  om.y};
  double ts = 2.0 / s;
  cplxd g = cdivd({ts*(1.0 - om.x), ts*(-om.y)}, one_p);
  cplxd c = cdivd({2.0, 0.0}, one_p);
  double k11x = 0.0, k11y = 0.0;
  float2* rcrow = rc + ((size_t)dv*LSEQ + l)*NM;
  for (int u = 0; u < 16; u++) {
    int n = qn*16 + u;
    float lre = fminf(Lre[n*NDIV+dv], -0.0001f);
    float lim = Lim[n*NDIV+dv];
    cplxd den = {g.x - (double)lre, g.y - (double)lim};
    cplxd r   = cdivd({1.0, 0.0}, den);
    cplxd rcv = cmuld(c, r);
    rcrow[n] = make_float2((float)rcv.x, (float)rcv.y);
    double pr = (double)Pre[n*NDIV+dv], pi = (double)Pim[n*NDIV+dv];
    double p2 = pr*pr + pi*pi;                  // conj(p)*p is real
    k11x += p2 * rcv.x; k11y += p2 * rcv.y;
  }
  k11x += __shfl_xor(k11x, 1); k11y += __shfl_xor(k11y, 1);
  k11x += __shfl_xor(k11x, 2); k11y += __shfl_xor(k11y, 2);
  if (qn == 0)
    cpx[(size_t)dv*LSEQ + l] = make_float2((float)(c.x + k11x), (float)(c.y + k11y));
}

// ---------------- K0b: A1 = (c*k01)/cpx, k10c = c*k10; 16 l per block, n-halves ----------------
__global__ __launch_bounds__(256) void ssm_k0b(
    const float2* __restrict__ PT, const float2* __restrict__ CT,
    const float2* __restrict__ BT, const float2* __restrict__ rc,
    const float2* __restrict__ cpx, float2* __restrict__ A1, float2* __restrict__ k10c) {
  int dv = blockIdx.y;
  int l0 = blockIdx.x * 16;
  __shared__ float2 CTs[32][64];    // 16 KB  [n'][i]
  __shared__ float2 BTs[32][64];    // 16 KB  [n'][j]
  __shared__ float2 rcs[16][64];    // 8 KB
  __shared__ float2 ps[64];
  int tid = threadIdx.x;
  for (int q = tid; q < 16*64; q += 256) {
    int ll = q >> 6, n = q & 63;
    rcs[ll][n] = rc[((size_t)dv*LSEQ + l0 + ll)*NM + n];
  }
  if (tid < NM) ps[tid] = PT[dv*NM + tid];
  int lg = tid >> 6, idx = tid & 63;
  float k01r[4], k01i[4], k10r[4], k10i[4];
  #pragma unroll
  for (int g = 0; g < 4; g++) { k01r[g]=0.f; k01i[g]=0.f; k10r[g]=0.f; k10i[g]=0.f; }
  const float2* CTd = CT + (size_t)dv*NM*HD;
  const float2* BTd = BT + (size_t)dv*NM*HD;
  for (int nh = 0; nh < 2; nh++) {
    __syncthreads();
    for (int q = tid; q < 32*64; q += 256) {
      int n = q >> 6, x = q & 63;
      CTs[n][x] = CTd[(nh*32 + n)*HD + x];
      BTs[n][x] = BTd[(nh*32 + n)*HD + x];
    }
    __syncthreads();
    for (int np = 0; np < 32; np++) {
      int n = nh*32 + np;
      float2 cv = CTs[np][idx];
      float2 bv = BTs[np][idx];
      float2 pv = ps[n];
      #pragma unroll
      for (int g = 0; g < 4; g++) {
        float2 rv = rcs[g*4 + lg][n];
        float tr = cv.x*rv.x - cv.y*rv.y, ti = cv.x*rv.y + cv.y*rv.x;
        k01r[g] += tr*pv.x - ti*pv.y; k01i[g] += tr*pv.y + ti*pv.x;
        float ur = pv.x*rv.x + pv.y*rv.y;           // conj(p)*rv
        float ui = pv.x*rv.y - pv.y*rv.x;
        k10r[g] += ur*bv.x - ui*bv.y; k10i[g] += ur*bv.y + ui*bv.x;
      }
    }
  }
  #pragma unroll
  for (int g = 0; g < 4; g++) {
    int l = l0 + g*4 + lg;
    float2 wv = cpx[(size_t)dv*LSEQ + l];
    float inv = 1.0f / (wv.x*wv.x + wv.y*wv.y);
    A1  [((size_t)dv*LSEQ + l)*HD + idx] = make_float2((k01r[g]*wv.x + k01i[g]*wv.y)*inv,
                                                       (k01i[g]*wv.x - k01r[g]*wv.y)*inv);
    k10c[((size_t)dv*LSEQ + l)*HD + idx] = make_float2(k10r[g], k10i[g]);
  }
}

// ---------------- Ku: u (b,l,512) -> ut[div][b][h][l] ----------------
__global__ __launch_bounds__(256) void ssm_ku(const float* __restrict__ u, float* __restrict__ ut) {
  __shared__ float s[16][513];
  int b  = blockIdx.x >> 7;
  int l0 = (blockIdx.x & 127) << 4;
  int tid = threadIdx.x;
  for (int q = tid; q < 16*512; q += 256) {
    int ll = q >> 9, dd = q & 511;
    s[ll][dd] = u[((size_t)b*LSEQ + l0 + ll)*512 + dd];
  }
  __syncthreads();
  for (int q = tid; q < 16*512; q += 256) {
    int d = q >> 4, ll = q & 15;
    int dvv = d & 7, h = d >> 3;
    ut[(((size_t)(dvv*NB + b))*HD + h)*LSEQ + l0 + ll] = s[ll][d];
  }
}

// ---------------- K3: per div: ud[c][f] = rfft_4096(pad(ut row)) ----------------
__global__ __launch_bounds__(256) void ssm_k3(const float* __restrict__ ut, float2* __restrict__ ud, int dv) {
  __shared__ float2 b0[FFT_BUF];
  __shared__ float2 b1[FFT_BUF];
  __shared__ float2 TW[1024];
  int tid = threadIdx.x;
  int c = blockIdx.x;                           // 0..511 = b*64 + h
  const float2* src = (const float2*)(ut + ((size_t)dv*512 + c) * LSEQ);
  float2* dst = ud + (size_t)c * NF;
  build_tw(TW);
  for (int p = tid; p < 2048; p += 256)
    b0[SL(p)] = (p < 1024) ? src[p] : make_float2(0.f, 0.f);   // z[t]=x[2t]+i x[2t+1]
  fft2048_st<-1>(b0, b1, TW);                                   // Z natural order
  for (int f = tid; f <= 2048; f += 256) {
    int fa = f & 2047, fb = (2048 - f) & 2047;
    float2 Zf = b0[SL(fa)];
    float2 Zm = b0[SL(fb)];
    float Ex = (Zf.x + Zm.x)*0.5f, Ey = (Zf.y - Zm.y)*0.5f;
    float Dx = Zf.x - Zm.x,        Dy = Zf.y + Zm.y;
    float Ox = Dy*0.5f, Oy = -Dx*0.5f;                     // (Zf-conj(Zm))/(2i)
    float s, c2;
    __sincosf(-6.28318530717958647f * (float)f * (1.0f/4096.0f), &s, &c2);
    float WOx = Ox*c2 - Oy*s, WOy = Ox*s + Oy*c2;
    dst[f] = make_float2(Ex + WOx, Ey + WOy);
  }
}

// ---------------- K1: at_roots for (div, i-half, j-half), chain-major ----------------
__global__ __launch_bounds__(256) void ssm_k1(
    const float2* __restrict__ CT, const float2* __restrict__ BT,
    const float2* __restrict__ rc, const float2* __restrict__ A1,
    const float2* __restrict__ k10c, float2* __restrict__ big,
    int dv, int iBase) {
  __shared__ float2 CC[NM][IH];     // conj(C)[iBase+il][n]   16 KB
  __shared__ float2 BB[NM][IH];     // B[n][j0+jl]            16 KB
  __shared__ float2 rcs[8][NM+1];   // 8 l's (padded)         4.1 KB
  int tid = threadIdx.x;
  int lg = blockIdx.x >> 1, jh = blockIdx.x & 1;
  int l0 = lg * 8, j0 = jh * 32;
  const float2* CTd = CT + (size_t)dv*NM*HD;
  const float2* BTd = BT + (size_t)dv*NM*HD;
  for (int q = tid; q < NM*IH; q += 256) {
    int n = q >> 5, x = q & 31;
    CC[n][x] = CTd[n*HD + iBase + x];
    BB[n][x] = BTd[n*HD + j0 + x];
  }
  for (int q = tid; q < 8*NM; q += 256) {
    int ll = q >> 6, n = q & 63;
    rcs[ll][n] = rc[((size_t)dv*LSEQ + l0 + ll)*NM + n];
  }
  __syncthreads();
  int lq = tid & 7;           // adjacent lanes = adjacent l (64B store chunks)
  int tile = tid >> 3;        // 32 tiles
  int ti = (tile >> 3) * 8;   // iloc base: 0/8/16/24
  int tj = tile & 7;          // j = j0 + tj + 8*b
  int l = l0 + lq;
  float2 acc[8][4];
  #pragma unroll
  for (int a = 0; a < 8; a++)
    #pragma unroll
    for (int b = 0; b < 4; b++) acc[a][b] = make_float2(0.f, 0.f);
  for (int n = 0; n < NM; n++) {
    float2 rv = rcs[lq][n];
    float2 uu[8];
    #pragma unroll
    for (int a = 0; a < 8; a++) {
      float2 cv = CC[n][ti+a];
      uu[a] = make_float2(cv.x*rv.x - cv.y*rv.y, cv.x*rv.y + cv.y*rv.x);
    }
    #pragma unroll
    for (int b = 0; b < 4; b++) {
      float2 bv = BB[n][tj + 8*b];
      #pragma unroll
      for (int a = 0; a < 8; a++) {
        acc[a][b].x = fmaf(uu[a].x, bv.x, fmaf(-uu[a].y, bv.y, acc[a][b].x));
        acc[a][b].y = fmaf(uu[a].x, bv.y, fmaf( uu[a].y, bv.x, acc[a][b].y));
      }
    }
  }
  const float2* A1row = A1   + ((size_t)dv*LSEQ + l)*HD;
  const float2* kqrow = k10c + ((size_t)dv*LSEQ + l)*HD;
  float2 ua[8], kb[4];
  #pragma unroll
  for (int a = 0; a < 8; a++) ua[a] = A1row[iBase + ti + a];
  #pragma unroll
  for (int b = 0; b < 4; b++) kb[b] = kqrow[j0 + tj + 8*b];
  #pragma unroll
  for (int a = 0; a < 8; a++)
    #pragma unroll
    for (int b = 0; b < 4; b++) {
      acc[a][b].x -= ua[a].x*kb[b].x - ua[a].y*kb[b].y;
      acc[a][b].y -= ua[a].x*kb[b].y + ua[a].y*kb[b].x;
    }
  #pragma unroll
  for (int a = 0; a < 8; a++)
    #pragma unroll
    for (int b = 0; b < 4; b++)
      big[((size_t)((ti+a)*64 + j0 + tj + 8*b))*NF + l] = acc[a][b];
}

// ---------------- K2: in-place per chain: art row (2048) -> Kd row (2049) ----------------
__global__ __launch_bounds__(256) void ssm_k2(float2* __restrict__ big) {
  __shared__ float2 b0[FFT_BUF];
  __shared__ float2 b1[FFT_BUF];
  __shared__ float2 TW[1024];
  int tid = threadIdx.x;
  float2* row = big + (size_t)blockIdx.x * NF;
  build_tw(TW);
  for (int p = tid; p < 2048; p += 256) b0[SL(p)] = row[p];
  __syncthreads();
  // even bins X4096[2l] = (ar[l] + conj(ar[(2048-l)%2048]))/2
  float2 ev[4];
  #pragma unroll
  for (int k = 0; k < 4; k++) {
    int l = tid + 256*k;                         // l in [0,1024)
    float2 a = b0[SL(l)], b = b0[SL((2048 - l) & 2047)];
    ev[k] = make_float2((a.x+b.x)*0.5f, (a.y-b.y)*0.5f);
  }
  float ev1024 = b0[SL(1024)].x;                 // bin 2048 = Re(ar[1024])
  // K = Re(ifft(ar)) (scale 1/2048), modulate by e^{-i*pi*t/2048}
  fft2048_st<1>(b0, b1, TW);                     // natural t order
  const float sc = 1.0f/2048.0f;
  for (int t = tid; t < 2048; t += 256) {
    float kr = b0[SL(t)].x * sc;
    float s, c;
    __sincosf(-3.14159265358979324f * (float)t * (1.0f/2048.0f), &s, &c);
    b0[SL(t)] = make_float2(kr*c, kr*s);
  }
  fft2048_st<-1>(b0, b1, TW);   // odd bins: b0[k] = X4096[2k+1], natural order
  // stash evens into b1 (dead) for one coalesced interleaved write pass
  #pragma unroll
  for (int k = 0; k < 4; k++) { int l = tid + 256*k; b1[SL(l)] = ev[k]; }
  __syncthreads();
  for (int e = tid; e < 2048; e += 256)
    row[e] = (e & 1) ? b0[SL(e >> 1)] : b1[SL(e >> 1)];
  if (tid == 0) row[2048] = make_float2(ev1024, 0.f);
}

// ---------------- K4: yf[b,f,iloc] = sum_j Kd[iloc*64+j][f] * ud[b*64+j][f] ----------------
__global__ __launch_bounds__(256) void ssm_k4(
    const float2* __restrict__ kdt, const float2* __restrict__ ud,
    float2* __restrict__ yf) {
  __shared__ float2 uds[NB][HD][8];   // 32KB
  int tid = threadIdx.x;
  int f0 = blockIdx.x * 8;
  for (int q = tid; q < NB*HD*8; q += 256) {
    int b = q >> 9, j = (q >> 3) & 63, ff = q & 7;
    int f = f0 + ff;
    uds[b][j][ff] = (f < NF) ? ud[((size_t)(b*HD + j))*NF + f] : make_float2(0.f, 0.f);
  }
  __syncthreads();
  int i = tid >> 3, fq = tid & 7;     // i = iloc in [0,32)
  int f = f0 + fq;
  if (f >= NF) return;
  float2 acc[NB];
  #pragma unroll
  for (int b = 0; b < NB; b++) acc[b] = make_float2(0.f, 0.f);
  for (int j = 0; j < HD; j++) {
    float2 kv = kdt[((size_t)(i*HD + j))*NF + f];
    #pragma unroll
    for (int b = 0; b < NB; b++) {
      float2 uv = uds[b][j][fq];
      acc[b].x += kv.x*uv.x - kv.y*uv.y;
      acc[b].y += kv.x*uv.y + kv.y*uv.x;
    }
  }
  #pragma unroll
  for (int b = 0; b < NB; b++)
    yf[((size_t)(b*IH + i))*NF + f] = acc[b];
}

// ---------------- K5: yt row = irfft_4096(yf row)[0:2048] ----------------
__global__ __launch_bounds__(256) void ssm_k5(const float2* __restrict__ yf,
                                              float* __restrict__ yt, int dv, int iBase) {
  __shared__ float2 b0[FFT_BUF];
  __shared__ float2 b1[FFT_BUF];
  __shared__ float2 TW[1024];
  int tid = threadIdx.x;
  int b = blockIdx.x >> 5, iloc = blockIdx.x & 31;
  const float2* src = yf + (size_t)(b*IH + iloc) * NF;
  float2* dst = (float2*)(yt + (((size_t)(dv*NB + b))*HD + iBase + iloc) * LSEQ);
  build_tw(TW);
  for (int k = tid; k < 2048; k += 256) {
    float2 Xk = src[k];
    float2 Xm = src[2048 - k];
    float Ex = (Xk.x + Xm.x)*0.5f, Ey = (Xk.y - Xm.y)*0.5f;
    float Dx = Xk.x - Xm.x,        Dy = Xk.y + Xm.y;
    float s, c;
    __sincosf(6.28318530717958647f * (float)k * (1.0f/4096.0f), &s, &c);
    float Ox = 0.5f*(Dx*c - Dy*s);
    float Oy = 0.5f*(Dx*s + Dy*c);
    b0[SL(k)] = make_float2(Ex - Oy, Ey + Ox);   // Z = E + i*O
  }
  fft2048_st<1>(b0, b1, TW);                     // natural t order
  const float sc = 1.0f/2048.0f;
  for (int t = tid; t < 1024; t += 256) {
    float2 z = b0[SL(t)];
    dst[t] = make_float2(z.x*sc, z.y*sc);        // y[2t], y[2t+1]
  }
}

// ---------------- T2: yt[div][b][i][t] -> out[b][t][i*8+div] ----------------
__global__ __launch_bounds__(256) void ssm_t2(const float* __restrict__ yt, float* __restrict__ out) {
  __shared__ float s[512][17];
  int b  = blockIdx.x >> 7;
  int t0 = (blockIdx.x & 127) << 4;
  int tid = threadIdx.x;
  for (int q = tid; q < 512*16; q += 256) {
    int d = q >> 4, tt = q & 15;
    int dvv = d & 7, i = d >> 3;
    s[d][tt] = yt[(((size_t)(dvv*NB + b))*HD + i)*LSEQ + t0 + tt];
  }
  __syncthreads();
  for (int q = tid; q < 512*16; q += 256) {
    int tt = q >> 9, d = q & 511;
    out[((size_t)b*LSEQ + t0 + tt)*512 + d] = s[d][tt];
  }
}

// ---------------- host ----------------
extern "C" void kernel_launch(void* const* d_in, const int* in_sizes, int n_in,
                              void* d_out, int out_size, void* d_ws, size_t ws_size,
                              hipStream_t stream) {
  const float* u    = (const float*)d_in[0];
  const float* Lre  = (const float*)d_in[1];
  const float* Lim  = (const float*)d_in[2];
  const float* Pre  = (const float*)d_in[3];
  const float* Pim  = (const float*)d_in[4];
  const float* Bre  = (const float*)d_in[5];
  const float* Bim  = (const float*)d_in[6];
  const float* Cre  = (const float*)d_in[7];
  const float* Cim  = (const float*)d_in[8];
  const float* step = (const float*)d_in[9];
  float* out = (float*)d_out;

  char* w = (char*)d_ws;
  size_t off = 0;
  auto carve = [&](size_t bytes) -> void* {
    void* p = (void*)(w + off);
    off += (bytes + 255) & ~(size_t)255;
    return p;
  };
  float2* rc   = (float2*)carve((size_t)NDIV*LSEQ*NM*sizeof(float2));     // 8.39 MB
  float2* cpx  = (float2*)carve((size_t)NDIV*LSEQ*sizeof(float2));        // 0.13 MB
  float2* A1   = (float2*)carve((size_t)NDIV*LSEQ*HD*sizeof(float2));     // 8.39 MB
  float2* k10c = (float2*)carve((size_t)NDIV*LSEQ*HD*sizeof(float2));     // 8.39 MB
  float*  ut   = (float*) carve((size_t)NDIV*NB*HD*LSEQ*sizeof(float));   // 33.55 MB (later = yt)
  float2* big  = (float2*)carve((size_t)2048*NF*sizeof(float2));          // 33.57 MB (art/Kd, in-place)
  float2* ud   = (float2*)carve((size_t)512*NF*sizeof(float2));           // 8.39 MB (per div)
  float2* yf   = (float2*)carve((size_t)256*NF*sizeof(float2));           // 4.20 MB (per div-half)
  float2* CT   = (float2*)carve((size_t)NDIV*NM*HD*sizeof(float2));       // 256 KB
  float2* BT   = (float2*)carve((size_t)NDIV*NM*HD*sizeof(float2));       // 256 KB
  float2* PT   = (float2*)carve((size_t)NDIV*NM*sizeof(float2));          // 4 KB
  (void)in_sizes; (void)n_in; (void)out_size;
  if (ws_size < off) return;   // insufficient scratch -> leave out zeroed (diagnosable)

  ssm_kt<<<128, 256, 0, stream>>>(Cre, Cim, Bre, Bim, Pre, Pim, CT, BT, PT);
  ssm_k0a<<<256, 256, 0, stream>>>(Lre, Lim, Pre, Pim, step, rc, cpx);
  ssm_k0b<<<dim3(128, 8), 256, 0, stream>>>(PT, CT, BT, rc, cpx, A1, k10c);
  ssm_ku<<<1024, 256, 0, stream>>>(u, ut);
  for (int dv = 0; dv < NDIV; ++dv) {
    ssm_k3<<<512, 256, 0, stream>>>(ut, ud, dv);
    for (int ih = 0; ih < 2; ++ih) {
      int iBase = ih * IH;
      ssm_k1<<<512, 256, 0, stream>>>(CT, BT, rc, A1, k10c, big, dv, iBase);
      ssm_k2<<<2048, 256, 0, stream>>>(big);
      ssm_k4<<<257, 256, 0, stream>>>(big, ud, yf);
      ssm_k5<<<256, 256, 0, stream>>>(yf, ut, dv, iBase);
    }
  }
  ssm_t2<<<1024, 256, 0, stream>>>(ut, out);
}

// Round 5
// 1552.884 us; speedup vs baseline: 1.6986x; 1.1588x over previous
//
#include <hip/hip_runtime.h>
#include <hip/hip_bf16.h>
#include <math.h>

#define LSEQ 2048
#define NM   64     // N modes
#define HD   64     // H
#define NDIV 8
#define NB   8      // batch
#define NF   2049   // rfft bins of 4096

// padded LDS slot: +1 float2 every 32 -> all FFT accesses <=2-way bank aliasing
#define SL(E) ((E) + ((E) >> 5))
#define FFT_BUF 2112   // SL(2047)=2110 < 2112

// ---------------- bf16x2 complex pack/unpack ----------------
__device__ __forceinline__ unsigned pack_c(float2 v) {
  __hip_bfloat162 h = __float22bfloat162_rn(v);
  return *reinterpret_cast<unsigned*>(&h);
}
__device__ __forceinline__ float2 unpack_c(unsigned u) {
  __hip_bfloat162 h = *reinterpret_cast<__hip_bfloat162*>(&u);
  return __bfloat1622float2(h);
}

// ---------------- double complex helpers (precompute only) ----------------
struct cplxd { double x, y; };
__device__ __forceinline__ cplxd cmuld(cplxd a, cplxd b) {
  return {a.x*b.x - a.y*b.y, a.x*b.y + a.y*b.x};
}
__device__ __forceinline__ cplxd cdivd(cplxd a, cplxd b) {
  double inv = 1.0 / (b.x*b.x + b.y*b.y);
  return {(a.x*b.x + a.y*b.y)*inv, (a.y*b.x - a.x*b.y)*inv};
}

// ---------------- TW[m] = exp(-2*pi*i*m/2048), m=0..1023 ----------------
__device__ __forceinline__ void build_tw(float2* TW) {
  for (int m = threadIdx.x; m < 1024; m += 256) {
    float s, c;
    __sincosf(-6.28318530717958647f * (float)m * (1.0f/2048.0f), &s, &c);
    TW[m] = make_float2(c, s);
  }
}

// ---------------- Stockham radix-4 stage (N=2048, 256 threads) ----------------
template<int SIGN, int M>
__device__ __forceinline__ void r4_stage(const float2* __restrict__ src,
                                         float2* __restrict__ dst,
                                         const float2* __restrict__ TW) {
  constexpr int L = 2048 / (4 * M);
  __syncthreads();
  #pragma unroll
  for (int t = 0; t < 2; t++) {
    int idx = (int)threadIdx.x + t * 256;      // [0,512)
    int q = idx / M;
    int p = idx & (M - 1);
    float2 a0 = src[SL(idx)];
    float2 a1 = src[SL(idx + 512)];
    float2 a2 = src[SL(idx + 1024)];
    float2 a3 = src[SL(idx + 1536)];
    float2 w = TW[p * L];
    float2 W1 = make_float2(w.x, (SIGN > 0) ? -w.y : w.y);
    float2 W2 = make_float2(W1.x*W1.x - W1.y*W1.y, 2.f*W1.x*W1.y);
    float2 W3 = make_float2(W2.x*W1.x - W2.y*W1.y, W2.x*W1.y + W2.y*W1.x);
    float2 b1 = make_float2(a1.x*W1.x - a1.y*W1.y, a1.x*W1.y + a1.y*W1.x);
    float2 b2 = make_float2(a2.x*W2.x - a2.y*W2.y, a2.x*W2.y + a2.y*W2.x);
    float2 b3 = make_float2(a3.x*W3.x - a3.y*W3.y, a3.x*W3.y + a3.y*W3.x);
    float2 e0 = make_float2(a0.x + b2.x, a0.y + b2.y);
    float2 e1 = make_float2(b1.x + b3.x, b1.y + b3.y);
    float2 d0 = make_float2(a0.x - b2.x, a0.y - b2.y);
    float2 d1 = make_float2(b1.x - b3.x, b1.y - b3.y);
    float2 o1, o3;
    if (SIGN < 0) { o1 = make_float2(d0.x + d1.y, d0.y - d1.x);
                    o3 = make_float2(d0.x - d1.y, d0.y + d1.x); }
    else          { o1 = make_float2(d0.x - d1.y, d0.y + d1.x);
                    o3 = make_float2(d0.x + d1.y, d0.y - d1.x); }
    int ob = q * 4 * M + p;
    dst[SL(ob)]         = make_float2(e0.x + e1.x, e0.y + e1.y);
    dst[SL(ob + M)]     = o1;
    dst[SL(ob + 2*M)]   = make_float2(e0.x - e1.x, e0.y - e1.y);
    dst[SL(ob + 3*M)]   = o3;
  }
}

template<int SIGN>
__device__ __forceinline__ void r2_stage_final(const float2* __restrict__ src,
                                               float2* __restrict__ dst,
                                               const float2* __restrict__ TW) {
  __syncthreads();
  #pragma unroll
  for (int t = 0; t < 4; t++) {
    int p = (int)threadIdx.x + t * 256;
    float2 a = src[SL(p)], b = src[SL(p + 1024)];
    float2 w = TW[p];
    float wy = (SIGN > 0) ? -w.y : w.y;
    float2 wb = make_float2(b.x*w.x - b.y*wy, b.x*wy + b.y*w.x);
    dst[SL(p)]        = make_float2(a.x + wb.x, a.y + wb.y);
    dst[SL(p + 1024)] = make_float2(a.x - wb.x, a.y - wb.y);
  }
}

// Full 2048-pt FFT: natural in (b0) -> natural out (b0). Trailing barrier included.
template<int SIGN>
__device__ __forceinline__ void fft2048_st(float2* b0, float2* b1, const float2* TW) {
  r4_stage<SIGN,   1>(b0, b1, TW);
  r4_stage<SIGN,   4>(b1, b0, TW);
  r4_stage<SIGN,  16>(b0, b1, TW);
  r4_stage<SIGN,  64>(b1, b0, TW);
  r4_stage<SIGN, 256>(b0, b1, TW);
  r2_stage_final<SIGN>(b1, b0, TW);
  __syncthreads();
}

// ---------------- KT: params -> div-major coalesced layouts ----------------
__global__ __launch_bounds__(256) void ssm_kt(
    const float* __restrict__ Cre, const float* __restrict__ Cim,
    const float* __restrict__ Bre, const float* __restrict__ Bim,
    const float* __restrict__ Pre, const float* __restrict__ Pim,
    float2* __restrict__ CT, float2* __restrict__ BT, float2* __restrict__ PT) {
  int idx = blockIdx.x * 256 + threadIdx.x;   // 32768 = dv*4096 + n*64 + x
  int dv = idx >> 12, n = (idx >> 6) & 63, x = idx & 63;
  CT[idx] = make_float2(Cre[((size_t)x*NM + n)*NDIV + dv], -Cim[((size_t)x*NM + n)*NDIV + dv]);
  BT[idx] = make_float2(Bre[((size_t)n*HD + x)*NDIV + dv],  Bim[((size_t)n*HD + x)*NDIV + dv]);
  if (idx < NDIV*NM) {
    int dv2 = idx >> 6, n2 = idx & 63;
    PT[idx] = make_float2(Pre[n2*NDIV + dv2], Pim[n2*NDIV + dv2]);
  }
}

// ---------------- K0a: rc = c*r, cpx = c*(1+k11); 4 lanes per (l,dv) ----------------
__global__ __launch_bounds__(256) void ssm_k0a(
    const float* __restrict__ Lre, const float* __restrict__ Lim,
    const float* __restrict__ Pre, const float* __restrict__ Pim,
    const float* __restrict__ step, float2* __restrict__ rc, float2* __restrict__ cpx) {
  int idx = blockIdx.x * 256 + threadIdx.x;     // 65536 = (dv*2048 + l)*4 + qn
  int qn = idx & 3;
  int rest = idx >> 2;
  int l = rest & (LSEQ - 1);
  int dv = rest >> 11;
  double s = (double)expf(step[0]);
  float angf = -6.2831855f * ((float)l * (1.0f/2048.0f));
  double si, co;
  sincos((double)angf, &si, &co);
  cplxd om    = {co, si};
  cplxd one_p = {1.0 + om.x,  om.y};
  double ts = 2.0 / s;
  cplxd g = cdivd({ts*(1.0 - om.x), ts*(-om.y)}, one_p);
  cplxd c = cdivd({2.0, 0.0}, one_p);
  double k11x = 0.0, k11y = 0.0;
  float2* rcrow = rc + ((size_t)dv*LSEQ + l)*NM;
  for (int u = 0; u < 16; u++) {
    int n = qn*16 + u;
    float lre = fminf(Lre[n*NDIV+dv], -0.0001f);
    float lim = Lim[n*NDIV+dv];
    cplxd den = {g.x - (double)lre, g.y - (double)lim};
    cplxd r   = cdivd({1.0, 0.0}, den);
    cplxd rcv = cmuld(c, r);
    rcrow[n] = make_float2((float)rcv.x, (float)rcv.y);
    double pr = (double)Pre[n*NDIV+dv], pi = (double)Pim[n*NDIV+dv];
    double p2 = pr*pr + pi*pi;
    k11x += p2 * rcv.x; k11y += p2 * rcv.y;
  }
  k11x += __shfl_xor(k11x, 1); k11y += __shfl_xor(k11y, 1);
  k11x += __shfl_xor(k11x, 2); k11y += __shfl_xor(k11y, 2);
  if (qn == 0)
    cpx[(size_t)dv*LSEQ + l] = make_float2((float)(c.x + k11x), (float)(c.y + k11y));
}

// ---------------- K0b: A1 = (c*k01)/cpx, k10c = c*k10; 16 l per block, n-quarters ----------------
__global__ __launch_bounds__(256) void ssm_k0b(
    const float2* __restrict__ PT, const float2* __restrict__ CT,
    const float2* __restrict__ BT, const float2* __restrict__ rc,
    const float2* __restrict__ cpx, float2* __restrict__ A1, float2* __restrict__ k10c) {
  int dv = blockIdx.y;
  int l0 = blockIdx.x * 16;
  __shared__ float2 CTs[16][64];    // 8 KB
  __shared__ float2 BTs[16][64];    // 8 KB
  __shared__ float2 rcs[16][64];    // 8 KB
  __shared__ float2 ps[64];
  int tid = threadIdx.x;
  for (int q = tid; q < 16*64; q += 256) {
    int ll = q >> 6, n = q & 63;
    rcs[ll][n] = rc[((size_t)dv*LSEQ + l0 + ll)*NM + n];
  }
  if (tid < NM) ps[tid] = PT[dv*NM + tid];
  int lg = tid >> 6, idx = tid & 63;
  float k01r[4], k01i[4], k10r[4], k10i[4];
  #pragma unroll
  for (int g = 0; g < 4; g++) { k01r[g]=0.f; k01i[g]=0.f; k10r[g]=0.f; k10i[g]=0.f; }
  const float2* CTd = CT + (size_t)dv*NM*HD;
  const float2* BTd = BT + (size_t)dv*NM*HD;
  for (int nq = 0; nq < 4; nq++) {
    __syncthreads();
    for (int q = tid; q < 16*64; q += 256) {
      int n = q >> 6, x = q & 63;
      CTs[n][x] = CTd[(nq*16 + n)*HD + x];
      BTs[n][x] = BTd[(nq*16 + n)*HD + x];
    }
    __syncthreads();
    for (int np = 0; np < 16; np++) {
      int n = nq*16 + np;
      float2 cv = CTs[np][idx];
      float2 bv = BTs[np][idx];
      float2 pv = ps[n];
      #pragma unroll
      for (int g = 0; g < 4; g++) {
        float2 rv = rcs[g*4 + lg][n];
        float tr = cv.x*rv.x - cv.y*rv.y, ti = cv.x*rv.y + cv.y*rv.x;
        k01r[g] += tr*pv.x - ti*pv.y; k01i[g] += tr*pv.y + ti*pv.x;
        float ur = pv.x*rv.x + pv.y*rv.y;
        float ui = pv.x*rv.y - pv.y*rv.x;
        k10r[g] += ur*bv.x - ui*bv.y; k10i[g] += ur*bv.y + ui*bv.x;
      }
    }
  }
  #pragma unroll
  for (int g = 0; g < 4; g++) {
    int l = l0 + g*4 + lg;
    float2 wv = cpx[(size_t)dv*LSEQ + l];
    float inv = 1.0f / (wv.x*wv.x + wv.y*wv.y);
    A1  [((size_t)dv*LSEQ + l)*HD + idx] = make_float2((k01r[g]*wv.x + k01i[g]*wv.y)*inv,
                                                       (k01i[g]*wv.x - k01r[g]*wv.y)*inv);
    k10c[((size_t)dv*LSEQ + l)*HD + idx] = make_float2(k10r[g], k10i[g]);
  }
}

// ---------------- Ku: u (b,l,512) -> ut[div][b][h][l] ----------------
__global__ __launch_bounds__(256) void ssm_ku(const float* __restrict__ u, float* __restrict__ ut) {
  __shared__ float s[16][513];
  int b  = blockIdx.x >> 7;
  int l0 = (blockIdx.x & 127) << 4;
  int tid = threadIdx.x;
  for (int q = tid; q < 16*512; q += 256) {
    int ll = q >> 9, dd = q & 511;
    s[ll][dd] = u[((size_t)b*LSEQ + l0 + ll)*512 + dd];
  }
  __syncthreads();
  for (int q = tid; q < 16*512; q += 256) {
    int d = q >> 4, ll = q & 15;
    int dvv = d & 7, h = d >> 3;
    ut[(((size_t)(dvv*NB + b))*HD + h)*LSEQ + l0 + ll] = s[ll][d];
  }
}

// ---------------- K3: per div: ud[c][f] = rfft_4096(pad(ut row)) ----------------
__global__ __launch_bounds__(256) void ssm_k3(const float* __restrict__ ut, float2* __restrict__ ud, int dv) {
  __shared__ float2 b0[FFT_BUF];
  __shared__ float2 b1[FFT_BUF];
  __shared__ float2 TW[1024];
  int tid = threadIdx.x;
  int c = blockIdx.x;                           // 0..511 = b*64 + h
  const float2* src = (const float2*)(ut + ((size_t)dv*512 + c) * LSEQ);
  float2* dst = ud + (size_t)c * NF;
  build_tw(TW);
  for (int p = tid; p < 2048; p += 256)
    b0[SL(p)] = (p < 1024) ? src[p] : make_float2(0.f, 0.f);
  fft2048_st<-1>(b0, b1, TW);
  for (int f = tid; f <= 2048; f += 256) {
    int fa = f & 2047, fb = (2048 - f) & 2047;
    float2 Zf = b0[SL(fa)];
    float2 Zm = b0[SL(fb)];
    float Ex = (Zf.x + Zm.x)*0.5f, Ey = (Zf.y - Zm.y)*0.5f;
    float Dx = Zf.x - Zm.x,        Dy = Zf.y + Zm.y;
    float Ox = Dy*0.5f, Oy = -Dx*0.5f;
    float s, c2;
    __sincosf(-6.28318530717958647f * (float)f * (1.0f/4096.0f), &s, &c2);
    float WOx = Ox*c2 - Oy*s, WOy = Ox*s + Oy*c2;
    dst[f] = make_float2(Ex + WOx, Ey + WOy);
  }
}

// ---------------- K1: at_roots, chain-major bf16x2; grid (512, 2=ih) ----------------
__global__ __launch_bounds__(256) void ssm_k1(
    const float2* __restrict__ CT, const float2* __restrict__ BT,
    const float2* __restrict__ rc, const float2* __restrict__ A1,
    const float2* __restrict__ k10c, unsigned* __restrict__ big, int dv) {
  __shared__ float2 CC[NM][32];     // conj(C)[iBase+il][n]   16 KB
  __shared__ float2 BB[NM][32];     // B[n][j0+jl]            16 KB
  __shared__ float2 rcs[8][NM+1];   // 8 l's (padded)         4.1 KB
  int tid = threadIdx.x;
  int lg = blockIdx.x >> 1, jh = blockIdx.x & 1;
  int iBase = blockIdx.y * 32;
  int l0 = lg * 8, j0 = jh * 32;
  const float2* CTd = CT + (size_t)dv*NM*HD;
  const float2* BTd = BT + (size_t)dv*NM*HD;
  for (int q = tid; q < NM*32; q += 256) {
    int n = q >> 5, x = q & 31;
    CC[n][x] = CTd[n*HD + iBase + x];
    BB[n][x] = BTd[n*HD + j0 + x];
  }
  for (int q = tid; q < 8*NM; q += 256) {
    int ll = q >> 6, n = q & 63;
    rcs[ll][n] = rc[((size_t)dv*LSEQ + l0 + ll)*NM + n];
  }
  __syncthreads();
  int lq = tid & 7;
  int tile = tid >> 3;
  int ti = (tile >> 3) * 8;
  int tj = tile & 7;
  int l = l0 + lq;
  float2 acc[8][4];
  #pragma unroll
  for (int a = 0; a < 8; a++)
    #pragma unroll
    for (int b = 0; b < 4; b++) acc[a][b] = make_float2(0.f, 0.f);
  for (int n = 0; n < NM; n++) {
    float2 rv = rcs[lq][n];
    float2 uu[8];
    #pragma unroll
    for (int a = 0; a < 8; a++) {
      float2 cv = CC[n][ti+a];
      uu[a] = make_float2(cv.x*rv.x - cv.y*rv.y, cv.x*rv.y + cv.y*rv.x);
    }
    #pragma unroll
    for (int b = 0; b < 4; b++) {
      float2 bv = BB[n][tj + 8*b];
      #pragma unroll
      for (int a = 0; a < 8; a++) {
        acc[a][b].x = fmaf(uu[a].x, bv.x, fmaf(-uu[a].y, bv.y, acc[a][b].x));
        acc[a][b].y = fmaf(uu[a].x, bv.y, fmaf( uu[a].y, bv.x, acc[a][b].y));
      }
    }
  }
  const float2* A1row = A1   + ((size_t)dv*LSEQ + l)*HD;
  const float2* kqrow = k10c + ((size_t)dv*LSEQ + l)*HD;
  float2 ua[8], kb[4];
  #pragma unroll
  for (int a = 0; a < 8; a++) ua[a] = A1row[iBase + ti + a];
  #pragma unroll
  for (int b = 0; b < 4; b++) kb[b] = kqrow[j0 + tj + 8*b];
  #pragma unroll
  for (int a = 0; a < 8; a++)
    #pragma unroll
    for (int b = 0; b < 4; b++) {
      acc[a][b].x -= ua[a].x*kb[b].x - ua[a].y*kb[b].y;
      acc[a][b].y -= ua[a].x*kb[b].y + ua[a].y*kb[b].x;
    }
  #pragma unroll
  for (int a = 0; a < 8; a++)
    #pragma unroll
    for (int b = 0; b < 4; b++)
      big[((size_t)((iBase+ti+a)*64 + j0 + tj + 8*b))*NF + l] = pack_c(acc[a][b]);
}

// ---------------- K2: in-place per chain: art row (2048) -> Kd row (2049), bf16x2 ----------------
__global__ __launch_bounds__(256) void ssm_k2(unsigned* __restrict__ big) {
  __shared__ float2 b0[FFT_BUF];
  __shared__ float2 b1[FFT_BUF];
  __shared__ float2 TW[1024];
  int tid = threadIdx.x;
  unsigned* row = big + (size_t)blockIdx.x * NF;
  build_tw(TW);
  for (int p = tid; p < 2048; p += 256) b0[SL(p)] = unpack_c(row[p]);
  __syncthreads();
  float2 ev[4];
  #pragma unroll
  for (int k = 0; k < 4; k++) {
    int l = tid + 256*k;
    float2 a = b0[SL(l)], b = b0[SL((2048 - l) & 2047)];
    ev[k] = make_float2((a.x+b.x)*0.5f, (a.y-b.y)*0.5f);
  }
  float ev1024 = b0[SL(1024)].x;
  fft2048_st<1>(b0, b1, TW);
  const float sc = 1.0f/2048.0f;
  for (int t = tid; t < 2048; t += 256) {
    float kr = b0[SL(t)].x * sc;
    float s, c;
    __sincosf(-3.14159265358979324f * (float)t * (1.0f/2048.0f), &s, &c);
    b0[SL(t)] = make_float2(kr*c, kr*s);
  }
  fft2048_st<-1>(b0, b1, TW);
  #pragma unroll
  for (int k = 0; k < 4; k++) { int l = tid + 256*k; b1[SL(l)] = ev[k]; }
  __syncthreads();
  for (int e = tid; e < 2048; e += 256)
    row[e] = pack_c((e & 1) ? b0[SL(e >> 1)] : b1[SL(e >> 1)]);
  if (tid == 0) row[2048] = pack_c(make_float2(ev1024, 0.f));
}

// ---------------- K4: yf[b*64+i][f] = sum_j Kd[i*64+j][f]*ud[b*64+j][f] ----------------
// grid (129 f-tiles, 4 i-tiles), 256 thr = 16 i x 16 f
__global__ __launch_bounds__(256) void ssm_k4(
    const unsigned* __restrict__ kdt, const float2* __restrict__ ud,
    float2* __restrict__ yf) {
  __shared__ float2 uds[NB][32][16];   // 32 KB (j-half x f)
  int tid = threadIdx.x;
  int f0 = blockIdx.x * 16;
  int i0 = blockIdx.y * 16;
  int ii = tid >> 4, ff = tid & 15;
  int i = i0 + ii;
  int f = f0 + ff;
  int fr = (f < NF) ? f : 2048;
  float2 acc[NB];
  #pragma unroll
  for (int b = 0; b < NB; b++) acc[b] = make_float2(0.f, 0.f);
  for (int jh = 0; jh < 2; jh++) {
    __syncthreads();
    for (int q = tid; q < NB*32*16; q += 256) {
      int b = q >> 9, j = (q >> 4) & 31, fq = q & 15;
      int f_ = f0 + fq;
      uds[b][j][fq] = (f_ < NF) ? ud[((size_t)(b*HD + jh*32 + j))*NF + f_]
                                : make_float2(0.f, 0.f);
    }
    __syncthreads();
    for (int j = 0; j < 32; j++) {
      float2 kv = unpack_c(kdt[((size_t)(i*HD + jh*32 + j))*NF + fr]);
      #pragma unroll
      for (int b = 0; b < NB; b++) {
        float2 uv = uds[b][j][ff];
        acc[b].x += kv.x*uv.x - kv.y*uv.y;
        acc[b].y += kv.x*uv.y + kv.y*uv.x;
      }
    }
  }
  if (f < NF) {
    #pragma unroll
    for (int b = 0; b < NB; b++)
      yf[((size_t)(b*HD + i))*NF + f] = acc[b];
  }
}

// ---------------- K5: yt row = irfft_4096(yf row)[0:2048]; grid 512 ----------------
__global__ __launch_bounds__(256) void ssm_k5(const float2* __restrict__ yf,
                                              float* __restrict__ yt, int dv) {
  __shared__ float2 b0[FFT_BUF];
  __shared__ float2 b1[FFT_BUF];
  __shared__ float2 TW[1024];
  int tid = threadIdx.x;
  int b = blockIdx.x >> 6, i = blockIdx.x & 63;
  const float2* src = yf + (size_t)(b*HD + i) * NF;
  float2* dst = (float2*)(yt + (((size_t)(dv*NB + b))*HD + i) * LSEQ);
  build_tw(TW);
  for (int k = tid; k < 2048; k += 256) {
    float2 Xk = src[k];
    float2 Xm = src[2048 - k];
    float Ex = (Xk.x + Xm.x)*0.5f, Ey = (Xk.y - Xm.y)*0.5f;
    float Dx = Xk.x - Xm.x,        Dy = Xk.y + Xm.y;
    float s, c;
    __sincosf(6.28318530717958647f * (float)k * (1.0f/4096.0f), &s, &c);
    float Ox = 0.5f*(Dx*c - Dy*s);
    float Oy = 0.5f*(Dx*s + Dy*c);
    b0[SL(k)] = make_float2(Ex - Oy, Ey + Ox);
  }
  fft2048_st<1>(b0, b1, TW);
  const float sc = 1.0f/2048.0f;
  for (int t = tid; t < 1024; t += 256) {
    float2 z = b0[SL(t)];
    dst[t] = make_float2(z.x*sc, z.y*sc);
  }
}

// ---------------- T2: yt[div][b][i][t] -> out[b][t][i*8+div] ----------------
__global__ __launch_bounds__(256) void ssm_t2(const float* __restrict__ yt, float* __restrict__ out) {
  __shared__ float s[512][17];
  int b  = blockIdx.x >> 7;
  int t0 = (blockIdx.x & 127) << 4;
  int tid = threadIdx.x;
  for (int q = tid; q < 512*16; q += 256) {
    int d = q >> 4, tt = q & 15;
    int dvv = d & 7, i = d >> 3;
    s[d][tt] = yt[(((size_t)(dvv*NB + b))*HD + i)*LSEQ + t0 + tt];
  }
  __syncthreads();
  for (int q = tid; q < 512*16; q += 256) {
    int tt = q >> 9, d = q & 511;
    out[((size_t)b*LSEQ + t0 + tt)*512 + d] = s[d][tt];
  }
}

// ---------------- host ----------------
extern "C" void kernel_launch(void* const* d_in, const int* in_sizes, int n_in,
                              void* d_out, int out_size, void* d_ws, size_t ws_size,
                              hipStream_t stream) {
  const float* u    = (const float*)d_in[0];
  const float* Lre  = (const float*)d_in[1];
  const float* Lim  = (const float*)d_in[2];
  const float* Pre  = (const float*)d_in[3];
  const float* Pim  = (const float*)d_in[4];
  const float* Bre  = (const float*)d_in[5];
  const float* Bim  = (const float*)d_in[6];
  const float* Cre  = (const float*)d_in[7];
  const float* Cim  = (const float*)d_in[8];
  const float* step = (const float*)d_in[9];
  float* out = (float*)d_out;

  char* w = (char*)d_ws;
  size_t off = 0;
  auto carve = [&](size_t bytes) -> void* {
    void* p = (void*)(w + off);
    off += (bytes + 255) & ~(size_t)255;
    return p;
  };
  float2*   rc   = (float2*)carve((size_t)NDIV*LSEQ*NM*sizeof(float2));   // 8.39 MB
  float2*   cpx  = (float2*)carve((size_t)NDIV*LSEQ*sizeof(float2));      // 0.13 MB
  float2*   A1   = (float2*)carve((size_t)NDIV*LSEQ*HD*sizeof(float2));   // 8.39 MB
  float2*   k10c = (float2*)carve((size_t)NDIV*LSEQ*HD*sizeof(float2));   // 8.39 MB
  float*    ut   = (float*) carve((size_t)NDIV*NB*HD*LSEQ*sizeof(float)); // 33.55 MB (later = yt)
  unsigned* big  = (unsigned*)carve((size_t)4096*NF*sizeof(unsigned));    // 33.57 MB (bf16x2, full div)
  float2*   ud   = (float2*)carve((size_t)512*NF*sizeof(float2));         // 8.39 MB (per div)
  float2*   yf   = (float2*)carve((size_t)512*NF*sizeof(float2));         // 8.39 MB (per div)
  float2*   CT   = (float2*)carve((size_t)NDIV*NM*HD*sizeof(float2));     // 256 KB
  float2*   BT   = (float2*)carve((size_t)NDIV*NM*HD*sizeof(float2));     // 256 KB
  float2*   PT   = (float2*)carve((size_t)NDIV*NM*sizeof(float2));        // 4 KB
  (void)in_sizes; (void)n_in; (void)out_size;
  if (ws_size < off) return;   // insufficient scratch -> clean failure, diagnosable

  ssm_kt<<<128, 256, 0, stream>>>(Cre, Cim, Bre, Bim, Pre, Pim, CT, BT, PT);
  ssm_k0a<<<256, 256, 0, stream>>>(Lre, Lim, Pre, Pim, step, rc, cpx);
  ssm_k0b<<<dim3(128, 8), 256, 0, stream>>>(PT, CT, BT, rc, cpx, A1, k10c);
  ssm_ku<<<1024, 256, 0, stream>>>(u, ut);
  for (int dv = 0; dv < NDIV; ++dv) {
    ssm_k3<<<512, 256, 0, stream>>>(ut, ud, dv);
    ssm_k1<<<dim3(512, 2), 256, 0, stream>>>(CT, BT, rc, A1, k10c, big, dv);
    ssm_k2<<<4096, 256, 0, stream>>>(big);
    ssm_k4<<<dim3(129, 4), 256, 0, stream>>>(big, ud, yf);
    ssm_k5<<<512, 256, 0, stream>>>(yf, ut, dv);
  }
  ssm_t2<<<1024, 256, 0, stream>>>(ut, out);
}

// Round 6
// 1419.011 us; speedup vs baseline: 1.8588x; 1.0943x over previous
//
#include <hip/hip_runtime.h>
#include <hip/hip_bf16.h>
#include <math.h>

#define LSEQ 2048
#define NM   64     // N modes
#define HD   64     // H
#define NDIV 8
#define NB   8      // batch
#define NF   2049   // rfft bins of 4096

// padded LDS slot: +1 float2 every 32 -> all FFT accesses <=2-way bank aliasing
#define SL(E) ((E) + ((E) >> 5))
#define FFT_BUF 2112   // SL(2047)=2110 < 2112

// ---------------- bf16x2 complex pack/unpack ----------------
__device__ __forceinline__ unsigned pack_c(float2 v) {
  __hip_bfloat162 h = __float22bfloat162_rn(v);
  return *reinterpret_cast<unsigned*>(&h);
}
__device__ __forceinline__ float2 unpack_c(unsigned u) {
  __hip_bfloat162 h = *reinterpret_cast<__hip_bfloat162*>(&u);
  return __bfloat1622float2(h);
}

// ---------------- double complex helpers (precompute only) ----------------
struct cplxd { double x, y; };
__device__ __forceinline__ cplxd cmuld(cplxd a, cplxd b) {
  return {a.x*b.x - a.y*b.y, a.x*b.y + a.y*b.x};
}
__device__ __forceinline__ cplxd cdivd(cplxd a, cplxd b) {
  double inv = 1.0 / (b.x*b.x + b.y*b.y);
  return {(a.x*b.x + a.y*b.y)*inv, (a.y*b.x - a.x*b.y)*inv};
}

// ---------------- TW256[m] = exp(-2*pi*i*(2m)/2048) = exp(-i*pi*m/512) ----------------
// r4 stages only index even twiddles (p*L always even, p*L<512); r2 finals use sincos.
__device__ __forceinline__ void build_tw256(float2* TW) {
  int m = threadIdx.x;
  if (m < 256) {
    float s, c;
    __sincosf(-3.14159265358979324f * (float)m * (1.0f/512.0f), &s, &c);
    TW[m] = make_float2(c, s);
  }
}

// ---------------- Stockham radix-4 stage (N=2048, 256 threads), LDS->LDS ----------------
template<int SIGN, int M>
__device__ __forceinline__ void r4_stage(const float2* __restrict__ src,
                                         float2* __restrict__ dst,
                                         const float2* __restrict__ TW) {
  constexpr int L = 2048 / (4 * M);
  __syncthreads();
  #pragma unroll
  for (int t = 0; t < 2; t++) {
    int idx = (int)threadIdx.x + t * 256;      // [0,512)
    int q = idx / M;
    int p = idx & (M - 1);
    float2 a0 = src[SL(idx)];
    float2 a1 = src[SL(idx + 512)];
    float2 a2 = src[SL(idx + 1024)];
    float2 a3 = src[SL(idx + 1536)];
    float2 w = TW[(p * L) >> 1];
    float2 W1 = make_float2(w.x, (SIGN > 0) ? -w.y : w.y);
    float2 W2 = make_float2(W1.x*W1.x - W1.y*W1.y, 2.f*W1.x*W1.y);
    float2 W3 = make_float2(W2.x*W1.x - W2.y*W1.y, W2.x*W1.y + W2.y*W1.x);
    float2 b1 = make_float2(a1.x*W1.x - a1.y*W1.y, a1.x*W1.y + a1.y*W1.x);
    float2 b2 = make_float2(a2.x*W2.x - a2.y*W2.y, a2.x*W2.y + a2.y*W2.x);
    float2 b3 = make_float2(a3.x*W3.x - a3.y*W3.y, a3.x*W3.y + a3.y*W3.x);
    float2 e0 = make_float2(a0.x + b2.x, a0.y + b2.y);
    float2 e1 = make_float2(b1.x + b3.x, b1.y + b3.y);
    float2 d0 = make_float2(a0.x - b2.x, a0.y - b2.y);
    float2 d1 = make_float2(b1.x - b3.x, b1.y - b3.y);
    float2 o1, o3;
    if (SIGN < 0) { o1 = make_float2(d0.x + d1.y, d0.y - d1.x);
                    o3 = make_float2(d0.x - d1.y, d0.y + d1.x); }
    else          { o1 = make_float2(d0.x - d1.y, d0.y + d1.x);
                    o3 = make_float2(d0.x + d1.y, d0.y - d1.x); }
    int ob = q * 4 * M + p;
    dst[SL(ob)]         = make_float2(e0.x + e1.x, e0.y + e1.y);
    dst[SL(ob + M)]     = o1;
    dst[SL(ob + 2*M)]   = make_float2(e0.x - e1.x, e0.y - e1.y);
    dst[SL(ob + 3*M)]   = o3;
  }
}

// middle 4 radix-4 stages: input in a, output in a (a->b->a->b->a)
template<int SIGN>
__device__ __forceinline__ void r4_mid(float2* a, float2* b, const float2* TW) {
  r4_stage<SIGN,   4>(a, b, TW);
  r4_stage<SIGN,  16>(b, a, TW);
  r4_stage<SIGN,  64>(a, b, TW);
  r4_stage<SIGN, 256>(b, a, TW);
}

// final radix-2 stage, LDS->LDS, sincos twiddles
template<int SIGN>
__device__ __forceinline__ void r2f_ldst(const float2* __restrict__ src,
                                         float2* __restrict__ dst) {
  __syncthreads();
  #pragma unroll
  for (int t = 0; t < 4; t++) {
    int p = (int)threadIdx.x + t * 256;
    float2 a = src[SL(p)], b = src[SL(p + 1024)];
    float s, c;
    __sincosf(-6.28318530717958647f * (float)p * (1.0f/2048.0f), &s, &c);
    float wy = (SIGN > 0) ? -s : s;
    float2 wb = make_float2(b.x*c - b.y*wy, b.x*wy + b.y*c);
    dst[SL(p)]        = make_float2(a.x + wb.x, a.y + wb.y);
    dst[SL(p + 1024)] = make_float2(a.x - wb.x, a.y - wb.y);
  }
}

// k2 FFT#1 stage 1 (SIGN=+1, M=1): reads bf16 row direct from global
__device__ __forceinline__ void r4g_bf16_inv(const unsigned* __restrict__ row,
                                             float2* __restrict__ dst) {
  #pragma unroll
  for (int t = 0; t < 2; t++) {
    int idx = (int)threadIdx.x + t * 256;
    float2 a0 = unpack_c(row[idx]);
    float2 a1 = unpack_c(row[idx + 512]);
    float2 a2 = unpack_c(row[idx + 1024]);
    float2 a3 = unpack_c(row[idx + 1536]);
    float2 e0 = make_float2(a0.x + a2.x, a0.y + a2.y);
    float2 e1 = make_float2(a1.x + a3.x, a1.y + a3.y);
    float2 d0 = make_float2(a0.x - a2.x, a0.y - a2.y);
    float2 d1 = make_float2(a1.x - a3.x, a1.y - a3.y);
    // SIGN=+1
    float2 o1 = make_float2(d0.x - d1.y, d0.y + d1.x);
    float2 o3 = make_float2(d0.x + d1.y, d0.y - d1.x);
    int ob = idx * 4;
    dst[SL(ob)]   = make_float2(e0.x + e1.x, e0.y + e1.y);
    dst[SL(ob+1)] = o1;
    dst[SL(ob+2)] = make_float2(e0.x - e1.x, e0.y - e1.y);
    dst[SL(ob+3)] = o3;
  }
}

// k3 stage 1 (SIGN=-1, M=1): reads f32 z-pairs from global, upper half zero-padded
__device__ __forceinline__ void r4g_f32pad_fwd(const float2* __restrict__ g,
                                               float2* __restrict__ dst) {
  #pragma unroll
  for (int t = 0; t < 2; t++) {
    int idx = (int)threadIdx.x + t * 256;
    float2 a0 = g[idx];
    float2 a1 = g[idx + 512];
    // a2 = a3 = 0 -> e0=d0=a0, e1=d1=a1
    int ob = idx * 4;
    dst[SL(ob)]   = make_float2(a0.x + a1.x, a0.y + a1.y);
    dst[SL(ob+1)] = make_float2(a0.x + a1.y, a0.y - a1.x);   // SIGN=-1 o1
    dst[SL(ob+2)] = make_float2(a0.x - a1.x, a0.y - a1.y);
    dst[SL(ob+3)] = make_float2(a0.x - a1.y, a0.y + a1.x);   // SIGN=-1 o3
  }
}

// k2 FFT#2 stage 1 (SIGN=-1, M=1) fused with Re()*(1/2048)*mod[t], mod=e^{-i*pi*t/2048}
__device__ __forceinline__ void r4_modstage(const float2* __restrict__ src,
                                            float2* __restrict__ dst) {
  __syncthreads();
  const float sc = 1.0f/2048.0f;
  const float R = 0.70710678118654752f;
  #pragma unroll
  for (int t = 0; t < 2; t++) {
    int idx = (int)threadIdx.x + t * 256;
    float k0 = src[SL(idx)].x        * sc;
    float k1 = src[SL(idx + 512)].x  * sc;
    float k2 = src[SL(idx + 1024)].x * sc;
    float k3 = src[SL(idx + 1536)].x * sc;
    float s, c;
    __sincosf(-3.14159265358979324f * (float)idx * (1.0f/2048.0f), &s, &c);
    float2 a0 = make_float2(k0*c,         k0*s);
    float2 a1 = make_float2(k1*R*(c + s), k1*R*(s - c));   // *e^{-i pi/4}
    float2 a2 = make_float2(k2*s,        -k2*c);           // *e^{-i pi/2}
    float2 a3 = make_float2(k3*R*(s - c), -k3*R*(s + c));  // *e^{-i 3pi/4}
    float2 e0 = make_float2(a0.x + a2.x, a0.y + a2.y);
    float2 e1 = make_float2(a1.x + a3.x, a1.y + a3.y);
    float2 d0 = make_float2(a0.x - a2.x, a0.y - a2.y);
    float2 d1 = make_float2(a1.x - a3.x, a1.y - a3.y);
    // SIGN=-1
    float2 o1 = make_float2(d0.x + d1.y, d0.y - d1.x);
    float2 o3 = make_float2(d0.x - d1.y, d0.y + d1.x);
    int ob = idx * 4;
    dst[SL(ob)]   = make_float2(e0.x + e1.x, e0.y + e1.y);
    dst[SL(ob+1)] = o1;
    dst[SL(ob+2)] = make_float2(e0.x - e1.x, e0.y - e1.y);
    dst[SL(ob+3)] = o3;
  }
}

// k2 FFT#2 final radix-2 (SIGN=-1): write odd bins (k<1024 only) packed to global
__device__ __forceinline__ void r2f_gw_bf16(const float2* __restrict__ src,
                                            unsigned* __restrict__ row) {
  __syncthreads();
  #pragma unroll
  for (int t = 0; t < 4; t++) {
    int p = (int)threadIdx.x + t * 256;        // odd bin index k = p
    float2 a = src[SL(p)], b = src[SL(p + 1024)];
    float s, c;
    __sincosf(-6.28318530717958647f * (float)p * (1.0f/2048.0f), &s, &c);
    float2 wb = make_float2(b.x*c - b.y*s, b.x*s + b.y*c);   // SIGN=-1: wy=s
    row[2*p + 1] = pack_c(make_float2(a.x + wb.x, a.y + wb.y));
  }
}

// k5 final radix-2 (SIGN=+1): only t<1024 needed; scaled; writes f32 pairs to global
__device__ __forceinline__ void r2f_gw_f32h(const float2* __restrict__ src,
                                            float2* __restrict__ dst) {
  __syncthreads();
  const float sc = 1.0f/2048.0f;
  #pragma unroll
  for (int t = 0; t < 4; t++) {
    int p = (int)threadIdx.x + t * 256;        // [0,1024)
    float2 a = src[SL(p)], b = src[SL(p + 1024)];
    float s, c;
    __sincosf(-6.28318530717958647f * (float)p * (1.0f/2048.0f), &s, &c);
    float wy = -s;                              // SIGN=+1
    float2 wb = make_float2(b.x*c - b.y*wy, b.x*wy + b.y*c);
    dst[p] = make_float2((a.x + wb.x)*sc, (a.y + wb.y)*sc);
  }
}

// ---------------- KT: params -> div-major coalesced layouts ----------------
__global__ __launch_bounds__(256) void ssm_kt(
    const float* __restrict__ Cre, const float* __restrict__ Cim,
    const float* __restrict__ Bre, const float* __restrict__ Bim,
    const float* __restrict__ Pre, const float* __restrict__ Pim,
    float2* __restrict__ CT, float2* __restrict__ BT, float2* __restrict__ PT) {
  int idx = blockIdx.x * 256 + threadIdx.x;   // 32768 = dv*4096 + n*64 + x
  int dv = idx >> 12, n = (idx >> 6) & 63, x = idx & 63;
  CT[idx] = make_float2(Cre[((size_t)x*NM + n)*NDIV + dv], -Cim[((size_t)x*NM + n)*NDIV + dv]);
  BT[idx] = make_float2(Bre[((size_t)n*HD + x)*NDIV + dv],  Bim[((size_t)n*HD + x)*NDIV + dv]);
  if (idx < NDIV*NM) {
    int dv2 = idx >> 6, n2 = idx & 63;
    PT[idx] = make_float2(Pre[n2*NDIV + dv2], Pim[n2*NDIV + dv2]);
  }
}

// ---------------- K0a: rc = c*r, cpx = c*(1+k11); 4 lanes per (l,dv) ----------------
__global__ __launch_bounds__(256) void ssm_k0a(
    const float* __restrict__ Lre, const float* __restrict__ Lim,
    const float* __restrict__ Pre, const float* __restrict__ Pim,
    const float* __restrict__ step, float2* __restrict__ rc, float2* __restrict__ cpx) {
  int idx = blockIdx.x * 256 + threadIdx.x;     // 65536 = (dv*2048 + l)*4 + qn
  int qn = idx & 3;
  int rest = idx >> 2;
  int l = rest & (LSEQ - 1);
  int dv = rest >> 11;
  double s = (double)expf(step[0]);
  float angf = -6.2831855f * ((float)l * (1.0f/2048.0f));
  double si, co;
  sincos((double)angf, &si, &co);
  cplxd om    = {co, si};
  cplxd one_p = {1.0 + om.x,  om.y};
  double ts = 2.0 / s;
  cplxd g = cdivd({ts*(1.0 - om.x), ts*(-om.y)}, one_p);
  cplxd c = cdivd({2.0, 0.0}, one_p);
  double k11x = 0.0, k11y = 0.0;
  float2* rcrow = rc + ((size_t)dv*LSEQ + l)*NM;
  for (int u = 0; u < 16; u++) {
    int n = qn*16 + u;
    float lre = fminf(Lre[n*NDIV+dv], -0.0001f);
    float lim = Lim[n*NDIV+dv];
    cplxd den = {g.x - (double)lre, g.y - (double)lim};
    cplxd r   = cdivd({1.0, 0.0}, den);
    cplxd rcv = cmuld(c, r);
    rcrow[n] = make_float2((float)rcv.x, (float)rcv.y);
    double pr = (double)Pre[n*NDIV+dv], pi = (double)Pim[n*NDIV+dv];
    double p2 = pr*pr + pi*pi;                  // conj(p)*p is real
    k11x += p2 * rcv.x; k11y += p2 * rcv.y;
  }
  k11x += __shfl_xor(k11x, 1); k11y += __shfl_xor(k11y, 1);
  k11x += __shfl_xor(k11x, 2); k11y += __shfl_xor(k11y, 2);
  if (qn == 0)
    cpx[(size_t)dv*LSEQ + l] = make_float2((float)(c.x + k11x), (float)(c.y + k11y));
}

// ---------------- Ku: u (b,l,512) -> ut[div][b][h][l] ----------------
__global__ __launch_bounds__(256) void ssm_ku(const float* __restrict__ u, float* __restrict__ ut) {
  __shared__ float s[16][513];
  int b  = blockIdx.x >> 7;
  int l0 = (blockIdx.x & 127) << 4;
  int tid = threadIdx.x;
  for (int q = tid; q < 16*512; q += 256) {
    int ll = q >> 9, dd = q & 511;
    s[ll][dd] = u[((size_t)b*LSEQ + l0 + ll)*512 + dd];
  }
  __syncthreads();
  for (int q = tid; q < 16*512; q += 256) {
    int d = q >> 4, ll = q & 15;
    int dvv = d & 7, h = d >> 3;
    ut[(((size_t)(dvv*NB + b))*HD + h)*LSEQ + l0 + ll] = s[ll][d];
  }
}

// ---------------- K3: per div: ud[c][f] = rfft_4096(pad(ut row)) ----------------
__global__ __launch_bounds__(256) void ssm_k3(const float* __restrict__ ut, float2* __restrict__ ud, int dv) {
  __shared__ float2 b0[FFT_BUF];
  __shared__ float2 b1[FFT_BUF];
  __shared__ float2 TW[256];
  int tid = threadIdx.x;
  int c = blockIdx.x;                           // 0..511 = b*64 + h
  const float2* src = (const float2*)(ut + ((size_t)dv*512 + c) * LSEQ);
  float2* dst = ud + (size_t)c * NF;
  build_tw256(TW);
  r4g_f32pad_fwd(src, b1);      // stage 1 reads global (zero-pad fused)
  r4_mid<-1>(b1, b0, TW);       // ends in b1
  r2f_ldst<-1>(b1, b0);         // b0 = Z natural order
  __syncthreads();
  for (int f = tid; f <= 2048; f += 256) {
    int fa = f & 2047, fb = (2048 - f) & 2047;
    float2 Zf = b0[SL(fa)];
    float2 Zm = b0[SL(fb)];
    float Ex = (Zf.x + Zm.x)*0.5f, Ey = (Zf.y - Zm.y)*0.5f;
    float Dx = Zf.x - Zm.x,        Dy = Zf.y + Zm.y;
    float Ox = Dy*0.5f, Oy = -Dx*0.5f;
    float s, c2;
    __sincosf(-6.28318530717958647f * (float)f * (1.0f/4096.0f), &s, &c2);
    float WOx = Ox*c2 - Oy*s, WOy = Ox*s + Oy*c2;
    dst[f] = make_float2(Ex + WOx, Ey + WOy);
  }
}

// ---------------- K1: at_roots, chain-major bf16x2; k0b folded in as prologue ----------------
__global__ __launch_bounds__(256) void ssm_k1(
    const float2* __restrict__ CT, const float2* __restrict__ BT,
    const float2* __restrict__ PT, const float2* __restrict__ rc,
    const float2* __restrict__ cpx, unsigned* __restrict__ big, int dv) {
  __shared__ float2 CC[NM][32];     // conj(C)[iBase+il][n]   16 KB
  __shared__ float2 BB[NM][32];     // B[n][j0+jl]            16 KB
  __shared__ float2 rcs[8][NM+1];   // 8 l's (padded)         4.1 KB
  __shared__ float2 a1s[8][32];     // A1[l][iloc]            2 KB
  __shared__ float2 k10s[8][32];    // K10c[l][jloc]          2 KB
  __shared__ float2 pps[NM];        // p[n]                   0.5 KB
  int tid = threadIdx.x;
  int lg = blockIdx.x >> 1, jh = blockIdx.x & 1;
  int iBase = blockIdx.y * 32;
  int l0 = lg * 8, j0 = jh * 32;
  const float2* CTd = CT + (size_t)dv*NM*HD;
  const float2* BTd = BT + (size_t)dv*NM*HD;
  for (int q = tid; q < NM*32; q += 256) {
    int n = q >> 5, x = q & 31;
    CC[n][x] = CTd[n*HD + iBase + x];
    BB[n][x] = BTd[n*HD + j0 + x];
  }
  for (int q = tid; q < 8*NM; q += 256) {
    int ll = q >> 6, n = q & 63;
    rcs[ll][n] = rc[((size_t)dv*LSEQ + l0 + ll)*NM + n];
  }
  if (tid < NM) pps[tid] = PT[dv*NM + tid];
  __syncthreads();
  int lq = tid & 7;
  int tile = tid >> 3;
  // ---- prologue (was k0b): A1 for (l, i=iBase+tile), K10c for (l, j=j0+tile) ----
  {
    float2 s01 = make_float2(0.f, 0.f), s10 = make_float2(0.f, 0.f);
    for (int n = 0; n < NM; n++) {
      float2 rv = rcs[lq][n];
      float2 pv = pps[n];
      float2 pr = make_float2(pv.x*rv.x - pv.y*rv.y, pv.x*rv.y + pv.y*rv.x);  // p*rc
      float2 qr = make_float2(pv.x*rv.x + pv.y*rv.y, pv.x*rv.y - pv.y*rv.x);  // conj(p)*rc
      float2 cv = CC[n][tile];
      s01.x += cv.x*pr.x - cv.y*pr.y; s01.y += cv.x*pr.y + cv.y*pr.x;
      float2 bv = BB[n][tile];
      s10.x += qr.x*bv.x - qr.y*bv.y; s10.y += qr.x*bv.y + qr.y*bv.x;
    }
    float2 wv = cpx[(size_t)dv*LSEQ + l0 + lq];
    float inv = 1.0f / (wv.x*wv.x + wv.y*wv.y);
    a1s[lq][tile]  = make_float2((s01.x*wv.x + s01.y*wv.y)*inv,
                                 (s01.y*wv.x - s01.x*wv.y)*inv);
    k10s[lq][tile] = s10;
  }
  __syncthreads();
  // ---- main GEMM ----
  int ti = (tile >> 3) * 8;
  int tj = tile & 7;
  int l = l0 + lq;
  float2 acc[8][4];
  #pragma unroll
  for (int a = 0; a < 8; a++)
    #pragma unroll
    for (int b = 0; b < 4; b++) acc[a][b] = make_float2(0.f, 0.f);
  for (int n = 0; n < NM; n++) {
    float2 rv = rcs[lq][n];
    float2 uu[8];
    #pragma unroll
    for (int a = 0; a < 8; a++) {
      float2 cv = CC[n][ti+a];
      uu[a] = make_float2(cv.x*rv.x - cv.y*rv.y, cv.x*rv.y + cv.y*rv.x);
    }
    #pragma unroll
    for (int b = 0; b < 4; b++) {
      float2 bv = BB[n][tj + 8*b];
      #pragma unroll
      for (int a = 0; a < 8; a++) {
        acc[a][b].x = fmaf(uu[a].x, bv.x, fmaf(-uu[a].y, bv.y, acc[a][b].x));
        acc[a][b].y = fmaf(uu[a].x, bv.y, fmaf( uu[a].y, bv.x, acc[a][b].y));
      }
    }
  }
  float2 ua[8], kb[4];
  #pragma unroll
  for (int a = 0; a < 8; a++) ua[a] = a1s[lq][ti + a];
  #pragma unroll
  for (int b = 0; b < 4; b++) kb[b] = k10s[lq][tj + 8*b];
  #pragma unroll
  for (int a = 0; a < 8; a++)
    #pragma unroll
    for (int b = 0; b < 4; b++) {
      acc[a][b].x -= ua[a].x*kb[b].x - ua[a].y*kb[b].y;
      acc[a][b].y -= ua[a].x*kb[b].y + ua[a].y*kb[b].x;
    }
  #pragma unroll
  for (int a = 0; a < 8; a++)
    #pragma unroll
    for (int b = 0; b < 4; b++)
      big[((size_t)((iBase+ti+a)*64 + j0 + tj + 8*b))*NF + l] = pack_c(acc[a][b]);
}

// ---------------- K2: in-place per chain: ar row (2048 bf16x2) -> Kd row (2049) ----------------
__global__ __launch_bounds__(256) void ssm_k2(unsigned* __restrict__ big) {
  __shared__ float2 b0[FFT_BUF];
  __shared__ float2 b1[FFT_BUF];
  __shared__ float2 TW[256];
  int tid = threadIdx.x;
  unsigned* row = big + (size_t)blockIdx.x * NF;
  build_tw256(TW);
  // even bins Kd[2m] = (ar[m] + conj(ar[(2048-m)%2048]))/2  (from global, into regs)
  float2 ev[4];
  #pragma unroll
  for (int k = 0; k < 4; k++) {
    int l = tid + 256*k;                        // [0,1024)
    float2 a = unpack_c(row[l]);
    float2 b = unpack_c(row[(2048 - l) & 2047]);
    ev[k] = make_float2((a.x + b.x)*0.5f, (a.y - b.y)*0.5f);
  }
  float ev1024 = (tid == 0) ? unpack_c(row[1024]).x : 0.f;
  // FFT#1 = ifft(ar): stage 1 reads global
  r4g_bf16_inv(row, b1);
  __syncthreads();                               // all global reads of row complete
  #pragma unroll
  for (int k = 0; k < 4; k++) { int l = tid + 256*k; row[2*l] = pack_c(ev[k]); }
  if (tid == 0) row[2048] = pack_c(make_float2(ev1024, 0.f));
  r4_mid<1>(b1, b0, TW);                         // ends in b1
  r2f_ldst<1>(b1, b0);                           // b0 = z natural order
  // FFT#2 = forward FFT of Re(z)*sc*mod (fused stage 1)
  r4_modstage(b0, b1);
  r4_mid<-1>(b1, b0, TW);                        // ends in b1
  r2f_gw_bf16(b1, row);                          // odd bins direct to global
}

// ---------------- K4: yf[b*64+i][f] = sum_j Kd[i*64+j][f]*ud[b*64+j][f] ----------------
// grid (129 f-tiles, 4 i-tiles), 256 thr = 16 i x 16 f
__global__ __launch_bounds__(256) void ssm_k4(
    const unsigned* __restrict__ kdt, const float2* __restrict__ ud,
    float2* __restrict__ yf) {
  __shared__ float2 uds[NB][32][16];   // 32 KB (j-half x f)
  int tid = threadIdx.x;
  int f0 = blockIdx.x * 16;
  int i0 = blockIdx.y * 16;
  int ii = tid >> 4, ff = tid & 15;
  int i = i0 + ii;
  int f = f0 + ff;
  int fr = (f < NF) ? f : 2048;
  float2 acc[NB];
  #pragma unroll
  for (int b = 0; b < NB; b++) acc[b] = make_float2(0.f, 0.f);
  for (int jh = 0; jh < 2; jh++) {
    __syncthreads();
    for (int q = tid; q < NB*32*16; q += 256) {
      int b = q >> 9, j = (q >> 4) & 31, fq = q & 15;
      int f_ = f0 + fq;
      uds[b][j][fq] = (f_ < NF) ? ud[((size_t)(b*HD + jh*32 + j))*NF + f_]
                                : make_float2(0.f, 0.f);
    }
    __syncthreads();
    for (int j = 0; j < 32; j++) {
      float2 kv = unpack_c(kdt[((size_t)(i*HD + jh*32 + j))*NF + fr]);
      #pragma unroll
      for (int b = 0; b < NB; b++) {
        float2 uv = uds[b][j][ff];
        acc[b].x += kv.x*uv.x - kv.y*uv.y;
        acc[b].y += kv.x*uv.y + kv.y*uv.x;
      }
    }
  }
  if (f < NF) {
    #pragma unroll
    for (int b = 0; b < NB; b++)
      yf[((size_t)(b*HD + i))*NF + f] = acc[b];
  }
}

// ---------------- K5: yt row = irfft_4096(yf row)[0:2048]; grid 512 ----------------
__global__ __launch_bounds__(256) void ssm_k5(const float2* __restrict__ yf,
                                              float* __restrict__ yt, int dv) {
  __shared__ float2 b0[FFT_BUF];
  __shared__ float2 b1[FFT_BUF];
  __shared__ float2 TW[256];
  int tid = threadIdx.x;
  int b = blockIdx.x >> 6, i = blockIdx.x & 63;
  const float2* src = yf + (size_t)(b*HD + i) * NF;
  float2* dst = (float2*)(yt + (((size_t)(dv*NB + b))*HD + i) * LSEQ);
  build_tw256(TW);
  for (int k = tid; k < 2048; k += 256) {
    float2 Xk = src[k];
    float2 Xm = src[2048 - k];
    float Ex = (Xk.x + Xm.x)*0.5f, Ey = (Xk.y - Xm.y)*0.5f;
    float Dx = Xk.x - Xm.x,        Dy = Xk.y + Xm.y;
    float s, c;
    __sincosf(6.28318530717958647f * (float)k * (1.0f/4096.0f), &s, &c);
    float Ox = 0.5f*(Dx*c - Dy*s);
    float Oy = 0.5f*(Dx*s + Dy*c);
    b0[SL(k)] = make_float2(Ex - Oy, Ey + Ox);   // Z = E + i*O
  }
  r4_stage<1, 1>(b0, b1, TW);
  r4_mid<1>(b1, b0, TW);                         // ends in b1
  r2f_gw_f32h(b1, dst);                          // scaled, t<1024 only, direct write
}

// ---------------- T2: yt[div][b][i][t] -> out[b][t][i*8+div] ----------------
__global__ __launch_bounds__(256) void ssm_t2(const float* __restrict__ yt, float* __restrict__ out) {
  __shared__ float s[512][17];
  int b  = blockIdx.x >> 7;
  int t0 = (blockIdx.x & 127) << 4;
  int tid = threadIdx.x;
  for (int q = tid; q < 512*16; q += 256) {
    int d = q >> 4, tt = q & 15;
    int dvv = d & 7, i = d >> 3;
    s[d][tt] = yt[(((size_t)(dvv*NB + b))*HD + i)*LSEQ + t0 + tt];
  }
  __syncthreads();
  for (int q = tid; q < 512*16; q += 256) {
    int tt = q >> 9, d = q & 511;
    out[((size_t)b*LSEQ + t0 + tt)*512 + d] = s[d][tt];
  }
}

// ---------------- host ----------------
extern "C" void kernel_launch(void* const* d_in, const int* in_sizes, int n_in,
                              void* d_out, int out_size, void* d_ws, size_t ws_size,
                              hipStream_t stream) {
  const float* u    = (const float*)d_in[0];
  const float* Lre  = (const float*)d_in[1];
  const float* Lim  = (const float*)d_in[2];
  const float* Pre  = (const float*)d_in[3];
  const float* Pim  = (const float*)d_in[4];
  const float* Bre  = (const float*)d_in[5];
  const float* Bim  = (const float*)d_in[6];
  const float* Cre  = (const float*)d_in[7];
  const float* Cim  = (const float*)d_in[8];
  const float* step = (const float*)d_in[9];
  float* out = (float*)d_out;

  char* w = (char*)d_ws;
  size_t off = 0;
  auto carve = [&](size_t bytes) -> void* {
    void* p = (void*)(w + off);
    off += (bytes + 255) & ~(size_t)255;
    return p;
  };
  float2*   rc   = (float2*)carve((size_t)NDIV*LSEQ*NM*sizeof(float2));   // 8.39 MB
  float2*   cpx  = (float2*)carve((size_t)NDIV*LSEQ*sizeof(float2));      // 0.13 MB
  float*    ut   = (float*) carve((size_t)NDIV*NB*HD*LSEQ*sizeof(float)); // 33.55 MB (later = yt)
  unsigned* big  = (unsigned*)carve((size_t)4096*NF*sizeof(unsigned));    // 33.57 MB (bf16x2)
  float2*   ud   = (float2*)carve((size_t)512*NF*sizeof(float2));         // 8.39 MB (per div)
  float2*   yf   = (float2*)carve((size_t)512*NF*sizeof(float2));         // 8.39 MB (per div)
  float2*   CT   = (float2*)carve((size_t)NDIV*NM*HD*sizeof(float2));     // 256 KB
  float2*   BT   = (float2*)carve((size_t)NDIV*NM*HD*sizeof(float2));     // 256 KB
  float2*   PT   = (float2*)carve((size_t)NDIV*NM*sizeof(float2));        // 4 KB
  (void)in_sizes; (void)n_in; (void)out_size;
  if (ws_size < off) return;   // insufficient scratch -> clean failure, diagnosable

  ssm_kt<<<128, 256, 0, stream>>>(Cre, Cim, Bre, Bim, Pre, Pim, CT, BT, PT);
  ssm_k0a<<<256, 256, 0, stream>>>(Lre, Lim, Pre, Pim, step, rc, cpx);
  ssm_ku<<<1024, 256, 0, stream>>>(u, ut);
  for (int dv = 0; dv < NDIV; ++dv) {
    ssm_k3<<<512, 256, 0, stream>>>(ut, ud, dv);
    ssm_k1<<<dim3(512, 2), 256, 0, stream>>>(CT, BT, PT, rc, cpx, big, dv);
    ssm_k2<<<4096, 256, 0, stream>>>(big);
    ssm_k4<<<dim3(129, 4), 256, 0, stream>>>(big, ud, yf);
    ssm_k5<<<512, 256, 0, stream>>>(yf, ut, dv);
  }
  ssm_t2<<<1024, 256, 0, stream>>>(ut, out);
}

// Round 7
// 1022.127 us; speedup vs baseline: 2.5806x; 1.3883x over previous
//
#include <hip/hip_runtime.h>
#include <hip/hip_bf16.h>
#include <math.h>

#define LSEQ 2048
#define NM   64     // N modes
#define HD   64     // H
#define NDIV 8
#define NB   8      // batch
#define NF   2049   // rfft bins of 4096
#define ATROWS 4224 // 4096 ij + 64 Mp + 64 Mq

// padded LDS slot: +1 float2 every 32 -> all FFT accesses <=2-way bank aliasing
#define SL(E) ((E) + ((E) >> 5))
#define FFT_BUF 2112   // SL(2047)=2110 < 2112

typedef __attribute__((ext_vector_type(8))) short bf16x8;
typedef __attribute__((ext_vector_type(4))) float f32x4;

// ---------------- bf16 helpers ----------------
__device__ __forceinline__ unsigned pack_c(float2 v) {
  __hip_bfloat162 h = __float22bfloat162_rn(v);
  return *reinterpret_cast<unsigned*>(&h);
}
__device__ __forceinline__ float2 unpack_c(unsigned u) {
  __hip_bfloat162 h = *reinterpret_cast<__hip_bfloat162*>(&u);
  return __bfloat1622float2(h);
}
__device__ __forceinline__ unsigned short f2bf(float v) {
  __hip_bfloat16 h = __float2bfloat16(v);
  return *reinterpret_cast<unsigned short*>(&h);
}

// ---------------- double complex helpers (precompute only) ----------------
struct cplxd { double x, y; };
__device__ __forceinline__ cplxd cmuld(cplxd a, cplxd b) {
  return {a.x*b.x - a.y*b.y, a.x*b.y + a.y*b.x};
}
__device__ __forceinline__ cplxd cdivd(cplxd a, cplxd b) {
  double inv = 1.0 / (b.x*b.x + b.y*b.y);
  return {(a.x*b.x + a.y*b.y)*inv, (a.y*b.x - a.x*b.y)*inv};
}

// ---------------- TW256[m] = exp(-i*pi*m/512) ----------------
__device__ __forceinline__ void build_tw256(float2* TW) {
  int m = threadIdx.x;
  if (m < 256) {
    float s, c;
    __sincosf(-3.14159265358979324f * (float)m * (1.0f/512.0f), &s, &c);
    TW[m] = make_float2(c, s);
  }
}

// ---------------- Stockham radix-4 stage (N=2048, 256 threads), LDS->LDS ----------------
template<int SIGN, int M>
__device__ __forceinline__ void r4_stage(const float2* __restrict__ src,
                                         float2* __restrict__ dst,
                                         const float2* __restrict__ TW) {
  constexpr int L = 2048 / (4 * M);
  __syncthreads();
  #pragma unroll
  for (int t = 0; t < 2; t++) {
    int idx = (int)threadIdx.x + t * 256;      // [0,512)
    int q = idx / M;
    int p = idx & (M - 1);
    float2 a0 = src[SL(idx)];
    float2 a1 = src[SL(idx + 512)];
    float2 a2 = src[SL(idx + 1024)];
    float2 a3 = src[SL(idx + 1536)];
    float2 w = TW[(p * L) >> 1];
    float2 W1 = make_float2(w.x, (SIGN > 0) ? -w.y : w.y);
    float2 W2 = make_float2(W1.x*W1.x - W1.y*W1.y, 2.f*W1.x*W1.y);
    float2 W3 = make_float2(W2.x*W1.x - W2.y*W1.y, W2.x*W1.y + W2.y*W1.x);
    float2 b1 = make_float2(a1.x*W1.x - a1.y*W1.y, a1.x*W1.y + a1.y*W1.x);
    float2 b2 = make_float2(a2.x*W2.x - a2.y*W2.y, a2.x*W2.y + a2.y*W2.x);
    float2 b3 = make_float2(a3.x*W3.x - a3.y*W3.y, a3.x*W3.y + a3.y*W3.x);
    float2 e0 = make_float2(a0.x + b2.x, a0.y + b2.y);
    float2 e1 = make_float2(b1.x + b3.x, b1.y + b3.y);
    float2 d0 = make_float2(a0.x - b2.x, a0.y - b2.y);
    float2 d1 = make_float2(b1.x - b3.x, b1.y - b3.y);
    float2 o1, o3;
    if (SIGN < 0) { o1 = make_float2(d0.x + d1.y, d0.y - d1.x);
                    o3 = make_float2(d0.x - d1.y, d0.y + d1.x); }
    else          { o1 = make_float2(d0.x - d1.y, d0.y + d1.x);
                    o3 = make_float2(d0.x + d1.y, d0.y - d1.x); }
    int ob = q * 4 * M + p;
    dst[SL(ob)]         = make_float2(e0.x + e1.x, e0.y + e1.y);
    dst[SL(ob + M)]     = o1;
    dst[SL(ob + 2*M)]   = make_float2(e0.x - e1.x, e0.y - e1.y);
    dst[SL(ob + 3*M)]   = o3;
  }
}

template<int SIGN>
__device__ __forceinline__ void r4_mid(float2* a, float2* b, const float2* TW) {
  r4_stage<SIGN,   4>(a, b, TW);
  r4_stage<SIGN,  16>(b, a, TW);
  r4_stage<SIGN,  64>(a, b, TW);
  r4_stage<SIGN, 256>(b, a, TW);
}

template<int SIGN>
__device__ __forceinline__ void r2f_ldst(const float2* __restrict__ src,
                                         float2* __restrict__ dst) {
  __syncthreads();
  #pragma unroll
  for (int t = 0; t < 4; t++) {
    int p = (int)threadIdx.x + t * 256;
    float2 a = src[SL(p)], b = src[SL(p + 1024)];
    float s, c;
    __sincosf(-6.28318530717958647f * (float)p * (1.0f/2048.0f), &s, &c);
    float wy = (SIGN > 0) ? -s : s;
    float2 wb = make_float2(b.x*c - b.y*wy, b.x*wy + b.y*c);
    dst[SL(p)]        = make_float2(a.x + wb.x, a.y + wb.y);
    dst[SL(p + 1024)] = make_float2(a.x - wb.x, a.y - wb.y);
  }
}

// k2 FFT#1 stage 1 (SIGN=+1, M=1): reads bf16 row direct from global
__device__ __forceinline__ void r4g_bf16_inv(const unsigned* __restrict__ row,
                                             float2* __restrict__ dst) {
  #pragma unroll
  for (int t = 0; t < 2; t++) {
    int idx = (int)threadIdx.x + t * 256;
    float2 a0 = unpack_c(row[idx]);
    float2 a1 = unpack_c(row[idx + 512]);
    float2 a2 = unpack_c(row[idx + 1024]);
    float2 a3 = unpack_c(row[idx + 1536]);
    float2 e0 = make_float2(a0.x + a2.x, a0.y + a2.y);
    float2 e1 = make_float2(a1.x + a3.x, a1.y + a3.y);
    float2 d0 = make_float2(a0.x - a2.x, a0.y - a2.y);
    float2 d1 = make_float2(a1.x - a3.x, a1.y - a3.y);
    float2 o1 = make_float2(d0.x - d1.y, d0.y + d1.x);
    float2 o3 = make_float2(d0.x + d1.y, d0.y - d1.x);
    int ob = idx * 4;
    dst[SL(ob)]   = make_float2(e0.x + e1.x, e0.y + e1.y);
    dst[SL(ob+1)] = o1;
    dst[SL(ob+2)] = make_float2(e0.x - e1.x, e0.y - e1.y);
    dst[SL(ob+3)] = o3;
  }
}

// k3 stage 1 (SIGN=-1, M=1): reads f32 z-pairs from global, upper half zero-padded
__device__ __forceinline__ void r4g_f32pad_fwd(const float2* __restrict__ g,
                                               float2* __restrict__ dst) {
  #pragma unroll
  for (int t = 0; t < 2; t++) {
    int idx = (int)threadIdx.x + t * 256;
    float2 a0 = g[idx];
    float2 a1 = g[idx + 512];
    int ob = idx * 4;
    dst[SL(ob)]   = make_float2(a0.x + a1.x, a0.y + a1.y);
    dst[SL(ob+1)] = make_float2(a0.x + a1.y, a0.y - a1.x);
    dst[SL(ob+2)] = make_float2(a0.x - a1.x, a0.y - a1.y);
    dst[SL(ob+3)] = make_float2(a0.x - a1.y, a0.y + a1.x);
  }
}

// k2 FFT#2 stage 1 (SIGN=-1, M=1) fused with Re()*(1/2048)*mod[t]
__device__ __forceinline__ void r4_modstage(const float2* __restrict__ src,
                                            float2* __restrict__ dst) {
  __syncthreads();
  const float sc = 1.0f/2048.0f;
  const float R = 0.70710678118654752f;
  #pragma unroll
  for (int t = 0; t < 2; t++) {
    int idx = (int)threadIdx.x + t * 256;
    float k0 = src[SL(idx)].x        * sc;
    float k1 = src[SL(idx + 512)].x  * sc;
    float k2 = src[SL(idx + 1024)].x * sc;
    float k3 = src[SL(idx + 1536)].x * sc;
    float s, c;
    __sincosf(-3.14159265358979324f * (float)idx * (1.0f/2048.0f), &s, &c);
    float2 a0 = make_float2(k0*c,         k0*s);
    float2 a1 = make_float2(k1*R*(c + s), k1*R*(s - c));
    float2 a2 = make_float2(k2*s,        -k2*c);
    float2 a3 = make_float2(k3*R*(s - c), -k3*R*(s + c));
    float2 e0 = make_float2(a0.x + a2.x, a0.y + a2.y);
    float2 e1 = make_float2(a1.x + a3.x, a1.y + a3.y);
    float2 d0 = make_float2(a0.x - a2.x, a0.y - a2.y);
    float2 d1 = make_float2(a1.x - a3.x, a1.y - a3.y);
    float2 o1 = make_float2(d0.x + d1.y, d0.y - d1.x);
    float2 o3 = make_float2(d0.x - d1.y, d0.y + d1.x);
    int ob = idx * 4;
    dst[SL(ob)]   = make_float2(e0.x + e1.x, e0.y + e1.y);
    dst[SL(ob+1)] = o1;
    dst[SL(ob+2)] = make_float2(e0.x - e1.x, e0.y - e1.y);
    dst[SL(ob+3)] = o3;
  }
}

__device__ __forceinline__ void r2f_gw_bf16(const float2* __restrict__ src,
                                            unsigned* __restrict__ row) {
  __syncthreads();
  #pragma unroll
  for (int t = 0; t < 4; t++) {
    int p = (int)threadIdx.x + t * 256;
    float2 a = src[SL(p)], b = src[SL(p + 1024)];
    float s, c;
    __sincosf(-6.28318530717958647f * (float)p * (1.0f/2048.0f), &s, &c);
    float2 wb = make_float2(b.x*c - b.y*s, b.x*s + b.y*c);
    row[2*p + 1] = pack_c(make_float2(a.x + wb.x, a.y + wb.y));
  }
}

__device__ __forceinline__ void r2f_gw_f32h(const float2* __restrict__ src,
                                            float2* __restrict__ dst) {
  __syncthreads();
  const float sc = 1.0f/2048.0f;
  #pragma unroll
  for (int t = 0; t < 4; t++) {
    int p = (int)threadIdx.x + t * 256;
    float2 a = src[SL(p)], b = src[SL(p + 1024)];
    float s, c;
    __sincosf(-6.28318530717958647f * (float)p * (1.0f/2048.0f), &s, &c);
    float wy = -s;
    float2 wb = make_float2(b.x*c - b.y*wy, b.x*wy + b.y*c);
    dst[p] = make_float2((a.x + wb.x)*sc, (a.y + wb.y)*sc);
  }
}

// ---------------- KT: params -> div-major coalesced layouts ----------------
__global__ __launch_bounds__(256) void ssm_kt(
    const float* __restrict__ Cre, const float* __restrict__ Cim,
    const float* __restrict__ Bre, const float* __restrict__ Bim,
    const float* __restrict__ Pre, const float* __restrict__ Pim,
    float2* __restrict__ CT, float2* __restrict__ BT, float2* __restrict__ PT) {
  int idx = blockIdx.x * 256 + threadIdx.x;   // 32768 = dv*4096 + n*64 + x
  int dv = idx >> 12, n = (idx >> 6) & 63, x = idx & 63;
  CT[idx] = make_float2(Cre[((size_t)x*NM + n)*NDIV + dv], -Cim[((size_t)x*NM + n)*NDIV + dv]);
  BT[idx] = make_float2(Bre[((size_t)n*HD + x)*NDIV + dv],  Bim[((size_t)n*HD + x)*NDIV + dv]);
  if (idx < NDIV*NM) {
    int dv2 = idx >> 6, n2 = idx & 63;
    PT[idx] = make_float2(Pre[n2*NDIV + dv2], Pim[n2*NDIV + dv2]);
  }
}

// ---------------- K0a: rcb bf16 planes (k-interleaved) + cpx ----------------
__global__ __launch_bounds__(256) void ssm_k0a(
    const float* __restrict__ Lre, const float* __restrict__ Lim,
    const float* __restrict__ Pre, const float* __restrict__ Pim,
    const float* __restrict__ step, unsigned short* __restrict__ RBr,
    unsigned short* __restrict__ RBi, float2* __restrict__ cpx) {
  int idx = blockIdx.x * 256 + threadIdx.x;     // 65536 = (dv*2048 + l)*4 + qn
  int qn = idx & 3;
  int rest = idx >> 2;
  int l = rest & (LSEQ - 1);
  int dv = rest >> 11;
  double s = (double)expf(step[0]);
  float angf = -6.2831855f * ((float)l * (1.0f/2048.0f));
  double si, co;
  sincos((double)angf, &si, &co);
  cplxd om    = {co, si};
  cplxd one_p = {1.0 + om.x,  om.y};
  double ts = 2.0 / s;
  cplxd g = cdivd({ts*(1.0 - om.x), ts*(-om.y)}, one_p);
  cplxd c = cdivd({2.0, 0.0}, one_p);
  double k11x = 0.0, k11y = 0.0;
  for (int u = 0; u < 16; u++) {
    int n = qn*16 + u;
    float lre = fminf(Lre[n*NDIV+dv], -0.0001f);
    float lim = Lim[n*NDIV+dv];
    cplxd den = {g.x - (double)lre, g.y - (double)lim};
    cplxd r   = cdivd({1.0, 0.0}, den);
    cplxd rcv = cmuld(c, r);
    size_t bidx = (((size_t)(dv*8 + (n >> 3)))*LSEQ + l)*8 + (n & 7);
    RBr[bidx] = f2bf((float)rcv.x);
    RBi[bidx] = f2bf((float)rcv.y);
    double pr = (double)Pre[n*NDIV+dv], pi = (double)Pim[n*NDIV+dv];
    double p2 = pr*pr + pi*pi;                  // conj(p)*p is real
    k11x += p2 * rcv.x; k11y += p2 * rcv.y;
  }
  k11x += __shfl_xor(k11x, 1); k11y += __shfl_xor(k11y, 1);
  k11x += __shfl_xor(k11x, 2); k11y += __shfl_xor(k11y, 2);
  if (qn == 0)
    cpx[(size_t)dv*LSEQ + l] = make_float2((float)(c.x + k11x), (float)(c.y + k11y));
}

// ---------------- KM: build AT planes (rows: 4096 ij, 64 Mp, 64 Mq) ----------------
__global__ __launch_bounds__(256) void ssm_km(
    const float2* __restrict__ CT, const float2* __restrict__ BT,
    const float2* __restrict__ PT, unsigned short* __restrict__ ATr,
    unsigned short* __restrict__ ATi, unsigned short* __restrict__ ATin) {
  __shared__ float2 PAN[4096];   // 32 KB
  __shared__ float2 ROW[64];
  int dv = blockIdx.y;
  int ib = blockIdx.x;           // 0..63 = i; 64 = Mp/Mq block
  int tid = threadIdx.x;
  if (ib < 64) {
    for (int q = tid; q < 4096; q += 256) PAN[q] = BT[(size_t)dv*4096 + q];  // [n][j]
    if (tid < 64) ROW[tid] = CT[(size_t)dv*4096 + tid*64 + ib];              // CC[ib][n]
    __syncthreads();
    int j = tid >> 2, nq = tid & 3;
    size_t rbase = ((size_t)dv*ATROWS + ib*64 + j)*64;
    for (int u = 0; u < 16; u++) {
      int n = nq*16 + u;
      float2 cv = ROW[n];
      float2 bv = PAN[n*64 + j];
      float xr = cv.x*bv.x - cv.y*bv.y, xi = cv.x*bv.y + cv.y*bv.x;
      ATr[rbase + n] = f2bf(xr); ATi[rbase + n] = f2bf(xi); ATin[rbase + n] = f2bf(-xi);
    }
  } else {
    // Mp rows 4096+x: CC[x][n]*p[n]
    for (int q = tid; q < 4096; q += 256) PAN[q] = CT[(size_t)dv*4096 + q];  // [n][x]
    if (tid < 64) ROW[tid] = PT[dv*64 + tid];
    __syncthreads();
    int x = tid >> 2, nq = tid & 3;
    size_t pbase = ((size_t)dv*ATROWS + 4096 + x)*64;
    for (int u = 0; u < 16; u++) {
      int n = nq*16 + u;
      float2 cv = PAN[n*64 + x];
      float2 pv = ROW[n];
      float xr = cv.x*pv.x - cv.y*pv.y, xi = cv.x*pv.y + cv.y*pv.x;
      ATr[pbase + n] = f2bf(xr); ATi[pbase + n] = f2bf(xi); ATin[pbase + n] = f2bf(-xi);
    }
    __syncthreads();
    // Mq rows 4160+x: conj(p)[n]*B[n][x]
    for (int q = tid; q < 4096; q += 256) PAN[q] = BT[(size_t)dv*4096 + q];
    __syncthreads();
    size_t qbase = ((size_t)dv*ATROWS + 4160 + x)*64;
    for (int u = 0; u < 16; u++) {
      int n = nq*16 + u;
      float2 bv = PAN[n*64 + x];
      float2 pv = ROW[n];
      float xr = pv.x*bv.x + pv.y*bv.y, xi = pv.x*bv.y - pv.y*bv.x;
      ATr[qbase + n] = f2bf(xr); ATi[qbase + n] = f2bf(xi); ATin[qbase + n] = f2bf(-xi);
    }
  }
}

// ---------------- MFMA GEMM core: out[m-rows][l-cols] over K=64 modes ----------------
// A[m][k]: lane m=lane&15, k=(lane>>4)*8+e (row-major, 16B/frag).
// B[k][n]: lane n=lane&15, k=(lane>>4)*8+e (rcb k-interleaved layout, 16B/frag).
// D[m][n]: n=lane&15, m=(lane>>4)*4+reg.
__device__ __forceinline__ void gemm_core(
    const unsigned short* __restrict__ ATr, const unsigned short* __restrict__ ATi,
    const unsigned short* __restrict__ ATin, const unsigned short* __restrict__ RBr,
    const unsigned short* __restrict__ RBi, int dv, int mrow0, int l0, int lane,
    f32x4 accR[4], f32x4 accI[4]) {
  int mloc = lane & 15, kgrp = lane >> 4;
  #pragma unroll
  for (int t = 0; t < 4; t++) {
    accR[t] = (f32x4){0.f, 0.f, 0.f, 0.f};
    accI[t] = (f32x4){0.f, 0.f, 0.f, 0.f};
  }
  size_t abase = ((size_t)dv*ATROWS + mrow0 + mloc)*64 + kgrp*8;
  #pragma unroll
  for (int s = 0; s < 2; s++) {
    bf16x8 ar = *reinterpret_cast<const bf16x8*>(ATr  + abase + s*32);
    bf16x8 ai = *reinterpret_cast<const bf16x8*>(ATi  + abase + s*32);
    bf16x8 an = *reinterpret_cast<const bf16x8*>(ATin + abase + s*32);
    size_t bbase = (((size_t)(dv*8 + s*4 + kgrp))*LSEQ + l0 + mloc)*8;
    #pragma unroll
    for (int t = 0; t < 4; t++) {
      bf16x8 br = *reinterpret_cast<const bf16x8*>(RBr + bbase + t*128);
      bf16x8 bi = *reinterpret_cast<const bf16x8*>(RBi + bbase + t*128);
      accR[t] = __builtin_amdgcn_mfma_f32_16x16x32_bf16(ar, br, accR[t], 0, 0, 0);
      accR[t] = __builtin_amdgcn_mfma_f32_16x16x32_bf16(an, bi, accR[t], 0, 0, 0);
      accI[t] = __builtin_amdgcn_mfma_f32_16x16x32_bf16(ar, bi, accI[t], 0, 0, 0);
      accI[t] = __builtin_amdgcn_mfma_f32_16x16x32_bf16(ai, br, accI[t], 0, 0, 0);
    }
  }
}

// ---------------- G1: Woodbury vectors via the Mp/Mq GEMM rows ----------------
__global__ __launch_bounds__(256) void ssm_g1(
    const unsigned short* __restrict__ ATr, const unsigned short* __restrict__ ATi,
    const unsigned short* __restrict__ ATin, const unsigned short* __restrict__ RBr,
    const unsigned short* __restrict__ RBi, const float2* __restrict__ cpx,
    float2* __restrict__ A1h, float2* __restrict__ K10h) {
  int which = blockIdx.x;          // 0 = Mp -> A1h, 1 = Mq -> K10h
  int nBlk = blockIdx.y;
  int dv = blockIdx.z;
  int wave = threadIdx.x >> 6, lane = threadIdx.x & 63;
  int mrow0 = 4096 + which*64 + wave*16;
  int l0 = nBlk * 64;
  f32x4 accR[4], accI[4];
  gemm_core(ATr, ATi, ATin, RBr, RBi, dv, mrow0, l0, lane, accR, accI);
  int rbase = (lane >> 4) * 4;
  #pragma unroll
  for (int t = 0; t < 4; t++) {
    int l = l0 + t*16 + (lane & 15);
    if (which == 0) {
      float2 w = cpx[((size_t)dv << 11) + l];
      float inv = 1.0f / (w.x*w.x + w.y*w.y);
      #pragma unroll
      for (int r = 0; r < 4; r++) {
        int x = wave*16 + rbase + r;
        float sx = accR[t][r], sy = accI[t][r];
        A1h[((size_t)(dv*64 + x))*LSEQ + l] =
            make_float2((sx*w.x + sy*w.y)*inv, (sy*w.x - sx*w.y)*inv);
      }
    } else {
      #pragma unroll
      for (int r = 0; r < 4; r++) {
        int x = wave*16 + rbase + r;
        K10h[((size_t)(dv*LSEQ + l))*64 + x] = make_float2(accR[t][r], accI[t][r]);
      }
    }
  }
}

// ---------------- G2: at_roots GEMM + rank-1 correction, bf16x2 chain-major ----------------
__global__ __launch_bounds__(256) void ssm_g2(
    const unsigned short* __restrict__ ATr, const unsigned short* __restrict__ ATi,
    const unsigned short* __restrict__ ATin, const unsigned short* __restrict__ RBr,
    const unsigned short* __restrict__ RBi, const float2* __restrict__ A1h,
    const float2* __restrict__ K10h, unsigned* __restrict__ big, int dv) {
  int mBlk = blockIdx.x;           // = i (64 ij rows per block, one i)
  int nBlk = blockIdx.y;
  int wave = threadIdx.x >> 6, lane = threadIdx.x & 63;
  int mrow0 = mBlk*64 + wave*16;
  int l0 = nBlk * 64;
  f32x4 accR[4], accI[4];
  gemm_core(ATr, ATi, ATin, RBr, RBi, dv, mrow0, l0, lane, accR, accI);
  int rbase = (lane >> 4) * 4;
  #pragma unroll
  for (int t = 0; t < 4; t++) {
    int l = l0 + t*16 + (lane & 15);
    float2 a1 = A1h[((size_t)(dv*64 + mBlk))*LSEQ + l];
    const float2* kp = K10h + ((size_t)(dv*LSEQ + l))*64 + wave*16 + rbase;
    #pragma unroll
    for (int r = 0; r < 4; r++) {
      float2 k10 = kp[r];
      float cx = a1.x*k10.x - a1.y*k10.y;
      float cy = a1.x*k10.y + a1.y*k10.x;
      int chain = mBlk*64 + wave*16 + rbase + r;
      big[(size_t)chain*NF + l] = pack_c(make_float2(accR[t][r] - cx, accI[t][r] - cy));
    }
  }
}

// ---------------- Ku: u (b,l,512) -> ut[div][b][h][l] ----------------
__global__ __launch_bounds__(256) void ssm_ku(const float* __restrict__ u, float* __restrict__ ut) {
  __shared__ float s[16][513];
  int b  = blockIdx.x >> 7;
  int l0 = (blockIdx.x & 127) << 4;
  int tid = threadIdx.x;
  for (int q = tid; q < 16*512; q += 256) {
    int ll = q >> 9, dd = q & 511;
    s[ll][dd] = u[((size_t)b*LSEQ + l0 + ll)*512 + dd];
  }
  __syncthreads();
  for (int q = tid; q < 16*512; q += 256) {
    int d = q >> 4, ll = q & 15;
    int dvv = d & 7, h = d >> 3;
    ut[(((size_t)(dvv*NB + b))*HD + h)*LSEQ + l0 + ll] = s[ll][d];
  }
}

// ---------------- K3: per div: ud[c][f] = rfft_4096(pad(ut row)) ----------------
__global__ __launch_bounds__(256) void ssm_k3(const float* __restrict__ ut, float2* __restrict__ ud, int dv) {
  __shared__ float2 b0[FFT_BUF];
  __shared__ float2 b1[FFT_BUF];
  __shared__ float2 TW[256];
  int tid = threadIdx.x;
  int c = blockIdx.x;                           // 0..511 = b*64 + h
  const float2* src = (const float2*)(ut + ((size_t)dv*512 + c) * LSEQ);
  float2* dst = ud + (size_t)c * NF;
  build_tw256(TW);
  r4g_f32pad_fwd(src, b1);
  r4_mid<-1>(b1, b0, TW);
  r2f_ldst<-1>(b1, b0);
  __syncthreads();
  for (int f = tid; f <= 2048; f += 256) {
    int fa = f & 2047, fb = (2048 - f) & 2047;
    float2 Zf = b0[SL(fa)];
    float2 Zm = b0[SL(fb)];
    float Ex = (Zf.x + Zm.x)*0.5f, Ey = (Zf.y - Zm.y)*0.5f;
    float Dx = Zf.x - Zm.x,        Dy = Zf.y + Zm.y;
    float Ox = Dy*0.5f, Oy = -Dx*0.5f;
    float s, c2;
    __sincosf(-6.28318530717958647f * (float)f * (1.0f/4096.0f), &s, &c2);
    float WOx = Ox*c2 - Oy*s, WOy = Ox*s + Oy*c2;
    dst[f] = make_float2(Ex + WOx, Ey + WOy);
  }
}

// ---------------- K2: in-place per chain: ar row (2048 bf16x2) -> Kd row (2049) ----------------
__global__ __launch_bounds__(256) void ssm_k2(unsigned* __restrict__ big) {
  __shared__ float2 b0[FFT_BUF];
  __shared__ float2 b1[FFT_BUF];
  __shared__ float2 TW[256];
  int tid = threadIdx.x;
  unsigned* row = big + (size_t)blockIdx.x * NF;
  build_tw256(TW);
  float2 ev[4];
  #pragma unroll
  for (int k = 0; k < 4; k++) {
    int l = tid + 256*k;
    float2 a = unpack_c(row[l]);
    float2 b = unpack_c(row[(2048 - l) & 2047]);
    ev[k] = make_float2((a.x + b.x)*0.5f, (a.y - b.y)*0.5f);
  }
  float ev1024 = (tid == 0) ? unpack_c(row[1024]).x : 0.f;
  r4g_bf16_inv(row, b1);
  __syncthreads();
  #pragma unroll
  for (int k = 0; k < 4; k++) { int l = tid + 256*k; row[2*l] = pack_c(ev[k]); }
  if (tid == 0) row[2048] = pack_c(make_float2(ev1024, 0.f));
  r4_mid<1>(b1, b0, TW);
  r2f_ldst<1>(b1, b0);
  r4_modstage(b0, b1);
  r4_mid<-1>(b1, b0, TW);
  r2f_gw_bf16(b1, row);
}

// ---------------- K4: yf[b*64+i][f] = sum_j Kd[i*64+j][f]*ud[b*64+j][f] ----------------
__global__ __launch_bounds__(256) void ssm_k4(
    const unsigned* __restrict__ kdt, const float2* __restrict__ ud,
    float2* __restrict__ yf) {
  __shared__ float2 uds[NB][32][16];   // 32 KB
  int tid = threadIdx.x;
  int f0 = blockIdx.x * 16;
  int i0 = blockIdx.y * 16;
  int ii = tid >> 4, ff = tid & 15;
  int i = i0 + ii;
  int f = f0 + ff;
  int fr = (f < NF) ? f : 2048;
  float2 acc[NB];
  #pragma unroll
  for (int b = 0; b < NB; b++) acc[b] = make_float2(0.f, 0.f);
  for (int jh = 0; jh < 2; jh++) {
    __syncthreads();
    for (int q = tid; q < NB*32*16; q += 256) {
      int b = q >> 9, j = (q >> 4) & 31, fq = q & 15;
      int f_ = f0 + fq;
      uds[b][j][fq] = (f_ < NF) ? ud[((size_t)(b*HD + jh*32 + j))*NF + f_]
                                : make_float2(0.f, 0.f);
    }
    __syncthreads();
    for (int j = 0; j < 32; j++) {
      float2 kv = unpack_c(kdt[((size_t)(i*HD + jh*32 + j))*NF + fr]);
      #pragma unroll
      for (int b = 0; b < NB; b++) {
        float2 uv = uds[b][j][ff];
        acc[b].x += kv.x*uv.x - kv.y*uv.y;
        acc[b].y += kv.x*uv.y + kv.y*uv.x;
      }
    }
  }
  if (f < NF) {
    #pragma unroll
    for (int b = 0; b < NB; b++)
      yf[((size_t)(b*HD + i))*NF + f] = acc[b];
  }
}

// ---------------- K5: yt row = irfft_4096(yf row)[0:2048]; grid 512 ----------------
__global__ __launch_bounds__(256) void ssm_k5(const float2* __restrict__ yf,
                                              float* __restrict__ yt, int dv) {
  __shared__ float2 b0[FFT_BUF];
  __shared__ float2 b1[FFT_BUF];
  __shared__ float2 TW[256];
  int tid = threadIdx.x;
  int b = blockIdx.x >> 6, i = blockIdx.x & 63;
  const float2* src = yf + (size_t)(b*HD + i) * NF;
  float2* dst = (float2*)(yt + (((size_t)(dv*NB + b))*HD + i) * LSEQ);
  build_tw256(TW);
  for (int k = tid; k < 2048; k += 256) {
    float2 Xk = src[k];
    float2 Xm = src[2048 - k];
    float Ex = (Xk.x + Xm.x)*0.5f, Ey = (Xk.y - Xm.y)*0.5f;
    float Dx = Xk.x - Xm.x,        Dy = Xk.y + Xm.y;
    float s, c;
    __sincosf(6.28318530717958647f * (float)k * (1.0f/4096.0f), &s, &c);
    float Ox = 0.5f*(Dx*c - Dy*s);
    float Oy = 0.5f*(Dx*s + Dy*c);
    b0[SL(k)] = make_float2(Ex - Oy, Ey + Ox);
  }
  r4_stage<1, 1>(b0, b1, TW);
  r4_mid<1>(b1, b0, TW);
  r2f_gw_f32h(b1, dst);
}

// ---------------- T2: yt[div][b][i][t] -> out[b][t][i*8+div] ----------------
__global__ __launch_bounds__(256) void ssm_t2(const float* __restrict__ yt, float* __restrict__ out) {
  __shared__ float s[512][17];
  int b  = blockIdx.x >> 7;
  int t0 = (blockIdx.x & 127) << 4;
  int tid = threadIdx.x;
  for (int q = tid; q < 512*16; q += 256) {
    int d = q >> 4, tt = q & 15;
    int dvv = d & 7, i = d >> 3;
    s[d][tt] = yt[(((size_t)(dvv*NB + b))*HD + i)*LSEQ + t0 + tt];
  }
  __syncthreads();
  for (int q = tid; q < 512*16; q += 256) {
    int tt = q >> 9, d = q & 511;
    out[((size_t)b*LSEQ + t0 + tt)*512 + d] = s[d][tt];
  }
}

// ---------------- host ----------------
extern "C" void kernel_launch(void* const* d_in, const int* in_sizes, int n_in,
                              void* d_out, int out_size, void* d_ws, size_t ws_size,
                              hipStream_t stream) {
  const float* u    = (const float*)d_in[0];
  const float* Lre  = (const float*)d_in[1];
  const float* Lim  = (const float*)d_in[2];
  const float* Pre  = (const float*)d_in[3];
  const float* Pim  = (const float*)d_in[4];
  const float* Bre  = (const float*)d_in[5];
  const float* Bim  = (const float*)d_in[6];
  const float* Cre  = (const float*)d_in[7];
  const float* Cim  = (const float*)d_in[8];
  const float* step = (const float*)d_in[9];
  float* out = (float*)d_out;

  char* w = (char*)d_ws;
  size_t off = 0;
  auto carve = [&](size_t bytes) -> void* {
    void* p = (void*)(w + off);
    off += (bytes + 255) & ~(size_t)255;
    return p;
  };
  float2*   cpx  = (float2*)carve((size_t)NDIV*LSEQ*sizeof(float2));          // 0.13 MB
  float*    ut   = (float*) carve((size_t)NDIV*NB*HD*LSEQ*sizeof(float));     // 33.55 MB (later = yt)
  unsigned* big  = (unsigned*)carve((size_t)4096*NF*sizeof(unsigned));        // 33.57 MB (bf16x2)
  float2*   ud   = (float2*)carve((size_t)512*NF*sizeof(float2));             // 8.39 MB (per div)
  float2*   yf   = (float2*)carve((size_t)512*NF*sizeof(float2));             // 8.39 MB (per div)
  float2*   CT   = (float2*)carve((size_t)NDIV*NM*HD*sizeof(float2));         // 256 KB
  float2*   BT   = (float2*)carve((size_t)NDIV*NM*HD*sizeof(float2));         // 256 KB
  float2*   PT   = (float2*)carve((size_t)NDIV*NM*sizeof(float2));            // 4 KB
  unsigned short* ATr  = (unsigned short*)carve((size_t)NDIV*ATROWS*64*2);    // 4.33 MB
  unsigned short* ATi  = (unsigned short*)carve((size_t)NDIV*ATROWS*64*2);    // 4.33 MB
  unsigned short* ATin = (unsigned short*)carve((size_t)NDIV*ATROWS*64*2);    // 4.33 MB
  unsigned short* RBr  = (unsigned short*)carve((size_t)NDIV*8*LSEQ*8*2);     // 2.10 MB
  unsigned short* RBi  = (unsigned short*)carve((size_t)NDIV*8*LSEQ*8*2);     // 2.10 MB
  float2*   A1h  = (float2*)carve((size_t)NDIV*64*LSEQ*sizeof(float2));       // 8.39 MB
  float2*   K10h = (float2*)carve((size_t)NDIV*LSEQ*64*sizeof(float2));       // 8.39 MB
  (void)in_sizes; (void)n_in; (void)out_size;
  if (ws_size < off) return;   // insufficient scratch -> clean failure, diagnosable

  ssm_kt<<<128, 256, 0, stream>>>(Cre, Cim, Bre, Bim, Pre, Pim, CT, BT, PT);
  ssm_k0a<<<256, 256, 0, stream>>>(Lre, Lim, Pre, Pim, step, RBr, RBi, cpx);
  ssm_km<<<dim3(65, 8), 256, 0, stream>>>(CT, BT, PT, ATr, ATi, ATin);
  ssm_ku<<<1024, 256, 0, stream>>>(u, ut);
  ssm_g1<<<dim3(2, 32, 8), 256, 0, stream>>>(ATr, ATi, ATin, RBr, RBi, cpx, A1h, K10h);
  for (int dv = 0; dv < NDIV; ++dv) {
    ssm_k3<<<512, 256, 0, stream>>>(ut, ud, dv);
    ssm_g2<<<dim3(64, 32), 256, 0, stream>>>(ATr, ATi, ATin, RBr, RBi, A1h, K10h, big, dv);
    ssm_k2<<<4096, 256, 0, stream>>>(big);
    ssm_k4<<<dim3(129, 4), 256, 0, stream>>>(big, ud, yf);
    ssm_k5<<<512, 256, 0, stream>>>(yf, ut, dv);
  }
  ssm_t2<<<1024, 256, 0, stream>>>(ut, out);
}

// Round 8
// 951.555 us; speedup vs baseline: 2.7720x; 1.0742x over previous
//
#include <hip/hip_runtime.h>
#include <hip/hip_bf16.h>
#include <math.h>

#define LSEQ 2048
#define NM   64     // N modes
#define HD   64     // H
#define NDIV 8
#define NB   8      // batch
#define NF   2049   // rfft bins of 4096
#define ATROWS 4224 // 4096 ij + 64 Mp + 64 Mq

// padded LDS slot: +1 float2 every 8 -> ~uniform bank use for all FFT families
#define SL(E) ((E) + ((E) >> 3))
#define FFT_BUF 2304   // SL(2047)=2302 < 2304

typedef __attribute__((ext_vector_type(8))) short bf16x8;
typedef __attribute__((ext_vector_type(4))) float f32x4;

// ---------------- bf16 helpers ----------------
__device__ __forceinline__ unsigned pack_c(float2 v) {
  __hip_bfloat162 h = __float22bfloat162_rn(v);
  return *reinterpret_cast<unsigned*>(&h);
}
__device__ __forceinline__ float2 unpack_c(unsigned u) {
  __hip_bfloat162 h = *reinterpret_cast<__hip_bfloat162*>(&u);
  return __bfloat1622float2(h);
}
__device__ __forceinline__ unsigned short f2bf(float v) {
  __hip_bfloat16 h = __float2bfloat16(v);
  return *reinterpret_cast<unsigned short*>(&h);
}

// ---------------- double complex helpers (precompute only) ----------------
struct cplxd { double x, y; };
__device__ __forceinline__ cplxd cmuld(cplxd a, cplxd b) {
  return {a.x*b.x - a.y*b.y, a.x*b.y + a.y*b.x};
}
__device__ __forceinline__ cplxd cdivd(cplxd a, cplxd b) {
  double inv = 1.0 / (b.x*b.x + b.y*b.y);
  return {(a.x*b.x + a.y*b.y)*inv, (a.y*b.x - a.x*b.y)*inv};
}

// ---------------- Stockham radix-4 stage, twiddles via sincos ----------------
template<int SIGN, int M>
__device__ __forceinline__ void r4_stage(const float2* __restrict__ src,
                                         float2* __restrict__ dst) {
  constexpr int L = 2048 / (4 * M);
  __syncthreads();
  #pragma unroll
  for (int t = 0; t < 2; t++) {
    int idx = (int)threadIdx.x + t * 256;      // [0,512)
    int q = idx / M;
    int p = idx & (M - 1);
    float2 a0 = src[SL(idx)];
    float2 a1 = src[SL(idx + 512)];
    float2 a2 = src[SL(idx + 1024)];
    float2 a3 = src[SL(idx + 1536)];
    float2 b1, b2, b3;
    if constexpr (M > 1) {
      float s, c;
      __sincosf(-3.14159265358979324f * (float)(p * L) * (1.0f/1024.0f), &s, &c);
      float2 W1 = make_float2(c, (SIGN > 0) ? -s : s);
      float2 W2 = make_float2(W1.x*W1.x - W1.y*W1.y, 2.f*W1.x*W1.y);
      float2 W3 = make_float2(W2.x*W1.x - W2.y*W1.y, W2.x*W1.y + W2.y*W1.x);
      b1 = make_float2(a1.x*W1.x - a1.y*W1.y, a1.x*W1.y + a1.y*W1.x);
      b2 = make_float2(a2.x*W2.x - a2.y*W2.y, a2.x*W2.y + a2.y*W2.x);
      b3 = make_float2(a3.x*W3.x - a3.y*W3.y, a3.x*W3.y + a3.y*W3.x);
    } else { b1 = a1; b2 = a2; b3 = a3; }
    float2 e0 = make_float2(a0.x + b2.x, a0.y + b2.y);
    float2 e1 = make_float2(b1.x + b3.x, b1.y + b3.y);
    float2 d0 = make_float2(a0.x - b2.x, a0.y - b2.y);
    float2 d1 = make_float2(b1.x - b3.x, b1.y - b3.y);
    float2 o1, o3;
    if (SIGN < 0) { o1 = make_float2(d0.x + d1.y, d0.y - d1.x);
                    o3 = make_float2(d0.x - d1.y, d0.y + d1.x); }
    else          { o1 = make_float2(d0.x - d1.y, d0.y + d1.x);
                    o3 = make_float2(d0.x + d1.y, d0.y - d1.x); }
    int ob = q * 4 * M + p;
    dst[SL(ob)]         = make_float2(e0.x + e1.x, e0.y + e1.y);
    dst[SL(ob + M)]     = o1;
    dst[SL(ob + 2*M)]   = make_float2(e0.x - e1.x, e0.y - e1.y);
    dst[SL(ob + 3*M)]   = o3;
  }
}

// middle 4 radix-4 stages: input in a, output in a
template<int SIGN>
__device__ __forceinline__ void r4_mid(float2* a, float2* b) {
  r4_stage<SIGN,   4>(a, b);
  r4_stage<SIGN,  16>(b, a);
  r4_stage<SIGN,  64>(a, b);
  r4_stage<SIGN, 256>(b, a);
}

// final radix-2 stage, LDS->LDS
template<int SIGN>
__device__ __forceinline__ void r2f_ldst(const float2* __restrict__ src,
                                         float2* __restrict__ dst) {
  __syncthreads();
  #pragma unroll
  for (int t = 0; t < 4; t++) {
    int p = (int)threadIdx.x + t * 256;
    float2 a = src[SL(p)], b = src[SL(p + 1024)];
    float s, c;
    __sincosf(-6.28318530717958647f * (float)p * (1.0f/2048.0f), &s, &c);
    float wy = (SIGN > 0) ? -s : s;
    float2 wb = make_float2(b.x*c - b.y*wy, b.x*wy + b.y*c);
    dst[SL(p)]        = make_float2(a.x + wb.x, a.y + wb.y);
    dst[SL(p + 1024)] = make_float2(a.x - wb.x, a.y - wb.y);
  }
}

// k2 FFT#1 stage 1 (SIGN=+1, M=1): reads bf16 row direct from global
__device__ __forceinline__ void r4g_bf16_inv(const unsigned* __restrict__ row,
                                             float2* __restrict__ dst) {
  #pragma unroll
  for (int t = 0; t < 2; t++) {
    int idx = (int)threadIdx.x + t * 256;
    float2 a0 = unpack_c(row[idx]);
    float2 a1 = unpack_c(row[idx + 512]);
    float2 a2 = unpack_c(row[idx + 1024]);
    float2 a3 = unpack_c(row[idx + 1536]);
    float2 e0 = make_float2(a0.x + a2.x, a0.y + a2.y);
    float2 e1 = make_float2(a1.x + a3.x, a1.y + a3.y);
    float2 d0 = make_float2(a0.x - a2.x, a0.y - a2.y);
    float2 d1 = make_float2(a1.x - a3.x, a1.y - a3.y);
    float2 o1 = make_float2(d0.x - d1.y, d0.y + d1.x);
    float2 o3 = make_float2(d0.x + d1.y, d0.y - d1.x);
    int ob = idx * 4;
    dst[SL(ob)]   = make_float2(e0.x + e1.x, e0.y + e1.y);
    dst[SL(ob+1)] = o1;
    dst[SL(ob+2)] = make_float2(e0.x - e1.x, e0.y - e1.y);
    dst[SL(ob+3)] = o3;
  }
}

// k3 stage 1 (SIGN=-1, M=1): reads f32 z-pairs from global, upper half zero-padded
__device__ __forceinline__ void r4g_f32pad_fwd(const float2* __restrict__ g,
                                               float2* __restrict__ dst) {
  #pragma unroll
  for (int t = 0; t < 2; t++) {
    int idx = (int)threadIdx.x + t * 256;
    float2 a0 = g[idx];
    float2 a1 = g[idx + 512];
    int ob = idx * 4;
    dst[SL(ob)]   = make_float2(a0.x + a1.x, a0.y + a1.y);
    dst[SL(ob+1)] = make_float2(a0.x + a1.y, a0.y - a1.x);
    dst[SL(ob+2)] = make_float2(a0.x - a1.x, a0.y - a1.y);
    dst[SL(ob+3)] = make_float2(a0.x - a1.y, a0.y + a1.x);
  }
}

// k2: fused {final r2f of ifft} + {Re()*(1/2048)*mod} + {stage-1 (SIGN=-1,M=1)}.
// pre = buffer BEFORE the final radix-2 of FFT#1. Only real parts of z needed:
//   Re z[p]      = pre[p].x + (b.x*c + b.y*s),  Re z[p+1024] = pre[p].x - (...),
//   with (s,c)=sincos(-2pi p/2048), b = pre[p+1024]  (SIGN=+1 final r2f).
__device__ __forceinline__ void r4_modfused(const float2* __restrict__ pre,
                                            float2* __restrict__ dst) {
  __syncthreads();
  const float sc = 1.0f/2048.0f;
  const float R = 0.70710678118654752f;
  #pragma unroll
  for (int t = 0; t < 2; t++) {
    int idx = (int)threadIdx.x + t * 256;      // [0,512)
    float a0x = pre[SL(idx)].x;
    float a1x = pre[SL(idx + 512)].x;
    float2 bA = pre[SL(idx + 1024)];
    float2 bB = pre[SL(idx + 1536)];
    float sA, cA, sB, cB;
    __sincosf(-6.28318530717958647f * (float)idx * (1.0f/2048.0f), &sA, &cA);
    __sincosf(-6.28318530717958647f * (float)(idx + 512) * (1.0f/2048.0f), &sB, &cB);
    float rA = bA.x*cA + bA.y*sA;
    float rB = bB.x*cB + bB.y*sB;
    float k0 = (a0x + rA) * sc;     // Re z[idx]
    float k1 = (a1x + rB) * sc;     // Re z[idx+512]
    float k2 = (a0x - rA) * sc;     // Re z[idx+1024]
    float k3 = (a1x - rB) * sc;     // Re z[idx+1536]
    float s, c;
    __sincosf(-3.14159265358979324f * (float)idx * (1.0f/2048.0f), &s, &c);
    float2 a0 = make_float2(k0*c,         k0*s);
    float2 a1 = make_float2(k1*R*(c + s), k1*R*(s - c));
    float2 a2 = make_float2(k2*s,        -k2*c);
    float2 a3 = make_float2(k3*R*(s - c), -k3*R*(s + c));
    float2 e0 = make_float2(a0.x + a2.x, a0.y + a2.y);
    float2 e1 = make_float2(a1.x + a3.x, a1.y + a3.y);
    float2 d0 = make_float2(a0.x - a2.x, a0.y - a2.y);
    float2 d1 = make_float2(a1.x - a3.x, a1.y - a3.y);
    float2 o1 = make_float2(d0.x + d1.y, d0.y - d1.x);
    float2 o3 = make_float2(d0.x - d1.y, d0.y + d1.x);
    int ob = idx * 4;
    dst[SL(ob)]   = make_float2(e0.x + e1.x, e0.y + e1.y);
    dst[SL(ob+1)] = o1;
    dst[SL(ob+2)] = make_float2(e0.x - e1.x, e0.y - e1.y);
    dst[SL(ob+3)] = o3;
  }
}

__device__ __forceinline__ void r2f_gw_bf16(const float2* __restrict__ src,
                                            unsigned* __restrict__ row) {
  __syncthreads();
  #pragma unroll
  for (int t = 0; t < 4; t++) {
    int p = (int)threadIdx.x + t * 256;
    float2 a = src[SL(p)], b = src[SL(p + 1024)];
    float s, c;
    __sincosf(-6.28318530717958647f * (float)p * (1.0f/2048.0f), &s, &c);
    float2 wb = make_float2(b.x*c - b.y*s, b.x*s + b.y*c);
    row[2*p + 1] = pack_c(make_float2(a.x + wb.x, a.y + wb.y));
  }
}

__device__ __forceinline__ void r2f_gw_f32h(const float2* __restrict__ src,
                                            float2* __restrict__ dst) {
  __syncthreads();
  const float sc = 1.0f/2048.0f;
  #pragma unroll
  for (int t = 0; t < 4; t++) {
    int p = (int)threadIdx.x + t * 256;
    float2 a = src[SL(p)], b = src[SL(p + 1024)];
    float s, c;
    __sincosf(-6.28318530717958647f * (float)p * (1.0f/2048.0f), &s, &c);
    float wy = -s;
    float2 wb = make_float2(b.x*c - b.y*wy, b.x*wy + b.y*c);
    dst[p] = make_float2((a.x + wb.x)*sc, (a.y + wb.y)*sc);
  }
}

// ---------------- KT: params -> div-major coalesced layouts ----------------
__global__ __launch_bounds__(256) void ssm_kt(
    const float* __restrict__ Cre, const float* __restrict__ Cim,
    const float* __restrict__ Bre, const float* __restrict__ Bim,
    const float* __restrict__ Pre, const float* __restrict__ Pim,
    float2* __restrict__ CT, float2* __restrict__ BT, float2* __restrict__ PT) {
  int idx = blockIdx.x * 256 + threadIdx.x;   // 32768 = dv*4096 + n*64 + x
  int dv = idx >> 12, n = (idx >> 6) & 63, x = idx & 63;
  CT[idx] = make_float2(Cre[((size_t)x*NM + n)*NDIV + dv], -Cim[((size_t)x*NM + n)*NDIV + dv]);
  BT[idx] = make_float2(Bre[((size_t)n*HD + x)*NDIV + dv],  Bim[((size_t)n*HD + x)*NDIV + dv]);
  if (idx < NDIV*NM) {
    int dv2 = idx >> 6, n2 = idx & 63;
    PT[idx] = make_float2(Pre[n2*NDIV + dv2], Pim[n2*NDIV + dv2]);
  }
}

// ---------------- K0a: rcb bf16 planes (k-interleaved) + cpx ----------------
__global__ __launch_bounds__(256) void ssm_k0a(
    const float* __restrict__ Lre, const float* __restrict__ Lim,
    const float* __restrict__ Pre, const float* __restrict__ Pim,
    const float* __restrict__ step, unsigned short* __restrict__ RBr,
    unsigned short* __restrict__ RBi, float2* __restrict__ cpx) {
  int idx = blockIdx.x * 256 + threadIdx.x;     // 65536 = (dv*2048 + l)*4 + qn
  int qn = idx & 3;
  int rest = idx >> 2;
  int l = rest & (LSEQ - 1);
  int dv = rest >> 11;
  double s = (double)expf(step[0]);
  float angf = -6.2831855f * ((float)l * (1.0f/2048.0f));
  double si, co;
  sincos((double)angf, &si, &co);
  cplxd om    = {co, si};
  cplxd one_p = {1.0 + om.x,  om.y};
  double ts = 2.0 / s;
  cplxd g = cdivd({ts*(1.0 - om.x), ts*(-om.y)}, one_p);
  cplxd c = cdivd({2.0, 0.0}, one_p);
  double k11x = 0.0, k11y = 0.0;
  for (int u = 0; u < 16; u++) {
    int n = qn*16 + u;
    float lre = fminf(Lre[n*NDIV+dv], -0.0001f);
    float lim = Lim[n*NDIV+dv];
    cplxd den = {g.x - (double)lre, g.y - (double)lim};
    cplxd r   = cdivd({1.0, 0.0}, den);
    cplxd rcv = cmuld(c, r);
    size_t bidx = (((size_t)(dv*8 + (n >> 3)))*LSEQ + l)*8 + (n & 7);
    RBr[bidx] = f2bf((float)rcv.x);
    RBi[bidx] = f2bf((float)rcv.y);
    double pr = (double)Pre[n*NDIV+dv], pi = (double)Pim[n*NDIV+dv];
    double p2 = pr*pr + pi*pi;                  // conj(p)*p is real
    k11x += p2 * rcv.x; k11y += p2 * rcv.y;
  }
  k11x += __shfl_xor(k11x, 1); k11y += __shfl_xor(k11y, 1);
  k11x += __shfl_xor(k11x, 2); k11y += __shfl_xor(k11y, 2);
  if (qn == 0)
    cpx[(size_t)dv*LSEQ + l] = make_float2((float)(c.x + k11x), (float)(c.y + k11y));
}

// ---------------- KM: build AT planes (rows: 4096 ij, 64 Mp, 64 Mq) ----------------
__global__ __launch_bounds__(256) void ssm_km(
    const float2* __restrict__ CT, const float2* __restrict__ BT,
    const float2* __restrict__ PT, unsigned short* __restrict__ ATr,
    unsigned short* __restrict__ ATi, unsigned short* __restrict__ ATin) {
  __shared__ float2 PAN[4096];   // 32 KB
  __shared__ float2 ROW[64];
  int dv = blockIdx.y;
  int ib = blockIdx.x;           // 0..63 = i; 64 = Mp/Mq block
  int tid = threadIdx.x;
  if (ib < 64) {
    for (int q = tid; q < 4096; q += 256) PAN[q] = BT[(size_t)dv*4096 + q];  // [n][j]
    if (tid < 64) ROW[tid] = CT[(size_t)dv*4096 + tid*64 + ib];              // CC[ib][n]
    __syncthreads();
    int j = tid >> 2, nq = tid & 3;
    size_t rbase = ((size_t)dv*ATROWS + ib*64 + j)*64;
    for (int u = 0; u < 16; u++) {
      int n = nq*16 + u;
      float2 cv = ROW[n];
      float2 bv = PAN[n*64 + j];
      float xr = cv.x*bv.x - cv.y*bv.y, xi = cv.x*bv.y + cv.y*bv.x;
      ATr[rbase + n] = f2bf(xr); ATi[rbase + n] = f2bf(xi); ATin[rbase + n] = f2bf(-xi);
    }
  } else {
    for (int q = tid; q < 4096; q += 256) PAN[q] = CT[(size_t)dv*4096 + q];  // [n][x]
    if (tid < 64) ROW[tid] = PT[dv*64 + tid];
    __syncthreads();
    int x = tid >> 2, nq = tid & 3;
    size_t pbase = ((size_t)dv*ATROWS + 4096 + x)*64;
    for (int u = 0; u < 16; u++) {
      int n = nq*16 + u;
      float2 cv = PAN[n*64 + x];
      float2 pv = ROW[n];
      float xr = cv.x*pv.x - cv.y*pv.y, xi = cv.x*pv.y + cv.y*pv.x;
      ATr[pbase + n] = f2bf(xr); ATi[pbase + n] = f2bf(xi); ATin[pbase + n] = f2bf(-xi);
    }
    __syncthreads();
    for (int q = tid; q < 4096; q += 256) PAN[q] = BT[(size_t)dv*4096 + q];
    __syncthreads();
    size_t qbase = ((size_t)dv*ATROWS + 4160 + x)*64;
    for (int u = 0; u < 16; u++) {
      int n = nq*16 + u;
      float2 bv = PAN[n*64 + x];
      float2 pv = ROW[n];
      float xr = pv.x*bv.x + pv.y*bv.y, xi = pv.x*bv.y - pv.y*bv.x;
      ATr[qbase + n] = f2bf(xr); ATi[qbase + n] = f2bf(xi); ATin[qbase + n] = f2bf(-xi);
    }
  }
}

// ---------------- MFMA GEMM core ----------------
__device__ __forceinline__ void gemm_core(
    const unsigned short* __restrict__ ATr, const unsigned short* __restrict__ ATi,
    const unsigned short* __restrict__ ATin, const unsigned short* __restrict__ RBr,
    const unsigned short* __restrict__ RBi, int dv, int mrow0, int l0, int lane,
    f32x4 accR[4], f32x4 accI[4]) {
  int mloc = lane & 15, kgrp = lane >> 4;
  #pragma unroll
  for (int t = 0; t < 4; t++) {
    accR[t] = (f32x4){0.f, 0.f, 0.f, 0.f};
    accI[t] = (f32x4){0.f, 0.f, 0.f, 0.f};
  }
  size_t abase = ((size_t)dv*ATROWS + mrow0 + mloc)*64 + kgrp*8;
  #pragma unroll
  for (int s = 0; s < 2; s++) {
    bf16x8 ar = *reinterpret_cast<const bf16x8*>(ATr  + abase + s*32);
    bf16x8 ai = *reinterpret_cast<const bf16x8*>(ATi  + abase + s*32);
    bf16x8 an = *reinterpret_cast<const bf16x8*>(ATin + abase + s*32);
    size_t bbase = (((size_t)(dv*8 + s*4 + kgrp))*LSEQ + l0 + mloc)*8;
    #pragma unroll
    for (int t = 0; t < 4; t++) {
      bf16x8 br = *reinterpret_cast<const bf16x8*>(RBr + bbase + t*128);
      bf16x8 bi = *reinterpret_cast<const bf16x8*>(RBi + bbase + t*128);
      accR[t] = __builtin_amdgcn_mfma_f32_16x16x32_bf16(ar, br, accR[t], 0, 0, 0);
      accR[t] = __builtin_amdgcn_mfma_f32_16x16x32_bf16(an, bi, accR[t], 0, 0, 0);
      accI[t] = __builtin_amdgcn_mfma_f32_16x16x32_bf16(ar, bi, accI[t], 0, 0, 0);
      accI[t] = __builtin_amdgcn_mfma_f32_16x16x32_bf16(ai, br, accI[t], 0, 0, 0);
    }
  }
}

// ---------------- G1: Woodbury vectors ----------------
__global__ __launch_bounds__(256) void ssm_g1(
    const unsigned short* __restrict__ ATr, const unsigned short* __restrict__ ATi,
    const unsigned short* __restrict__ ATin, const unsigned short* __restrict__ RBr,
    const unsigned short* __restrict__ RBi, const float2* __restrict__ cpx,
    float2* __restrict__ A1h, float2* __restrict__ K10h) {
  int which = blockIdx.x;          // 0 = Mp -> A1h, 1 = Mq -> K10h
  int nBlk = blockIdx.y;
  int dv = blockIdx.z;
  int wave = threadIdx.x >> 6, lane = threadIdx.x & 63;
  int mrow0 = 4096 + which*64 + wave*16;
  int l0 = nBlk * 64;
  f32x4 accR[4], accI[4];
  gemm_core(ATr, ATi, ATin, RBr, RBi, dv, mrow0, l0, lane, accR, accI);
  int rbase = (lane >> 4) * 4;
  #pragma unroll
  for (int t = 0; t < 4; t++) {
    int l = l0 + t*16 + (lane & 15);
    if (which == 0) {
      float2 w = cpx[((size_t)dv << 11) + l];
      float inv = 1.0f / (w.x*w.x + w.y*w.y);
      #pragma unroll
      for (int r = 0; r < 4; r++) {
        int x = wave*16 + rbase + r;
        float sx = accR[t][r], sy = accI[t][r];
        A1h[((size_t)(dv*64 + x))*LSEQ + l] =
            make_float2((sx*w.x + sy*w.y)*inv, (sy*w.x - sx*w.y)*inv);
      }
    } else {
      #pragma unroll
      for (int r = 0; r < 4; r++) {
        int x = wave*16 + rbase + r;
        K10h[((size_t)(dv*LSEQ + l))*64 + x] = make_float2(accR[t][r], accI[t][r]);
      }
    }
  }
}

// ---------------- G2: at_roots GEMM + rank-1 correction ----------------
__global__ __launch_bounds__(256) void ssm_g2(
    const unsigned short* __restrict__ ATr, const unsigned short* __restrict__ ATi,
    const unsigned short* __restrict__ ATin, const unsigned short* __restrict__ RBr,
    const unsigned short* __restrict__ RBi, const float2* __restrict__ A1h,
    const float2* __restrict__ K10h, unsigned* __restrict__ big, int dv) {
  int mBlk = blockIdx.x;           // = i
  int nBlk = blockIdx.y;
  int wave = threadIdx.x >> 6, lane = threadIdx.x & 63;
  int mrow0 = mBlk*64 + wave*16;
  int l0 = nBlk * 64;
  f32x4 accR[4], accI[4];
  gemm_core(ATr, ATi, ATin, RBr, RBi, dv, mrow0, l0, lane, accR, accI);
  int rbase = (lane >> 4) * 4;
  #pragma unroll
  for (int t = 0; t < 4; t++) {
    int l = l0 + t*16 + (lane & 15);
    float2 a1 = A1h[((size_t)(dv*64 + mBlk))*LSEQ + l];
    const float2* kp = K10h + ((size_t)(dv*LSEQ + l))*64 + wave*16 + rbase;
    #pragma unroll
    for (int r = 0; r < 4; r++) {
      float2 k10 = kp[r];
      float cx = a1.x*k10.x - a1.y*k10.y;
      float cy = a1.x*k10.y + a1.y*k10.x;
      int chain = mBlk*64 + wave*16 + rbase + r;
      big[(size_t)chain*NF + l] = pack_c(make_float2(accR[t][r] - cx, accI[t][r] - cy));
    }
  }
}

// ---------------- Ku: u (b,l,512) -> ut[div][b][h][l] ----------------
__global__ __launch_bounds__(256) void ssm_ku(const float* __restrict__ u, float* __restrict__ ut) {
  __shared__ float s[16][513];
  int b  = blockIdx.x >> 7;
  int l0 = (blockIdx.x & 127) << 4;
  int tid = threadIdx.x;
  for (int q = tid; q < 16*512; q += 256) {
    int ll = q >> 9, dd = q & 511;
    s[ll][dd] = u[((size_t)b*LSEQ + l0 + ll)*512 + dd];
  }
  __syncthreads();
  for (int q = tid; q < 16*512; q += 256) {
    int d = q >> 4, ll = q & 15;
    int dvv = d & 7, h = d >> 3;
    ut[(((size_t)(dvv*NB + b))*HD + h)*LSEQ + l0 + ll] = s[ll][d];
  }
}

// ---------------- K3: ud[dst][f] = rfft_4096(pad(ut chain cbase+bid)) ----------------
__global__ __launch_bounds__(256) void ssm_k3(const float* __restrict__ ut,
                                              float2* __restrict__ ud, int cbase) {
  __shared__ float2 b0[FFT_BUF];
  __shared__ float2 b1[FFT_BUF];
  int tid = threadIdx.x;
  const float2* src = (const float2*)(ut + ((size_t)(cbase + blockIdx.x)) * LSEQ);
  float2* dst = ud + (size_t)blockIdx.x * NF;
  r4g_f32pad_fwd(src, b1);
  r4_mid<-1>(b1, b0);           // ends in b1
  r2f_ldst<-1>(b1, b0);         // b0 = Z natural order
  __syncthreads();
  for (int f = tid; f <= 2048; f += 256) {
    int fa = f & 2047, fb = (2048 - f) & 2047;
    float2 Zf = b0[SL(fa)];
    float2 Zm = b0[SL(fb)];
    float Ex = (Zf.x + Zm.x)*0.5f, Ey = (Zf.y - Zm.y)*0.5f;
    float Dx = Zf.x - Zm.x,        Dy = Zf.y + Zm.y;
    float Ox = Dy*0.5f, Oy = -Dx*0.5f;
    float s, c2;
    __sincosf(-6.28318530717958647f * (float)f * (1.0f/4096.0f), &s, &c2);
    float WOx = Ox*c2 - Oy*s, WOy = Ox*s + Oy*c2;
    dst[f] = make_float2(Ex + WOx, Ey + WOy);
  }
}

// ---------------- K2: in-place per chain: ar row (2048 bf16x2) -> Kd row (2049) ----------------
__global__ __launch_bounds__(256) void ssm_k2(unsigned* __restrict__ big) {
  __shared__ float2 b0[FFT_BUF];
  __shared__ float2 b1[FFT_BUF];
  int tid = threadIdx.x;
  unsigned* row = big + (size_t)blockIdx.x * NF;
  float2 ev[4];
  #pragma unroll
  for (int k = 0; k < 4; k++) {
    int l = tid + 256*k;
    float2 a = unpack_c(row[l]);
    float2 b = unpack_c(row[(2048 - l) & 2047]);
    ev[k] = make_float2((a.x + b.x)*0.5f, (a.y - b.y)*0.5f);
  }
  float ev1024 = (tid == 0) ? unpack_c(row[1024]).x : 0.f;
  r4g_bf16_inv(row, b1);
  __syncthreads();
  #pragma unroll
  for (int k = 0; k < 4; k++) { int l = tid + 256*k; row[2*l] = pack_c(ev[k]); }
  if (tid == 0) row[2048] = pack_c(make_float2(ev1024, 0.f));
  r4_mid<1>(b1, b0);            // ends in b1 (pre-r2f layout of z)
  r4_modfused(b1, b0);          // fused r2f + Re*mod + stage-1 -> b0
  r4_mid<-1>(b0, b1);           // ends in b0
  r2f_gw_bf16(b0, row);         // odd bins direct to global
}

// ---------------- K4: yf[b*64+i][f] = sum_j Kd[i*64+j][f]*ud[b*64+j][f] ----------------
__global__ __launch_bounds__(256) void ssm_k4(
    const unsigned* __restrict__ kdt, const float2* __restrict__ ud,
    float2* __restrict__ yf) {
  __shared__ float2 uds[NB][32][16];   // 32 KB
  int tid = threadIdx.x;
  int f0 = blockIdx.x * 16;
  int i0 = blockIdx.y * 16;
  int ii = tid >> 4, ff = tid & 15;
  int i = i0 + ii;
  int f = f0 + ff;
  int fr = (f < NF) ? f : 2048;
  float2 acc[NB];
  #pragma unroll
  for (int b = 0; b < NB; b++) acc[b] = make_float2(0.f, 0.f);
  for (int jh = 0; jh < 2; jh++) {
    __syncthreads();
    for (int q = tid; q < NB*32*16; q += 256) {
      int b = q >> 9, j = (q >> 4) & 31, fq = q & 15;
      int f_ = f0 + fq;
      uds[b][j][fq] = (f_ < NF) ? ud[((size_t)(b*HD + jh*32 + j))*NF + f_]
                                : make_float2(0.f, 0.f);
    }
    __syncthreads();
    for (int j = 0; j < 32; j++) {
      float2 kv = unpack_c(kdt[((size_t)(i*HD + jh*32 + j))*NF + fr]);
      #pragma unroll
      for (int b = 0; b < NB; b++) {
        float2 uv = uds[b][j][ff];
        acc[b].x += kv.x*uv.x - kv.y*uv.y;
        acc[b].y += kv.x*uv.y + kv.y*uv.x;
      }
    }
  }
  if (f < NF) {
    #pragma unroll
    for (int b = 0; b < NB; b++)
      yf[((size_t)(b*HD + i))*NF + f] = acc[b];
  }
}

// ---------------- K5: yt row = irfft_4096(yf row)[0:2048]; grid 512 ----------------
__global__ __launch_bounds__(256) void ssm_k5(const float2* __restrict__ yf,
                                              float* __restrict__ yt, int dv) {
  __shared__ float2 b0[FFT_BUF];
  __shared__ float2 b1[FFT_BUF];
  int tid = threadIdx.x;
  int b = blockIdx.x >> 6, i = blockIdx.x & 63;
  const float2* src = yf + (size_t)(b*HD + i) * NF;
  float2* dst = (float2*)(yt + (((size_t)(dv*NB + b))*HD + i) * LSEQ);
  for (int k = tid; k < 2048; k += 256) {
    float2 Xk = src[k];
    float2 Xm = src[2048 - k];
    float Ex = (Xk.x + Xm.x)*0.5f, Ey = (Xk.y - Xm.y)*0.5f;
    float Dx = Xk.x - Xm.x,        Dy = Xk.y + Xm.y;
    float s, c;
    __sincosf(6.28318530717958647f * (float)k * (1.0f/4096.0f), &s, &c);
    float Ox = 0.5f*(Dx*c - Dy*s);
    float Oy = 0.5f*(Dx*s + Dy*c);
    b0[SL(k)] = make_float2(Ex - Oy, Ey + Ox);
  }
  r4_stage<1, 1>(b0, b1);
  r4_mid<1>(b1, b0);            // ends in b1
  r2f_gw_f32h(b1, dst);
}

// ---------------- T2: yt[div][b][i][t] -> out[b][t][i*8+div] ----------------
__global__ __launch_bounds__(256) void ssm_t2(const float* __restrict__ yt, float* __restrict__ out) {
  __shared__ float s[512][17];
  int b  = blockIdx.x >> 7;
  int t0 = (blockIdx.x & 127) << 4;
  int tid = threadIdx.x;
  for (int q = tid; q < 512*16; q += 256) {
    int d = q >> 4, tt = q & 15;
    int dvv = d & 7, i = d >> 3;
    s[d][tt] = yt[(((size_t)(dvv*NB + b))*HD + i)*LSEQ + t0 + tt];
  }
  __syncthreads();
  for (int q = tid; q < 512*16; q += 256) {
    int tt = q >> 9, d = q & 511;
    out[((size_t)b*LSEQ + t0 + tt)*512 + d] = s[d][tt];
  }
}

// ---------------- host ----------------
extern "C" void kernel_launch(void* const* d_in, const int* in_sizes, int n_in,
                              void* d_out, int out_size, void* d_ws, size_t ws_size,
                              hipStream_t stream) {
  const float* u    = (const float*)d_in[0];
  const float* Lre  = (const float*)d_in[1];
  const float* Lim  = (const float*)d_in[2];
  const float* Pre  = (const float*)d_in[3];
  const float* Pim  = (const float*)d_in[4];
  const float* Bre  = (const float*)d_in[5];
  const float* Bim  = (const float*)d_in[6];
  const float* Cre  = (const float*)d_in[7];
  const float* Cim  = (const float*)d_in[8];
  const float* step = (const float*)d_in[9];
  float* out = (float*)d_out;

  char* w = (char*)d_ws;
  size_t off = 0;
  auto carve = [&](size_t bytes) -> void* {
    void* p = (void*)(w + off);
    off += (bytes + 255) & ~(size_t)255;
    return p;
  };
  float2*   cpx  = (float2*)carve((size_t)NDIV*LSEQ*sizeof(float2));          // 0.13 MB
  float*    ut   = (float*) carve((size_t)NDIV*NB*HD*LSEQ*sizeof(float));     // 33.55 MB (later = yt)
  unsigned* big  = (unsigned*)carve((size_t)4096*NF*sizeof(unsigned));        // 33.57 MB (bf16x2)
  float2*   yf   = (float2*)carve((size_t)512*NF*sizeof(float2));             // 8.39 MB (per div)
  float2*   CT   = (float2*)carve((size_t)NDIV*NM*HD*sizeof(float2));         // 256 KB
  float2*   BT   = (float2*)carve((size_t)NDIV*NM*HD*sizeof(float2));         // 256 KB
  float2*   PT   = (float2*)carve((size_t)NDIV*NM*sizeof(float2));            // 4 KB
  unsigned short* ATr  = (unsigned short*)carve((size_t)NDIV*ATROWS*64*2);    // 4.33 MB
  unsigned short* ATi  = (unsigned short*)carve((size_t)NDIV*ATROWS*64*2);    // 4.33 MB
  unsigned short* ATin = (unsigned short*)carve((size_t)NDIV*ATROWS*64*2);    // 4.33 MB
  unsigned short* RBr  = (unsigned short*)carve((size_t)NDIV*8*LSEQ*8*2);     // 2.10 MB
  unsigned short* RBi  = (unsigned short*)carve((size_t)NDIV*8*LSEQ*8*2);     // 2.10 MB
  float2*   A1h  = (float2*)carve((size_t)NDIV*64*LSEQ*sizeof(float2));       // 8.39 MB
  float2*   K10h = (float2*)carve((size_t)NDIV*LSEQ*64*sizeof(float2));       // 8.39 MB
  size_t off_m = off;
  // prefer all-div ud (67.1 MB); fall back to per-div (8.39 MB) if ws too small
  float2* ud_full = (float2*)carve((size_t)NDIV*512*NF*sizeof(float2));
  bool full = (ws_size >= off);
  float2* ud = ud_full;
  if (!full) {
    off = off_m;
    ud = (float2*)carve((size_t)512*NF*sizeof(float2));
    if (ws_size < off) return;   // insufficient scratch -> clean failure
  }
  (void)in_sizes; (void)n_in; (void)out_size;

  ssm_kt<<<128, 256, 0, stream>>>(Cre, Cim, Bre, Bim, Pre, Pim, CT, BT, PT);
  ssm_k0a<<<256, 256, 0, stream>>>(Lre, Lim, Pre, Pim, step, RBr, RBi, cpx);
  ssm_km<<<dim3(65, 8), 256, 0, stream>>>(CT, BT, PT, ATr, ATi, ATin);
  ssm_ku<<<1024, 256, 0, stream>>>(u, ut);
  ssm_g1<<<dim3(2, 32, 8), 256, 0, stream>>>(ATr, ATi, ATin, RBr, RBi, cpx, A1h, K10h);
  if (full) ssm_k3<<<4096, 256, 0, stream>>>(ut, ud_full, 0);
  for (int dv = 0; dv < NDIV; ++dv) {
    if (!full) ssm_k3<<<512, 256, 0, stream>>>(ut, ud, dv*512);
    const float2* udp = full ? (ud_full + (size_t)dv*512*NF) : ud;
    ssm_g2<<<dim3(64, 32), 256, 0, stream>>>(ATr, ATi, ATin, RBr, RBi, A1h, K10h, big, dv);
    ssm_k2<<<4096, 256, 0, stream>>>(big);
    ssm_k4<<<dim3(129, 4), 256, 0, stream>>>(big, udp, yf);
    ssm_k5<<<512, 256, 0, stream>>>(yf, ut, dv);
  }
  ssm_t2<<<1024, 256, 0, stream>>>(ut, out);
}